// Round 7
// baseline (1263.757 us; speedup 1.0000x reference)
//
#include <hip/hip_runtime.h>
#include <hip/hip_bf16.h>

#define N_NODES 50000
#define N_EDGES 800000
#define N_GRAPH 64
#define NHEAD 4
#define CDIM 64
#define HC 256      // NHEAD*CDIM
#define NTT 8
#define NRR 6
#define EDIMM 16
#define SCAN_CHUNK 1024
#define NBLK_SCAN ((N_NODES + SCAN_CHUNK - 1) / SCAN_CHUNK)   // 49

typedef unsigned short u16;

__device__ __forceinline__ float eluf(float v) { return v > 0.f ? v : expm1f(v); }
__device__ __forceinline__ float u2f(u16 u) {
    union { float f; unsigned int i; } c; c.i = ((unsigned int)u) << 16; return c.f;
}
__device__ __forceinline__ u16 f2u(float f) {
    union { float f; unsigned int i; } c; c.f = f;
    unsigned int i = c.i;
    return (u16)((i + 0x7FFFu + ((i >> 16) & 1u)) >> 16);
}

__global__ __launch_bounds__(256) void k_zero(float* __restrict__ p, int n)
{
    int i = blockIdx.x * 256 + threadIdx.x;
    if (i < n) p[i] = 0.f;
}

// ---------------------------------------------------------------------------
// Tiny tables: t_h0[8][256]=node_emb@W0; t_as0/t_ad0[8][4]; t_ae0/1[6][4]
// All inputs fp32.
// ---------------------------------------------------------------------------
__global__ __launch_bounds__(256) void k_tables(
    const float* __restrict__ node_emb, const float* __restrict__ edge_emb,
    const float* __restrict__ W0, const float* __restrict__ We0,
    const float* __restrict__ as0, const float* __restrict__ ad0,
    const float* __restrict__ ae0, const float* __restrict__ We1,
    const float* __restrict__ ae1,
    float* __restrict__ t_h0, float* __restrict__ t_as0,
    float* __restrict__ t_ad0, float* __restrict__ t_ae0,
    float* __restrict__ t_ae1)
{
    __shared__ float s_h0[NTT * HC];
    __shared__ float s_he[NRR * HC];
    int tid = threadIdx.x;   // == output column m = h*64+c

    for (int t = 0; t < NTT; t++) {
        float acc = 0.f;
        for (int k = 0; k < CDIM; k++)
            acc += node_emb[t * CDIM + k] * W0[k * HC + tid];
        s_h0[t * HC + tid] = acc;
        t_h0[t * HC + tid] = acc;
    }
    for (int r = 0; r < NRR; r++) {
        float acc = 0.f;
        for (int k = 0; k < EDIMM; k++)
            acc += edge_emb[r * EDIMM + k] * We0[k * HC + tid];
        s_he[r * HC + tid] = acc;
    }
    __syncthreads();
    if (tid < NTT * NHEAD) {
        int t = tid >> 2, h = tid & 3;
        float a = 0.f, d = 0.f;
        for (int c = 0; c < CDIM; c++) {
            float hv = s_h0[t * HC + h * CDIM + c];
            a += hv * as0[h * CDIM + c];
            d += hv * ad0[h * CDIM + c];
        }
        t_as0[tid] = a;
        t_ad0[tid] = d;
    }
    if (tid < NRR * NHEAD) {
        int r = tid >> 2, h = tid & 3;
        float a = 0.f;
        for (int c = 0; c < CDIM; c++)
            a += s_he[r * HC + h * CDIM + c] * ae0[h * CDIM + c];
        t_ae0[tid] = a;
    }
    __syncthreads();
    for (int r = 0; r < NRR; r++) {
        float acc = 0.f;
        for (int k = 0; k < EDIMM; k++)
            acc += edge_emb[r * EDIMM + k] * We1[k * HC + tid];
        s_he[r * HC + tid] = acc;
    }
    __syncthreads();
    if (tid < NRR * NHEAD) {
        int r = tid >> 2, h = tid & 3;
        float a = 0.f;
        for (int c = 0; c < CDIM; c++)
            a += s_he[r * HC + h * CDIM + c] * ae1[h * CDIM + c];
        t_ae1[tid] = a;
    }
}

// ---------------------------------------------------------------------------
// CSR: count -> hierarchical scan -> scatter  (verified on HW in R6: A bit4=0)
// ---------------------------------------------------------------------------
__global__ __launch_bounds__(256) void k_count(
    const int* __restrict__ edge_index, const int* __restrict__ batch,
    int* __restrict__ deg, int* __restrict__ cnt)
{
    int i = blockIdx.x * 256 + threadIdx.x;
    if (i < N_EDGES) atomicAdd(&deg[edge_index[N_EDGES + i]], 1);
    if (i < N_NODES) atomicAdd(&cnt[batch[i]], 1);
}

__global__ __launch_bounds__(256) void k_scan1(
    const int* __restrict__ deg, int* __restrict__ blksum)
{
    __shared__ int s[256];
    int b = blockIdx.x, tid = threadIdx.x;
    int base = b * SCAN_CHUNK + tid * 4;
    int t = 0;
    #pragma unroll
    for (int k = 0; k < 4; k++) { int i = base + k; if (i < N_NODES) t += deg[i]; }
    s[tid] = t;
    __syncthreads();
    for (int off = 128; off > 0; off >>= 1) {
        if (tid < off) s[tid] += s[tid + off];
        __syncthreads();
    }
    if (tid == 0) blksum[b] = s[0];
}

__global__ void k_scan2(int* __restrict__ blksum, int* __restrict__ offs)
{
    if (threadIdx.x == 0 && blockIdx.x == 0) {
        int acc = 0;
        for (int b = 0; b < NBLK_SCAN; b++) { int t = blksum[b]; blksum[b] = acc; acc += t; }
        offs[N_NODES] = acc;
    }
}

__global__ __launch_bounds__(256) void k_scan3(
    const int* __restrict__ deg, const int* __restrict__ blksum,
    int* __restrict__ offs, int* __restrict__ cursor)
{
    __shared__ int s[256];
    int b = blockIdx.x, tid = threadIdx.x;
    int base = b * SCAN_CHUNK + tid * 4;
    int d[4]; int t = 0;
    #pragma unroll
    for (int k = 0; k < 4; k++) {
        int i = base + k;
        d[k] = (i < N_NODES) ? deg[i] : 0;
        t += d[k];
    }
    s[tid] = t;
    __syncthreads();
    for (int off = 1; off < 256; off <<= 1) {
        int v = (tid >= off) ? s[tid - off] : 0;
        __syncthreads();
        s[tid] += v;
        __syncthreads();
    }
    int excl = blksum[b] + s[tid] - t;
    #pragma unroll
    for (int k = 0; k < 4; k++) {
        int i = base + k;
        if (i < N_NODES) { offs[i] = excl; cursor[i] = excl; }
        excl += d[k];
    }
}

__global__ __launch_bounds__(256) void k_scatter(
    const int* __restrict__ edge_index, int* __restrict__ cursor, int* __restrict__ csr)
{
    int e = blockIdx.x * 256 + threadIdx.x;
    if (e < N_EDGES) {
        int d = edge_index[N_EDGES + e];
        int pos = atomicAdd(&cursor[d], 1);
        csr[pos] = e;
    }
}

// ---------------------------------------------------------------------------
// FUSED layer0 + (x1@W1) + attention dots. One wave per node; 12500 blocks.
// x1 never materialized. W1 cached in LDS as bf16 (32 KB; |err|~0.1% << tol).
// ---------------------------------------------------------------------------
__global__ __launch_bounds__(256) void k_fused(
    const int* __restrict__ node_type, const int* __restrict__ edge_index,
    const int* __restrict__ edge_type, const int* __restrict__ offs,
    const int* __restrict__ csr,
    const float* __restrict__ t_h0, const float* __restrict__ t_as0,
    const float* __restrict__ t_ad0, const float* __restrict__ t_ae0,
    const float* __restrict__ b0, const float* __restrict__ W1,
    const float* __restrict__ as1, const float* __restrict__ ad1,
    float* __restrict__ h1, float* __restrict__ asrc1, float* __restrict__ adst1)
{
    __shared__ float s_h0[NTT * HC];                 // 8 KB
    __shared__ u16  s_W1[CDIM * HC];                 // 32 KB (bf16)
    __shared__ float s_as[NTT * NHEAD], s_ad[NTT * NHEAD], s_ae[NRR * NHEAD];
    __shared__ float s_as1[HC], s_ad1[HC], s_b0[CDIM];
    __shared__ float xrow[4][CDIM];                  // 1 KB

    int tid = threadIdx.x;
    for (int i = tid; i < NTT * HC; i += 256) s_h0[i] = t_h0[i];
    for (int i = tid; i < CDIM * HC; i += 256) s_W1[i] = f2u(W1[i]);
    if (tid < NTT * NHEAD) { s_as[tid] = t_as0[tid]; s_ad[tid] = t_ad0[tid]; }
    if (tid < NRR * NHEAD) s_ae[tid] = t_ae0[tid];
    for (int i = tid; i < HC; i += 256) { s_as1[i] = as1[i]; s_ad1[i] = ad1[i]; }
    if (tid < CDIM) s_b0[tid] = b0[tid];
    __syncthreads();

    int n = (blockIdx.x * 256 + tid) >> 6;
    int lane = tid & 63;
    int wv = tid >> 6;
    int h = lane >> 4;
    int cq = (lane & 15) << 2;

    // ---- layer 0: segment softmax + aggregate from type tables ----
    int tn = node_type[n];
    float adst = s_ad[tn * NHEAD + h];
    int e0 = offs[n], e1 = offs[n + 1];
    float ax = 0.f, ay = 0.f, az = 0.f, aw = 0.f, den = 0.f;
    for (int i = e0; i < e1; i++) {
        int e = csr[i];
        int s = edge_index[e];
        int et = edge_type[e];
        int ts = node_type[s];
        float lg = s_as[ts * NHEAD + h] + adst + s_ae[et * NHEAD + h];
        lg = lg > 0.f ? lg : 0.2f * lg;
        float p = __expf(lg);
        den += p;
        const float4 v = *(const float4*)(s_h0 + ts * HC + h * CDIM + cq);
        ax += p * v.x; ay += p * v.y; az += p * v.z; aw += p * v.w;
    }
    float inv = 0.25f / (den + 1e-16f);   // 1/den * (1/NHEAD) head-mean
    ax *= inv; ay *= inv; az *= inv; aw *= inv;
    ax += __shfl_xor(ax, 16); ax += __shfl_xor(ax, 32);
    ay += __shfl_xor(ay, 16); ay += __shfl_xor(ay, 32);
    az += __shfl_xor(az, 16); az += __shfl_xor(az, 32);
    aw += __shfl_xor(aw, 16); aw += __shfl_xor(aw, 32);
    if (lane < 16) {
        xrow[wv][cq + 0] = eluf(ax + s_b0[cq + 0]);
        xrow[wv][cq + 1] = eluf(ay + s_b0[cq + 1]);
        xrow[wv][cq + 2] = eluf(az + s_b0[cq + 2]);
        xrow[wv][cq + 3] = eluf(aw + s_b0[cq + 3]);
    }
    __syncthreads();

    // ---- gemm: h1[n, lane*4 .. +3] = xrow[wv] @ W1 ----
    int c0 = lane << 2;
    float a0 = 0.f, a1 = 0.f, a2 = 0.f, a3 = 0.f;
    #pragma unroll 8
    for (int k = 0; k < CDIM; k++) {
        float xk = xrow[wv][k];
        const ushort4 w = *(const ushort4*)(s_W1 + k * HC + c0);
        a0 += xk * u2f(w.x); a1 += xk * u2f(w.y);
        a2 += xk * u2f(w.z); a3 += xk * u2f(w.w);
    }
    float4 hv; hv.x = a0; hv.y = a1; hv.z = a2; hv.w = a3;
    *(float4*)(h1 + (size_t)n * HC + c0) = hv;

    float rs = a0 * s_as1[c0] + a1 * s_as1[c0 + 1] + a2 * s_as1[c0 + 2] + a3 * s_as1[c0 + 3];
    float rd = a0 * s_ad1[c0] + a1 * s_ad1[c0 + 1] + a2 * s_ad1[c0 + 2] + a3 * s_ad1[c0 + 3];
    #pragma unroll
    for (int d = 8; d >= 1; d >>= 1) {
        rs += __shfl_xor(rs, d);
        rd += __shfl_xor(rd, d);
    }
    int hh = lane >> 4;
    if ((lane & 15) == 0) {
        asrc1[n * NHEAD + hh] = rs;
        adst1[n * NHEAD + hh] = rd;
    }
}

// ---------------------------------------------------------------------------
// Layer 1 aggregation + ELU + fused mean-pool accumulation.
// ---------------------------------------------------------------------------
__global__ __launch_bounds__(256) void k_agg1(
    const int* __restrict__ edge_index, const int* __restrict__ edge_type,
    const int* __restrict__ offs, const int* __restrict__ csr,
    const float* __restrict__ h1, const float* __restrict__ asrc1,
    const float* __restrict__ adst1, const float* __restrict__ t_ae1,
    const float* __restrict__ b1, const int* __restrict__ batch,
    float* __restrict__ s_pool)
{
    __shared__ float s_ae[NRR * NHEAD];
    if (threadIdx.x < NRR * NHEAD) s_ae[threadIdx.x] = t_ae1[threadIdx.x];
    __syncthreads();

    int n = (blockIdx.x * 256 + threadIdx.x) >> 6;
    int lane = threadIdx.x & 63;
    if (n >= N_NODES) return;
    int h = lane >> 4;
    int cq = (lane & 15) << 2;
    float adst = adst1[n * NHEAD + h];
    int e0 = offs[n], e1 = offs[n + 1];

    float ax = 0.f, ay = 0.f, az = 0.f, aw = 0.f, den = 0.f;
    for (int i = e0; i < e1; i++) {
        int e = csr[i];
        int s = edge_index[e];
        int et = edge_type[e];
        float lg = asrc1[s * NHEAD + h] + adst + s_ae[et * NHEAD + h];
        lg = lg > 0.f ? lg : 0.2f * lg;
        float p = __expf(lg);
        den += p;
        const float4 v = *(const float4*)(h1 + (size_t)s * HC + h * CDIM + cq);
        ax += p * v.x; ay += p * v.y; az += p * v.z; aw += p * v.w;
    }
    float inv = 0.25f / (den + 1e-16f);
    ax *= inv; ay *= inv; az *= inv; aw *= inv;
    ax += __shfl_xor(ax, 16); ax += __shfl_xor(ax, 32);
    ay += __shfl_xor(ay, 16); ay += __shfl_xor(ay, 32);
    az += __shfl_xor(az, 16); az += __shfl_xor(az, 32);
    aw += __shfl_xor(aw, 16); aw += __shfl_xor(aw, 32);
    if (lane < 16) {
        int g = batch[n];
        float* dst = s_pool + g * CDIM + cq;
        atomicAdd(dst + 0, eluf(ax + b1[cq + 0]));
        atomicAdd(dst + 1, eluf(ay + b1[cq + 1]));
        atomicAdd(dst + 2, eluf(az + b1[cq + 2]));
        atomicAdd(dst + 3, eluf(aw + b1[cq + 3]));
    }
}

// ---------------------------------------------------------------------------
// Classifier: one wave per graph, fp32 output.
// ---------------------------------------------------------------------------
__global__ __launch_bounds__(64) void k_cls(
    const float* __restrict__ s_pool, const int* __restrict__ cnt,
    const float* __restrict__ cw1, const float* __restrict__ cb1,
    const float* __restrict__ cw2, const float* __restrict__ cb2,
    float* __restrict__ out)
{
    int g = blockIdx.x, j = threadIdx.x;
    __shared__ float gm[CDIM];
    int c = cnt[g];
    float invc = 1.f / (float)(c > 1 ? c : 1);
    gm[j] = s_pool[g * CDIM + j] * invc;
    __syncthreads();
    float acc = cb1[j];
    #pragma unroll
    for (int k = 0; k < CDIM; k++) acc += gm[k] * cw1[k * CDIM + j];
    float hid = acc > 0.f ? acc : 0.f;
    float o0 = hid * cw2[j * 2 + 0];
    float o1 = hid * cw2[j * 2 + 1];
    #pragma unroll
    for (int d = 32; d >= 1; d >>= 1) {
        o0 += __shfl_xor(o0, d);
        o1 += __shfl_xor(o1, d);
    }
    if (j == 0) {
        out[g * 2 + 0] = o0 + cb2[0];
        out[g * 2 + 1] = o1 + cb2[1];
    }
}

// ---------------------------------------------------------------------------
// DIAGNOSTIC: code = A<<20 | wsMB<<10 | B. Writes nothing when healthy.
//  A: 1 no ordering matched | 2 ws too small | 4 offs[N]!=E | 8 fp32 implausible
//  B: csr OOB count (or size codes when A&1)
// ---------------------------------------------------------------------------
__global__ void k_diag(int hostA, int wsMB, int hostB, int ran,
                       const int* __restrict__ offs, const int* __restrict__ csr,
                       const float* __restrict__ W1, float* __restrict__ out)
{
    if (threadIdx.x != 0 || blockIdx.x != 0) return;
    int A = hostA, B = hostB;
    if (ran) {
        if (offs[N_NODES] != N_EDGES) A |= 4;
        int impl = 0;
        for (int i = 0; i < 256; i++) {
            float v = W1[i];
            if (!(fabsf(v) < 100.f)) impl++;   // NaN counts
        }
        if (impl > 10) A |= 8;
        int oob = 0;
        for (int i = 0; i < 1000; i++) {
            int c = csr[i];
            if (c < 0 || c >= N_EDGES) oob++;
        }
        B = oob;
    }
    if (B > 1023) B = 1023;
    if (A == 0 && B == 0) return;
    out[0] = (float)((A << 20) | (wsMB << 10) | B);
}

// ---------------------------------------------------------------------------
extern "C" void kernel_launch(void* const* d_in, const int* in_sizes, int n_in,
                              void* d_out, int out_size, void* d_ws, size_t ws_size,
                              hipStream_t stream) {
    // Role order: NT ET EI BA NE EE W0 We0 as0 ad0 ae0 b0 W1 We1 as1 ad1 ae1 b1 cw1 cb1 cw2 cb2
    static const int rsize[22] = {50000, 800000, 1600000, 50000, 512, 96,
                                  16384, 4096, 256, 256, 256, 64,
                                  16384, 4096, 256, 256, 256, 64,
                                  4096, 64, 128, 2};
    static const int cand_pos[3][22] = {
        // ASCII sorted() order (matched in R6 — listed first)
        {21,19,18,12,20,17,0,2,8,4,6,10,1,3,9,5,7,11,15,13,16,14},
        // dict / signature order
        {0,1,2,3,4,5,6,7,8,9,10,11,12,13,14,15,16,17,18,19,20,21},
        // case-insensitive alphabetical
        {17,15,14,8,16,13,18,20,4,0,2,6,19,21,5,1,3,7,11,9,12,10},
    };
    int mc = -1;
    if (n_in == 22) {
        for (int c = 0; c < 3 && mc < 0; c++) {
            bool ok = true;
            for (int r = 0; r < 22; r++)
                if (in_sizes[cand_pos[c][r]] != rsize[r]) { ok = false; break; }
            if (ok) mc = c;
        }
    }

    auto szcode = [](int s) -> int {
        switch (s) {
            case 2: return 1;  case 64: return 2;  case 96: return 3;
            case 128: return 4; case 256: return 5; case 512: return 6;
            case 4096: return 7; case 16384: return 8; case 50000: return 9;
            case 800000: return 10; case 1600000: return 11; default: return 15;
        }
    };

    int hostA = 0, hostB = 0;
    if (mc < 0) {
        hostA |= 1;
        if (n_in != 22) hostB = (n_in < 1023 ? n_in : 1023);
        else hostB = szcode(in_sizes[0]) | (szcode(in_sizes[1]) << 4);
    }

    // workspace layout (~57 MiB; ws_size = 256 MiB per R6)
    char* ws = (char*)d_ws;
    size_t off = 0;
    auto alloc = [&](size_t b) { size_t r = off; off += (b + 255) & ~(size_t)255; return r; };
    int*   deg    = (int*)(ws + alloc(N_NODES * 4));
    int*   cnt    = (int*)(ws + alloc(N_GRAPH * 4));
    float* s_pool = (float*)(ws + alloc(N_GRAPH * CDIM * 4));
    size_t zero_bytes = off;
    int*   blksum = (int*)(ws + alloc(NBLK_SCAN * 4));
    int*   offs   = (int*)(ws + alloc((N_NODES + 1) * 4));
    int*   cursor = (int*)(ws + alloc(N_NODES * 4));
    int*   csr    = (int*)(ws + alloc(N_EDGES * 4));
    float* t_h0   = (float*)(ws + alloc(NTT * HC * 4));
    float* t_as0  = (float*)(ws + alloc(NTT * NHEAD * 4));
    float* t_ad0  = (float*)(ws + alloc(NTT * NHEAD * 4));
    float* t_ae0  = (float*)(ws + alloc(NRR * NHEAD * 4));
    float* t_ae1  = (float*)(ws + alloc(NRR * NHEAD * 4));
    float* asrc1  = (float*)(ws + alloc((size_t)N_NODES * NHEAD * 4));
    float* adst1  = (float*)(ws + alloc((size_t)N_NODES * NHEAD * 4));
    float* h1     = (float*)(ws + alloc((size_t)N_NODES * HC * 4));

    if (mc >= 0 && off > ws_size) hostA |= 2;
    int wsMB = (int)(ws_size >> 20); if (wsMB > 1023) wsMB = 1023;
    int ran = (hostA == 0) ? 1 : 0;

    if (ran) {
        const int* P = cand_pos[mc];
        const int*   node_type  = (const int*)d_in[P[0]];
        const int*   edge_type  = (const int*)d_in[P[1]];
        const int*   edge_index = (const int*)d_in[P[2]];
        const int*   batch      = (const int*)d_in[P[3]];
        const float* node_emb   = (const float*)d_in[P[4]];
        const float* edge_emb   = (const float*)d_in[P[5]];
        const float* W0  = (const float*)d_in[P[6]];
        const float* We0 = (const float*)d_in[P[7]];
        const float* as0 = (const float*)d_in[P[8]];
        const float* ad0 = (const float*)d_in[P[9]];
        const float* ae0 = (const float*)d_in[P[10]];
        const float* b0  = (const float*)d_in[P[11]];
        const float* W1  = (const float*)d_in[P[12]];
        const float* We1 = (const float*)d_in[P[13]];
        const float* as1 = (const float*)d_in[P[14]];
        const float* ad1 = (const float*)d_in[P[15]];
        const float* ae1 = (const float*)d_in[P[16]];
        const float* b1  = (const float*)d_in[P[17]];
        const float* cw1 = (const float*)d_in[P[18]];
        const float* cb1 = (const float*)d_in[P[19]];
        const float* cw2 = (const float*)d_in[P[20]];
        const float* cb2 = (const float*)d_in[P[21]];

        int zero_elems = (int)(zero_bytes / 4);
        k_zero<<<(zero_elems + 255) / 256, 256, 0, stream>>>((float*)ws, zero_elems);
        k_tables<<<1, 256, 0, stream>>>(node_emb, edge_emb, W0, We0, as0, ad0, ae0,
                                        We1, ae1, t_h0, t_as0, t_ad0, t_ae0, t_ae1);
        k_count<<<(N_EDGES + 255) / 256, 256, 0, stream>>>(edge_index, batch, deg, cnt);
        k_scan1<<<NBLK_SCAN, 256, 0, stream>>>(deg, blksum);
        k_scan2<<<1, 64, 0, stream>>>(blksum, offs);
        k_scan3<<<NBLK_SCAN, 256, 0, stream>>>(deg, blksum, offs, cursor);
        k_scatter<<<(N_EDGES + 255) / 256, 256, 0, stream>>>(edge_index, cursor, csr);
        k_fused<<<(N_NODES * 64) / 256, 256, 0, stream>>>(
            node_type, edge_index, edge_type, offs, csr,
            t_h0, t_as0, t_ad0, t_ae0, b0, W1, as1, ad1, h1, asrc1, adst1);
        k_agg1<<<(N_NODES * 64 + 255) / 256, 256, 0, stream>>>(
            edge_index, edge_type, offs, csr, h1, asrc1, adst1, t_ae1, b1, batch, s_pool);
        k_cls<<<N_GRAPH, 64, 0, stream>>>(s_pool, cnt, cw1, cb1, cw2, cb2, (float*)d_out);
        k_diag<<<1, 64, 0, stream>>>(0, wsMB, 0, 1, offs, csr, W1, (float*)d_out);
    } else {
        k_diag<<<1, 64, 0, stream>>>(hostA, wsMB, hostB, 0, nullptr, nullptr,
                                     nullptr, (float*)d_out);
    }
}

// Round 8
// 1001.171 us; speedup vs baseline: 1.2623x; 1.2623x over previous
//
#include <hip/hip_runtime.h>
#include <hip/hip_bf16.h>

#define N_NODES 50000
#define N_EDGES 800000
#define N_GRAPH 64
#define NHEAD 4
#define CDIM 64
#define HC 256      // NHEAD*CDIM
#define NTT 8
#define NRR 6
#define EDIMM 16
#define SCAN_CHUNK 1024
#define NBLK_SCAN ((N_NODES + SCAN_CHUNK - 1) / SCAN_CHUNK)   // 49
#define FB 3125     // k_fused blocks; FB*4 waves * 4 groups = 50000 nodes

typedef unsigned short u16;

__device__ __forceinline__ float eluf(float v) { return v > 0.f ? v : expm1f(v); }
__device__ __forceinline__ float u2f(u16 u) {
    union { float f; unsigned int i; } c; c.i = ((unsigned int)u) << 16; return c.f;
}
__device__ __forceinline__ u16 f2u(float f) {
    union { float f; unsigned int i; } c; c.f = f;
    unsigned int i = c.i;
    return (u16)((i + 0x7FFFu + ((i >> 16) & 1u)) >> 16);
}
__device__ __forceinline__ float lrelu(float v) { return v > 0.f ? v : 0.2f * v; }

__global__ __launch_bounds__(256) void k_zero(float* __restrict__ p, int n)
{
    int i = blockIdx.x * 256 + threadIdx.x;
    if (i < n) p[i] = 0.f;
}

// ---------------------------------------------------------------------------
// Tiny tables + W1 -> bf16 conversion (done once here, not per k_fused block)
// ---------------------------------------------------------------------------
__global__ __launch_bounds__(256) void k_tables(
    const float* __restrict__ node_emb, const float* __restrict__ edge_emb,
    const float* __restrict__ W0, const float* __restrict__ We0,
    const float* __restrict__ as0, const float* __restrict__ ad0,
    const float* __restrict__ ae0, const float* __restrict__ We1,
    const float* __restrict__ ae1, const float* __restrict__ W1,
    float* __restrict__ t_h0, float* __restrict__ t_as0,
    float* __restrict__ t_ad0, float* __restrict__ t_ae0,
    float* __restrict__ t_ae1, u16* __restrict__ w1b)
{
    __shared__ float s_h0[NTT * HC];
    __shared__ float s_he[NRR * HC];
    int tid = threadIdx.x;

    for (int i = tid; i < CDIM * HC; i += 256) w1b[i] = f2u(W1[i]);

    for (int t = 0; t < NTT; t++) {
        float acc = 0.f;
        #pragma unroll 8
        for (int k = 0; k < CDIM; k++)
            acc += node_emb[t * CDIM + k] * W0[k * HC + tid];
        s_h0[t * HC + tid] = acc;
        t_h0[t * HC + tid] = acc;
    }
    for (int r = 0; r < NRR; r++) {
        float acc = 0.f;
        #pragma unroll
        for (int k = 0; k < EDIMM; k++)
            acc += edge_emb[r * EDIMM + k] * We0[k * HC + tid];
        s_he[r * HC + tid] = acc;
    }
    __syncthreads();
    if (tid < NTT * NHEAD) {
        int t = tid >> 2, h = tid & 3;
        float a = 0.f, d = 0.f;
        for (int c = 0; c < CDIM; c++) {
            float hv = s_h0[t * HC + h * CDIM + c];
            a += hv * as0[h * CDIM + c];
            d += hv * ad0[h * CDIM + c];
        }
        t_as0[tid] = a;
        t_ad0[tid] = d;
    }
    if (tid < NRR * NHEAD) {
        int r = tid >> 2, h = tid & 3;
        float a = 0.f;
        for (int c = 0; c < CDIM; c++)
            a += s_he[r * HC + h * CDIM + c] * ae0[h * CDIM + c];
        t_ae0[tid] = a;
    }
    __syncthreads();
    for (int r = 0; r < NRR; r++) {
        float acc = 0.f;
        #pragma unroll
        for (int k = 0; k < EDIMM; k++)
            acc += edge_emb[r * EDIMM + k] * We1[k * HC + tid];
        s_he[r * HC + tid] = acc;
    }
    __syncthreads();
    if (tid < NRR * NHEAD) {
        int r = tid >> 2, h = tid & 3;
        float a = 0.f;
        for (int c = 0; c < CDIM; c++)
            a += s_he[r * HC + h * CDIM + c] * ae1[h * CDIM + c];
        t_ae1[tid] = a;
    }
}

// ---------------------------------------------------------------------------
// CSR build (HW-verified R6/R7)
// ---------------------------------------------------------------------------
__global__ __launch_bounds__(256) void k_count(
    const int* __restrict__ edge_index, const int* __restrict__ batch,
    int* __restrict__ deg, int* __restrict__ cnt)
{
    int i = blockIdx.x * 256 + threadIdx.x;
    if (i < N_EDGES) atomicAdd(&deg[edge_index[N_EDGES + i]], 1);
    if (i < N_NODES) atomicAdd(&cnt[batch[i]], 1);
}

__global__ __launch_bounds__(256) void k_scan1(
    const int* __restrict__ deg, int* __restrict__ blksum)
{
    __shared__ int s[256];
    int b = blockIdx.x, tid = threadIdx.x;
    int base = b * SCAN_CHUNK + tid * 4;
    int t = 0;
    #pragma unroll
    for (int k = 0; k < 4; k++) { int i = base + k; if (i < N_NODES) t += deg[i]; }
    s[tid] = t;
    __syncthreads();
    for (int off = 128; off > 0; off >>= 1) {
        if (tid < off) s[tid] += s[tid + off];
        __syncthreads();
    }
    if (tid == 0) blksum[b] = s[0];
}

__global__ void k_scan2(int* __restrict__ blksum, int* __restrict__ offs)
{
    if (threadIdx.x == 0 && blockIdx.x == 0) {
        int acc = 0;
        for (int b = 0; b < NBLK_SCAN; b++) { int t = blksum[b]; blksum[b] = acc; acc += t; }
        offs[N_NODES] = acc;
    }
}

__global__ __launch_bounds__(256) void k_scan3(
    const int* __restrict__ deg, const int* __restrict__ blksum,
    int* __restrict__ offs, int* __restrict__ cursor)
{
    __shared__ int s[256];
    int b = blockIdx.x, tid = threadIdx.x;
    int base = b * SCAN_CHUNK + tid * 4;
    int d[4]; int t = 0;
    #pragma unroll
    for (int k = 0; k < 4; k++) {
        int i = base + k;
        d[k] = (i < N_NODES) ? deg[i] : 0;
        t += d[k];
    }
    s[tid] = t;
    __syncthreads();
    for (int off = 1; off < 256; off <<= 1) {
        int v = (tid >= off) ? s[tid - off] : 0;
        __syncthreads();
        s[tid] += v;
        __syncthreads();
    }
    int excl = blksum[b] + s[tid] - t;
    #pragma unroll
    for (int k = 0; k < 4; k++) {
        int i = base + k;
        if (i < N_NODES) { offs[i] = excl; cursor[i] = excl; }
        excl += d[k];
    }
}

__global__ __launch_bounds__(256) void k_scatter(
    const int* __restrict__ edge_index, int* __restrict__ cursor, int* __restrict__ csr)
{
    int e = blockIdx.x * 256 + threadIdx.x;
    if (e < N_EDGES) {
        int d = edge_index[N_EDGES + e];
        int pos = atomicAdd(&cursor[d], 1);
        csr[pos] = e;
    }
}

// ---------------------------------------------------------------------------
// FUSED layer0 + (x1@W1) + attention dots. Grid-stride: 3125 blocks x 4 node
// groups -> W1/t_h0 staged once per block. Edge loop batch-4 (4 independent
// load chains in flight). h1 stored bf16.
// ---------------------------------------------------------------------------
__global__ __launch_bounds__(256) void k_fused(
    const int* __restrict__ node_type, const int* __restrict__ edge_index,
    const int* __restrict__ edge_type, const int* __restrict__ offs,
    const int* __restrict__ csr,
    const float* __restrict__ t_h0, const float* __restrict__ t_as0,
    const float* __restrict__ t_ad0, const float* __restrict__ t_ae0,
    const float* __restrict__ b0, const u16* __restrict__ w1b,
    const float* __restrict__ as1, const float* __restrict__ ad1,
    u16* __restrict__ h1b, float* __restrict__ asrc1, float* __restrict__ adst1)
{
    __shared__ float s_h0[NTT * HC];                 // 8 KB
    __shared__ u16  s_W1[CDIM * HC];                 // 32 KB
    __shared__ float s_as[NTT * NHEAD], s_ad[NTT * NHEAD], s_ae[NRR * NHEAD];
    __shared__ float s_as1[HC], s_ad1[HC], s_b0[CDIM];
    __shared__ float xrow[4][CDIM];                  // 1 KB

    int tid = threadIdx.x;
    for (int i = tid; i < NTT * HC; i += 256) s_h0[i] = t_h0[i];
    {
        const uint4* src = (const uint4*)w1b;
        uint4* dst = (uint4*)s_W1;
        for (int i = tid; i < 2048; i += 256) dst[i] = src[i];
    }
    if (tid < NTT * NHEAD) { s_as[tid] = t_as0[tid]; s_ad[tid] = t_ad0[tid]; }
    if (tid < NRR * NHEAD) s_ae[tid] = t_ae0[tid];
    for (int i = tid; i < HC; i += 256) { s_as1[i] = as1[i]; s_ad1[i] = ad1[i]; }
    if (tid < CDIM) s_b0[tid] = b0[tid];
    __syncthreads();

    int lane = tid & 63;
    int wv = tid >> 6;
    int h = lane >> 4;
    int cq = (lane & 15) << 2;
    int c0 = lane << 2;

    for (int grp = 0; grp < 4; ++grp) {
        int n = (grp * FB + blockIdx.x) * 4 + wv;    // exact cover of [0,50000)

        // ---- layer 0: batched edge loop over LDS tables ----
        int tn = node_type[n];
        float adst = s_ad[tn * NHEAD + h];
        int e0 = offs[n], e1 = offs[n + 1];
        float ax = 0.f, ay = 0.f, az = 0.f, aw = 0.f, den = 0.f;
        for (int i = e0; i < e1; i += 4) {
            int last = e1 - 1;
            int i1 = i + 1 > last ? last : i + 1;
            int i2 = i + 2 > last ? last : i + 2;
            int i3 = i + 3 > last ? last : i + 3;
            float m1 = (i + 1 < e1) ? 1.f : 0.f;
            float m2 = (i + 2 < e1) ? 1.f : 0.f;
            float m3 = (i + 3 < e1) ? 1.f : 0.f;
            int eA = csr[i],  eB = csr[i1], eC = csr[i2], eD = csr[i3];
            int sA = edge_index[eA], sB = edge_index[eB];
            int sC = edge_index[eC], sD = edge_index[eD];
            int rA = edge_type[eA], rB = edge_type[eB];
            int rC = edge_type[eC], rD = edge_type[eD];
            int tA = node_type[sA], tB = node_type[sB];
            int tC = node_type[sC], tD = node_type[sD];
            float pA = __expf(lrelu(s_as[tA * NHEAD + h] + adst + s_ae[rA * NHEAD + h]));
            float pB = m1 * __expf(lrelu(s_as[tB * NHEAD + h] + adst + s_ae[rB * NHEAD + h]));
            float pC = m2 * __expf(lrelu(s_as[tC * NHEAD + h] + adst + s_ae[rC * NHEAD + h]));
            float pD = m3 * __expf(lrelu(s_as[tD * NHEAD + h] + adst + s_ae[rD * NHEAD + h]));
            den += pA + pB + pC + pD;
            const float4 vA = *(const float4*)(s_h0 + tA * HC + h * CDIM + cq);
            const float4 vB = *(const float4*)(s_h0 + tB * HC + h * CDIM + cq);
            const float4 vC = *(const float4*)(s_h0 + tC * HC + h * CDIM + cq);
            const float4 vD = *(const float4*)(s_h0 + tD * HC + h * CDIM + cq);
            ax += pA * vA.x + pB * vB.x + pC * vC.x + pD * vD.x;
            ay += pA * vA.y + pB * vB.y + pC * vC.y + pD * vD.y;
            az += pA * vA.z + pB * vB.z + pC * vC.z + pD * vD.z;
            aw += pA * vA.w + pB * vB.w + pC * vC.w + pD * vD.w;
        }
        float inv = 0.25f / (den + 1e-16f);
        ax *= inv; ay *= inv; az *= inv; aw *= inv;
        ax += __shfl_xor(ax, 16); ax += __shfl_xor(ax, 32);
        ay += __shfl_xor(ay, 16); ay += __shfl_xor(ay, 32);
        az += __shfl_xor(az, 16); az += __shfl_xor(az, 32);
        aw += __shfl_xor(aw, 16); aw += __shfl_xor(aw, 32);
        if (lane < 16) {
            xrow[wv][cq + 0] = eluf(ax + s_b0[cq + 0]);
            xrow[wv][cq + 1] = eluf(ay + s_b0[cq + 1]);
            xrow[wv][cq + 2] = eluf(az + s_b0[cq + 2]);
            xrow[wv][cq + 3] = eluf(aw + s_b0[cq + 3]);
        }
        __syncthreads();

        // ---- gemm: h1[n, c0..c0+3] ----
        float a0 = 0.f, a1 = 0.f, a2 = 0.f, a3 = 0.f;
        #pragma unroll 8
        for (int k = 0; k < CDIM; k++) {
            float xk = xrow[wv][k];
            const ushort4 w = *(const ushort4*)(s_W1 + k * HC + c0);
            a0 += xk * u2f(w.x); a1 += xk * u2f(w.y);
            a2 += xk * u2f(w.z); a3 += xk * u2f(w.w);
        }
        ushort4 hv;
        hv.x = f2u(a0); hv.y = f2u(a1); hv.z = f2u(a2); hv.w = f2u(a3);
        *(ushort4*)(h1b + (size_t)n * HC + c0) = hv;

        float rs = a0 * s_as1[c0] + a1 * s_as1[c0 + 1] + a2 * s_as1[c0 + 2] + a3 * s_as1[c0 + 3];
        float rd = a0 * s_ad1[c0] + a1 * s_ad1[c0 + 1] + a2 * s_ad1[c0 + 2] + a3 * s_ad1[c0 + 3];
        #pragma unroll
        for (int d = 8; d >= 1; d >>= 1) {
            rs += __shfl_xor(rs, d);
            rd += __shfl_xor(rd, d);
        }
        int hh = lane >> 4;
        if ((lane & 15) == 0) {
            asrc1[n * NHEAD + hh] = rs;
            adst1[n * NHEAD + hh] = rd;
        }
        __syncthreads();   // xrow reused next grp
    }
}

// ---------------------------------------------------------------------------
// Layer 1 aggregation + ELU + mean-pool. Batch-4 edge loop, bf16 h1 gathers.
// ---------------------------------------------------------------------------
__global__ __launch_bounds__(256) void k_agg1(
    const int* __restrict__ edge_index, const int* __restrict__ edge_type,
    const int* __restrict__ offs, const int* __restrict__ csr,
    const u16* __restrict__ h1b, const float* __restrict__ asrc1,
    const float* __restrict__ adst1, const float* __restrict__ t_ae1,
    const float* __restrict__ b1, const int* __restrict__ batch,
    float* __restrict__ s_pool)
{
    __shared__ float s_ae[NRR * NHEAD];
    if (threadIdx.x < NRR * NHEAD) s_ae[threadIdx.x] = t_ae1[threadIdx.x];
    __syncthreads();

    int n = (blockIdx.x * 256 + threadIdx.x) >> 6;
    int lane = threadIdx.x & 63;
    int h = lane >> 4;
    int cq = (lane & 15) << 2;
    float adst = adst1[n * NHEAD + h];
    int e0 = offs[n], e1 = offs[n + 1];

    float ax = 0.f, ay = 0.f, az = 0.f, aw = 0.f, den = 0.f;
    for (int i = e0; i < e1; i += 4) {
        int last = e1 - 1;
        int i1 = i + 1 > last ? last : i + 1;
        int i2 = i + 2 > last ? last : i + 2;
        int i3 = i + 3 > last ? last : i + 3;
        float m1 = (i + 1 < e1) ? 1.f : 0.f;
        float m2 = (i + 2 < e1) ? 1.f : 0.f;
        float m3 = (i + 3 < e1) ? 1.f : 0.f;
        int eA = csr[i],  eB = csr[i1], eC = csr[i2], eD = csr[i3];
        int sA = edge_index[eA], sB = edge_index[eB];
        int sC = edge_index[eC], sD = edge_index[eD];
        int rA = edge_type[eA], rB = edge_type[eB];
        int rC = edge_type[eC], rD = edge_type[eD];
        float pA = __expf(lrelu(asrc1[sA * NHEAD + h] + adst + s_ae[rA * NHEAD + h]));
        float pB = m1 * __expf(lrelu(asrc1[sB * NHEAD + h] + adst + s_ae[rB * NHEAD + h]));
        float pC = m2 * __expf(lrelu(asrc1[sC * NHEAD + h] + adst + s_ae[rC * NHEAD + h]));
        float pD = m3 * __expf(lrelu(asrc1[sD * NHEAD + h] + adst + s_ae[rD * NHEAD + h]));
        den += pA + pB + pC + pD;
        const ushort4 vA = *(const ushort4*)(h1b + (size_t)sA * HC + h * CDIM + cq);
        const ushort4 vB = *(const ushort4*)(h1b + (size_t)sB * HC + h * CDIM + cq);
        const ushort4 vC = *(const ushort4*)(h1b + (size_t)sC * HC + h * CDIM + cq);
        const ushort4 vD = *(const ushort4*)(h1b + (size_t)sD * HC + h * CDIM + cq);
        ax += pA * u2f(vA.x) + pB * u2f(vB.x) + pC * u2f(vC.x) + pD * u2f(vD.x);
        ay += pA * u2f(vA.y) + pB * u2f(vB.y) + pC * u2f(vC.y) + pD * u2f(vD.y);
        az += pA * u2f(vA.z) + pB * u2f(vB.z) + pC * u2f(vC.z) + pD * u2f(vD.z);
        aw += pA * u2f(vA.w) + pB * u2f(vB.w) + pC * u2f(vC.w) + pD * u2f(vD.w);
    }
    float inv = 0.25f / (den + 1e-16f);
    ax *= inv; ay *= inv; az *= inv; aw *= inv;
    ax += __shfl_xor(ax, 16); ax += __shfl_xor(ax, 32);
    ay += __shfl_xor(ay, 16); ay += __shfl_xor(ay, 32);
    az += __shfl_xor(az, 16); az += __shfl_xor(az, 32);
    aw += __shfl_xor(aw, 16); aw += __shfl_xor(aw, 32);
    if (lane < 16) {
        int g = batch[n];
        float* dst = s_pool + g * CDIM + cq;
        atomicAdd(dst + 0, eluf(ax + b1[cq + 0]));
        atomicAdd(dst + 1, eluf(ay + b1[cq + 1]));
        atomicAdd(dst + 2, eluf(az + b1[cq + 2]));
        atomicAdd(dst + 3, eluf(aw + b1[cq + 3]));
    }
}

// ---------------------------------------------------------------------------
// Classifier
// ---------------------------------------------------------------------------
__global__ __launch_bounds__(64) void k_cls(
    const float* __restrict__ s_pool, const int* __restrict__ cnt,
    const float* __restrict__ cw1, const float* __restrict__ cb1,
    const float* __restrict__ cw2, const float* __restrict__ cb2,
    float* __restrict__ out)
{
    int g = blockIdx.x, j = threadIdx.x;
    __shared__ float gm[CDIM];
    int c = cnt[g];
    float invc = 1.f / (float)(c > 1 ? c : 1);
    gm[j] = s_pool[g * CDIM + j] * invc;
    __syncthreads();
    float acc = cb1[j];
    #pragma unroll
    for (int k = 0; k < CDIM; k++) acc += gm[k] * cw1[k * CDIM + j];
    float hid = acc > 0.f ? acc : 0.f;
    float o0 = hid * cw2[j * 2 + 0];
    float o1 = hid * cw2[j * 2 + 1];
    #pragma unroll
    for (int d = 32; d >= 1; d >>= 1) {
        o0 += __shfl_xor(o0, d);
        o1 += __shfl_xor(o1, d);
    }
    if (j == 0) {
        out[g * 2 + 0] = o0 + cb2[0];
        out[g * 2 + 1] = o1 + cb2[1];
    }
}

// ---------------------------------------------------------------------------
// DIAGNOSTIC (fires only on fault)
// ---------------------------------------------------------------------------
__global__ void k_diag(int hostA, int wsMB, int hostB, int ran,
                       const int* __restrict__ offs, const int* __restrict__ csr,
                       const float* __restrict__ W1, float* __restrict__ out)
{
    if (threadIdx.x != 0 || blockIdx.x != 0) return;
    int A = hostA, B = hostB;
    if (ran) {
        if (offs[N_NODES] != N_EDGES) A |= 4;
        int impl = 0;
        for (int i = 0; i < 256; i++) {
            float v = W1[i];
            if (!(fabsf(v) < 100.f)) impl++;
        }
        if (impl > 10) A |= 8;
        int oob = 0;
        for (int i = 0; i < 1000; i++) {
            int c = csr[i];
            if (c < 0 || c >= N_EDGES) oob++;
        }
        B = oob;
    }
    if (B > 1023) B = 1023;
    if (A == 0 && B == 0) return;
    out[0] = (float)((A << 20) | (wsMB << 10) | B);
}

// ---------------------------------------------------------------------------
extern "C" void kernel_launch(void* const* d_in, const int* in_sizes, int n_in,
                              void* d_out, int out_size, void* d_ws, size_t ws_size,
                              hipStream_t stream) {
    static const int rsize[22] = {50000, 800000, 1600000, 50000, 512, 96,
                                  16384, 4096, 256, 256, 256, 64,
                                  16384, 4096, 256, 256, 256, 64,
                                  4096, 64, 128, 2};
    static const int cand_pos[3][22] = {
        {21,19,18,12,20,17,0,2,8,4,6,10,1,3,9,5,7,11,15,13,16,14},   // ASCII sorted (R7)
        {0,1,2,3,4,5,6,7,8,9,10,11,12,13,14,15,16,17,18,19,20,21},   // dict order
        {17,15,14,8,16,13,18,20,4,0,2,6,19,21,5,1,3,7,11,9,12,10},   // case-insens
    };
    int mc = -1;
    if (n_in == 22) {
        for (int c = 0; c < 3 && mc < 0; c++) {
            bool ok = true;
            for (int r = 0; r < 22; r++)
                if (in_sizes[cand_pos[c][r]] != rsize[r]) { ok = false; break; }
            if (ok) mc = c;
        }
    }
    int hostA = 0, hostB = 0;
    if (mc < 0) { hostA |= 1; hostB = (n_in != 22) ? (n_in < 1023 ? n_in : 1023) : 0; }

    char* ws = (char*)d_ws;
    size_t off = 0;
    auto alloc = [&](size_t b) { size_t r = off; off += (b + 255) & ~(size_t)255; return r; };
    int*   deg    = (int*)(ws + alloc(N_NODES * 4));
    int*   cnt    = (int*)(ws + alloc(N_GRAPH * 4));
    float* s_pool = (float*)(ws + alloc(N_GRAPH * CDIM * 4));
    size_t zero_bytes = off;
    int*   blksum = (int*)(ws + alloc(NBLK_SCAN * 4));
    int*   offs   = (int*)(ws + alloc((N_NODES + 1) * 4));
    int*   cursor = (int*)(ws + alloc(N_NODES * 4));
    int*   csr    = (int*)(ws + alloc(N_EDGES * 4));
    float* t_h0   = (float*)(ws + alloc(NTT * HC * 4));
    float* t_as0  = (float*)(ws + alloc(NTT * NHEAD * 4));
    float* t_ad0  = (float*)(ws + alloc(NTT * NHEAD * 4));
    float* t_ae0  = (float*)(ws + alloc(NRR * NHEAD * 4));
    float* t_ae1  = (float*)(ws + alloc(NRR * NHEAD * 4));
    u16*   w1b    = (u16*)(ws + alloc(CDIM * HC * 2));
    float* asrc1  = (float*)(ws + alloc((size_t)N_NODES * NHEAD * 4));
    float* adst1  = (float*)(ws + alloc((size_t)N_NODES * NHEAD * 4));
    u16*   h1b    = (u16*)(ws + alloc((size_t)N_NODES * HC * 2));

    if (mc >= 0 && off > ws_size) hostA |= 2;
    int wsMB = (int)(ws_size >> 20); if (wsMB > 1023) wsMB = 1023;
    int ran = (hostA == 0) ? 1 : 0;

    if (ran) {
        const int* P = cand_pos[mc];
        const int*   node_type  = (const int*)d_in[P[0]];
        const int*   edge_type  = (const int*)d_in[P[1]];
        const int*   edge_index = (const int*)d_in[P[2]];
        const int*   batch      = (const int*)d_in[P[3]];
        const float* node_emb   = (const float*)d_in[P[4]];
        const float* edge_emb   = (const float*)d_in[P[5]];
        const float* W0  = (const float*)d_in[P[6]];
        const float* We0 = (const float*)d_in[P[7]];
        const float* as0 = (const float*)d_in[P[8]];
        const float* ad0 = (const float*)d_in[P[9]];
        const float* ae0 = (const float*)d_in[P[10]];
        const float* b0  = (const float*)d_in[P[11]];
        const float* W1  = (const float*)d_in[P[12]];
        const float* We1 = (const float*)d_in[P[13]];
        const float* as1 = (const float*)d_in[P[14]];
        const float* ad1 = (const float*)d_in[P[15]];
        const float* ae1 = (const float*)d_in[P[16]];
        const float* b1  = (const float*)d_in[P[17]];
        const float* cw1 = (const float*)d_in[P[18]];
        const float* cb1 = (const float*)d_in[P[19]];
        const float* cw2 = (const float*)d_in[P[20]];
        const float* cb2 = (const float*)d_in[P[21]];

        int zero_elems = (int)(zero_bytes / 4);
        k_zero<<<(zero_elems + 255) / 256, 256, 0, stream>>>((float*)ws, zero_elems);
        k_tables<<<1, 256, 0, stream>>>(node_emb, edge_emb, W0, We0, as0, ad0, ae0,
                                        We1, ae1, W1,
                                        t_h0, t_as0, t_ad0, t_ae0, t_ae1, w1b);
        k_count<<<(N_EDGES + 255) / 256, 256, 0, stream>>>(edge_index, batch, deg, cnt);
        k_scan1<<<NBLK_SCAN, 256, 0, stream>>>(deg, blksum);
        k_scan2<<<1, 64, 0, stream>>>(blksum, offs);
        k_scan3<<<NBLK_SCAN, 256, 0, stream>>>(deg, blksum, offs, cursor);
        k_scatter<<<(N_EDGES + 255) / 256, 256, 0, stream>>>(edge_index, cursor, csr);
        k_fused<<<FB, 256, 0, stream>>>(
            node_type, edge_index, edge_type, offs, csr,
            t_h0, t_as0, t_ad0, t_ae0, b0, w1b, as1, ad1, h1b, asrc1, adst1);
        k_agg1<<<(N_NODES * 64) / 256, 256, 0, stream>>>(
            edge_index, edge_type, offs, csr, h1b, asrc1, adst1, t_ae1, b1, batch, s_pool);
        k_cls<<<N_GRAPH, 64, 0, stream>>>(s_pool, cnt, cw1, cb1, cw2, cb2, (float*)d_out);
        k_diag<<<1, 64, 0, stream>>>(0, wsMB, 0, 1, offs, csr, W1, (float*)d_out);
    } else {
        k_diag<<<1, 64, 0, stream>>>(hostA, wsMB, hostB, 0, nullptr, nullptr,
                                     nullptr, (float*)d_out);
    }
}

// Round 9
// 878.831 us; speedup vs baseline: 1.4380x; 1.1392x over previous
//
#include <hip/hip_runtime.h>
#include <hip/hip_bf16.h>

#define N_NODES 50000
#define N_EDGES 800000
#define N_GRAPH 64
#define NHEAD 4
#define CDIM 64
#define HC 256      // NHEAD*CDIM
#define NTT 8
#define NRR 6
#define EDIMM 16
#define SCAN_CHUNK 1024
#define NBLK_SCAN ((N_NODES + SCAN_CHUNK - 1) / SCAN_CHUNK)   // 49
#define FB 3125     // k_fused blocks; FB*4 waves * 4 groups = 50000 nodes

typedef unsigned short u16;

__device__ __forceinline__ float eluf(float v) { return v > 0.f ? v : expm1f(v); }
__device__ __forceinline__ float u2f(u16 u) {
    union { float f; unsigned int i; } c; c.i = ((unsigned int)u) << 16; return c.f;
}
__device__ __forceinline__ u16 f2u(float f) {
    union { float f; unsigned int i; } c; c.f = f;
    unsigned int i = c.i;
    return (u16)((i + 0x7FFFu + ((i >> 16) & 1u)) >> 16);
}
__device__ __forceinline__ float lrelu(float v) { return v > 0.f ? v : 0.2f * v; }

__global__ __launch_bounds__(256) void k_zero(float* __restrict__ p, int n)
{
    int i = blockIdx.x * 256 + threadIdx.x;
    if (i < n) p[i] = 0.f;
}

// ---------------------------------------------------------------------------
// Tiny tables + W1 -> bf16 conversion
// ---------------------------------------------------------------------------
__global__ __launch_bounds__(256) void k_tables(
    const float* __restrict__ node_emb, const float* __restrict__ edge_emb,
    const float* __restrict__ W0, const float* __restrict__ We0,
    const float* __restrict__ as0, const float* __restrict__ ad0,
    const float* __restrict__ ae0, const float* __restrict__ We1,
    const float* __restrict__ ae1, const float* __restrict__ W1,
    float* __restrict__ t_h0, float* __restrict__ t_as0,
    float* __restrict__ t_ad0, float* __restrict__ t_ae0,
    float* __restrict__ t_ae1, u16* __restrict__ w1b)
{
    __shared__ float s_h0[NTT * HC];
    __shared__ float s_he[NRR * HC];
    int tid = threadIdx.x;

    for (int i = tid; i < CDIM * HC; i += 256) w1b[i] = f2u(W1[i]);

    for (int t = 0; t < NTT; t++) {
        float acc = 0.f;
        #pragma unroll 8
        for (int k = 0; k < CDIM; k++)
            acc += node_emb[t * CDIM + k] * W0[k * HC + tid];
        s_h0[t * HC + tid] = acc;
        t_h0[t * HC + tid] = acc;
    }
    for (int r = 0; r < NRR; r++) {
        float acc = 0.f;
        #pragma unroll
        for (int k = 0; k < EDIMM; k++)
            acc += edge_emb[r * EDIMM + k] * We0[k * HC + tid];
        s_he[r * HC + tid] = acc;
    }
    __syncthreads();
    if (tid < NTT * NHEAD) {
        int t = tid >> 2, h = tid & 3;
        float a = 0.f, d = 0.f;
        for (int c = 0; c < CDIM; c++) {
            float hv = s_h0[t * HC + h * CDIM + c];
            a += hv * as0[h * CDIM + c];
            d += hv * ad0[h * CDIM + c];
        }
        t_as0[tid] = a;
        t_ad0[tid] = d;
    }
    if (tid < NRR * NHEAD) {
        int r = tid >> 2, h = tid & 3;
        float a = 0.f;
        for (int c = 0; c < CDIM; c++)
            a += s_he[r * HC + h * CDIM + c] * ae0[h * CDIM + c];
        t_ae0[tid] = a;
    }
    __syncthreads();
    for (int r = 0; r < NRR; r++) {
        float acc = 0.f;
        #pragma unroll
        for (int k = 0; k < EDIMM; k++)
            acc += edge_emb[r * EDIMM + k] * We1[k * HC + tid];
        s_he[r * HC + tid] = acc;
    }
    __syncthreads();
    if (tid < NRR * NHEAD) {
        int r = tid >> 2, h = tid & 3;
        float a = 0.f;
        for (int c = 0; c < CDIM; c++)
            a += s_he[r * HC + h * CDIM + c] * ae1[h * CDIM + c];
        t_ae1[tid] = a;
    }
}

// ---------------------------------------------------------------------------
// CSR build. Scatter packs src(16b) | edge_type(3b @16) | node_type[src](3b @19)
// so edge consumers need NO further indirection.
// ---------------------------------------------------------------------------
__global__ __launch_bounds__(256) void k_count(
    const int* __restrict__ edge_index, const int* __restrict__ batch,
    int* __restrict__ deg, int* __restrict__ cnt)
{
    int i = blockIdx.x * 256 + threadIdx.x;
    if (i < N_EDGES) atomicAdd(&deg[edge_index[N_EDGES + i]], 1);
    if (i < N_NODES) atomicAdd(&cnt[batch[i]], 1);
}

__global__ __launch_bounds__(256) void k_scan1(
    const int* __restrict__ deg, int* __restrict__ blksum)
{
    __shared__ int s[256];
    int b = blockIdx.x, tid = threadIdx.x;
    int base = b * SCAN_CHUNK + tid * 4;
    int t = 0;
    #pragma unroll
    for (int k = 0; k < 4; k++) { int i = base + k; if (i < N_NODES) t += deg[i]; }
    s[tid] = t;
    __syncthreads();
    for (int off = 128; off > 0; off >>= 1) {
        if (tid < off) s[tid] += s[tid + off];
        __syncthreads();
    }
    if (tid == 0) blksum[b] = s[0];
}

__global__ void k_scan2(int* __restrict__ blksum, int* __restrict__ offs)
{
    if (threadIdx.x == 0 && blockIdx.x == 0) {
        int acc = 0;
        for (int b = 0; b < NBLK_SCAN; b++) { int t = blksum[b]; blksum[b] = acc; acc += t; }
        offs[N_NODES] = acc;
    }
}

__global__ __launch_bounds__(256) void k_scan3(
    const int* __restrict__ deg, const int* __restrict__ blksum,
    int* __restrict__ offs, int* __restrict__ cursor)
{
    __shared__ int s[256];
    int b = blockIdx.x, tid = threadIdx.x;
    int base = b * SCAN_CHUNK + tid * 4;
    int d[4]; int t = 0;
    #pragma unroll
    for (int k = 0; k < 4; k++) {
        int i = base + k;
        d[k] = (i < N_NODES) ? deg[i] : 0;
        t += d[k];
    }
    s[tid] = t;
    __syncthreads();
    for (int off = 1; off < 256; off <<= 1) {
        int v = (tid >= off) ? s[tid - off] : 0;
        __syncthreads();
        s[tid] += v;
        __syncthreads();
    }
    int excl = blksum[b] + s[tid] - t;
    #pragma unroll
    for (int k = 0; k < 4; k++) {
        int i = base + k;
        if (i < N_NODES) { offs[i] = excl; cursor[i] = excl; }
        excl += d[k];
    }
}

__global__ __launch_bounds__(256) void k_scatter(
    const int* __restrict__ edge_index, const int* __restrict__ edge_type,
    const int* __restrict__ node_type, int* __restrict__ cursor,
    int* __restrict__ csrp)
{
    int e = blockIdx.x * 256 + threadIdx.x;
    if (e < N_EDGES) {
        int d  = edge_index[N_EDGES + e];
        int s  = edge_index[e];
        int et = edge_type[e];
        int ts = node_type[s];
        int pos = atomicAdd(&cursor[d], 1);
        csrp[pos] = s | (et << 16) | (ts << 19);
    }
}

// ---------------------------------------------------------------------------
// FUSED layer0 + (x1@W1) + attention dots. Edge loop reads ONLY the packed
// CSR stream (sequential, wave-uniform) + LDS tables -> VALU-bound.
// ---------------------------------------------------------------------------
__global__ __launch_bounds__(256) void k_fused(
    const int* __restrict__ node_type, const int* __restrict__ offs,
    const int* __restrict__ csrp,
    const float* __restrict__ t_h0, const float* __restrict__ t_as0,
    const float* __restrict__ t_ad0, const float* __restrict__ t_ae0,
    const float* __restrict__ b0, const u16* __restrict__ w1b,
    const float* __restrict__ as1, const float* __restrict__ ad1,
    u16* __restrict__ h1b, float* __restrict__ asrc1, float* __restrict__ adst1)
{
    __shared__ float s_h0[NTT * HC];                 // 8 KB
    __shared__ u16  s_W1[CDIM * HC];                 // 32 KB
    __shared__ float s_as[NTT * NHEAD], s_ad[NTT * NHEAD], s_ae[NRR * NHEAD];
    __shared__ float s_as1[HC], s_ad1[HC], s_b0[CDIM];
    __shared__ float xrow[4][CDIM];                  // 1 KB

    int tid = threadIdx.x;
    for (int i = tid; i < NTT * HC; i += 256) s_h0[i] = t_h0[i];
    {
        const uint4* src = (const uint4*)w1b;
        uint4* dst = (uint4*)s_W1;
        for (int i = tid; i < 2048; i += 256) dst[i] = src[i];
    }
    if (tid < NTT * NHEAD) { s_as[tid] = t_as0[tid]; s_ad[tid] = t_ad0[tid]; }
    if (tid < NRR * NHEAD) s_ae[tid] = t_ae0[tid];
    for (int i = tid; i < HC; i += 256) { s_as1[i] = as1[i]; s_ad1[i] = ad1[i]; }
    if (tid < CDIM) s_b0[tid] = b0[tid];
    __syncthreads();

    int lane = tid & 63;
    int wv = tid >> 6;
    int h = lane >> 4;
    int cq = (lane & 15) << 2;
    int c0 = lane << 2;

    for (int grp = 0; grp < 4; ++grp) {
        int n = (grp * FB + blockIdx.x) * 4 + wv;    // exact cover of [0,50000)

        int tn = node_type[n];
        float adst = s_ad[tn * NHEAD + h];
        int e0 = offs[n], e1 = offs[n + 1];
        float ax = 0.f, ay = 0.f, az = 0.f, aw = 0.f, den = 0.f;
        for (int i = e0; i < e1; i += 4) {
            int last = e1 - 1;
            int i1 = i + 1 > last ? last : i + 1;
            int i2 = i + 2 > last ? last : i + 2;
            int i3 = i + 3 > last ? last : i + 3;
            float m1 = (i + 1 < e1) ? 1.f : 0.f;
            float m2 = (i + 2 < e1) ? 1.f : 0.f;
            float m3 = (i + 3 < e1) ? 1.f : 0.f;
            int rA = csrp[i],  rB = csrp[i1], rC = csrp[i2], rD = csrp[i3];
            int tA = rA >> 19, tB = rB >> 19, tC = rC >> 19, tD = rD >> 19;
            int eA = (rA >> 16) & 7, eB = (rB >> 16) & 7;
            int eC = (rC >> 16) & 7, eD = (rD >> 16) & 7;
            float pA = __expf(lrelu(s_as[tA * NHEAD + h] + adst + s_ae[eA * NHEAD + h]));
            float pB = m1 * __expf(lrelu(s_as[tB * NHEAD + h] + adst + s_ae[eB * NHEAD + h]));
            float pC = m2 * __expf(lrelu(s_as[tC * NHEAD + h] + adst + s_ae[eC * NHEAD + h]));
            float pD = m3 * __expf(lrelu(s_as[tD * NHEAD + h] + adst + s_ae[eD * NHEAD + h]));
            den += pA + pB + pC + pD;
            const float4 vA = *(const float4*)(s_h0 + tA * HC + h * CDIM + cq);
            const float4 vB = *(const float4*)(s_h0 + tB * HC + h * CDIM + cq);
            const float4 vC = *(const float4*)(s_h0 + tC * HC + h * CDIM + cq);
            const float4 vD = *(const float4*)(s_h0 + tD * HC + h * CDIM + cq);
            ax += pA * vA.x + pB * vB.x + pC * vC.x + pD * vD.x;
            ay += pA * vA.y + pB * vB.y + pC * vC.y + pD * vD.y;
            az += pA * vA.z + pB * vB.z + pC * vC.z + pD * vD.z;
            aw += pA * vA.w + pB * vB.w + pC * vC.w + pD * vD.w;
        }
        float inv = 0.25f / (den + 1e-16f);
        ax *= inv; ay *= inv; az *= inv; aw *= inv;
        ax += __shfl_xor(ax, 16); ax += __shfl_xor(ax, 32);
        ay += __shfl_xor(ay, 16); ay += __shfl_xor(ay, 32);
        az += __shfl_xor(az, 16); az += __shfl_xor(az, 32);
        aw += __shfl_xor(aw, 16); aw += __shfl_xor(aw, 32);
        if (lane < 16) {
            xrow[wv][cq + 0] = eluf(ax + s_b0[cq + 0]);
            xrow[wv][cq + 1] = eluf(ay + s_b0[cq + 1]);
            xrow[wv][cq + 2] = eluf(az + s_b0[cq + 2]);
            xrow[wv][cq + 3] = eluf(aw + s_b0[cq + 3]);
        }
        __syncthreads();

        float a0 = 0.f, a1 = 0.f, a2 = 0.f, a3 = 0.f;
        #pragma unroll 8
        for (int k = 0; k < CDIM; k++) {
            float xk = xrow[wv][k];
            const ushort4 w = *(const ushort4*)(s_W1 + k * HC + c0);
            a0 += xk * u2f(w.x); a1 += xk * u2f(w.y);
            a2 += xk * u2f(w.z); a3 += xk * u2f(w.w);
        }
        ushort4 hv;
        hv.x = f2u(a0); hv.y = f2u(a1); hv.z = f2u(a2); hv.w = f2u(a3);
        *(ushort4*)(h1b + (size_t)n * HC + c0) = hv;

        float rs = a0 * s_as1[c0] + a1 * s_as1[c0 + 1] + a2 * s_as1[c0 + 2] + a3 * s_as1[c0 + 3];
        float rd = a0 * s_ad1[c0] + a1 * s_ad1[c0 + 1] + a2 * s_ad1[c0 + 2] + a3 * s_ad1[c0 + 3];
        #pragma unroll
        for (int d = 8; d >= 1; d >>= 1) {
            rs += __shfl_xor(rs, d);
            rd += __shfl_xor(rd, d);
        }
        int hh = lane >> 4;
        if ((lane & 15) == 0) {
            asrc1[n * NHEAD + hh] = rs;
            adst1[n * NHEAD + hh] = rd;
        }
        __syncthreads();   // xrow reused next grp
    }
}

// ---------------------------------------------------------------------------
// Layer 1 aggregation + ELU + mean-pool. Batch-8, depth-2 chain:
// csrp[i] -> (asrc1[s] || h1b row). 8 gathers in flight per wave.
// ---------------------------------------------------------------------------
__global__ __launch_bounds__(256) void k_agg1(
    const int* __restrict__ offs, const int* __restrict__ csrp,
    const u16* __restrict__ h1b, const float* __restrict__ asrc1,
    const float* __restrict__ adst1, const float* __restrict__ t_ae1,
    const float* __restrict__ b1, const int* __restrict__ batch,
    float* __restrict__ s_pool)
{
    __shared__ float s_ae[NRR * NHEAD];
    if (threadIdx.x < NRR * NHEAD) s_ae[threadIdx.x] = t_ae1[threadIdx.x];
    __syncthreads();

    int n = (blockIdx.x * 256 + threadIdx.x) >> 6;
    int lane = threadIdx.x & 63;
    int h = lane >> 4;
    int cq = (lane & 15) << 2;
    float adst = adst1[n * NHEAD + h];
    int e0 = offs[n], e1 = offs[n + 1];

    float ax = 0.f, ay = 0.f, az = 0.f, aw = 0.f, den = 0.f;
    for (int i = e0; i < e1; i += 8) {
        int last = e1 - 1;
        int idx[8];
        float m[8];
        #pragma unroll
        for (int k = 0; k < 8; k++) {
            int ik = i + k;
            idx[k] = ik > last ? last : ik;
            m[k] = (k == 0 || ik < e1) ? 1.f : 0.f;
        }
        int rec[8], s[8], et[8];
        #pragma unroll
        for (int k = 0; k < 8; k++) rec[k] = csrp[idx[k]];
        #pragma unroll
        for (int k = 0; k < 8; k++) { s[k] = rec[k] & 0xFFFF; et[k] = (rec[k] >> 16) & 7; }
        // issue all 16 gathers (8 asrc + 8 rows) before any use
        float asv[8];
        ushort4 hv[8];
        #pragma unroll
        for (int k = 0; k < 8; k++) asv[k] = asrc1[s[k] * NHEAD + h];
        #pragma unroll
        for (int k = 0; k < 8; k++)
            hv[k] = *(const ushort4*)(h1b + (size_t)s[k] * HC + h * CDIM + cq);
        #pragma unroll
        for (int k = 0; k < 8; k++) {
            float p = m[k] * __expf(lrelu(asv[k] + adst + s_ae[et[k] * NHEAD + h]));
            den += p;
            ax += p * u2f(hv[k].x);
            ay += p * u2f(hv[k].y);
            az += p * u2f(hv[k].z);
            aw += p * u2f(hv[k].w);
        }
    }
    float inv = 0.25f / (den + 1e-16f);
    ax *= inv; ay *= inv; az *= inv; aw *= inv;
    ax += __shfl_xor(ax, 16); ax += __shfl_xor(ax, 32);
    ay += __shfl_xor(ay, 16); ay += __shfl_xor(ay, 32);
    az += __shfl_xor(az, 16); az += __shfl_xor(az, 32);
    aw += __shfl_xor(aw, 16); aw += __shfl_xor(aw, 32);
    if (lane < 16) {
        int g = batch[n];
        float* dst = s_pool + g * CDIM + cq;
        atomicAdd(dst + 0, eluf(ax + b1[cq + 0]));
        atomicAdd(dst + 1, eluf(ay + b1[cq + 1]));
        atomicAdd(dst + 2, eluf(az + b1[cq + 2]));
        atomicAdd(dst + 3, eluf(aw + b1[cq + 3]));
    }
}

// ---------------------------------------------------------------------------
// Classifier
// ---------------------------------------------------------------------------
__global__ __launch_bounds__(64) void k_cls(
    const float* __restrict__ s_pool, const int* __restrict__ cnt,
    const float* __restrict__ cw1, const float* __restrict__ cb1,
    const float* __restrict__ cw2, const float* __restrict__ cb2,
    float* __restrict__ out)
{
    int g = blockIdx.x, j = threadIdx.x;
    __shared__ float gm[CDIM];
    int c = cnt[g];
    float invc = 1.f / (float)(c > 1 ? c : 1);
    gm[j] = s_pool[g * CDIM + j] * invc;
    __syncthreads();
    float acc = cb1[j];
    #pragma unroll
    for (int k = 0; k < CDIM; k++) acc += gm[k] * cw1[k * CDIM + j];
    float hid = acc > 0.f ? acc : 0.f;
    float o0 = hid * cw2[j * 2 + 0];
    float o1 = hid * cw2[j * 2 + 1];
    #pragma unroll
    for (int d = 32; d >= 1; d >>= 1) {
        o0 += __shfl_xor(o0, d);
        o1 += __shfl_xor(o1, d);
    }
    if (j == 0) {
        out[g * 2 + 0] = o0 + cb2[0];
        out[g * 2 + 1] = o1 + cb2[1];
    }
}

// ---------------------------------------------------------------------------
// DIAGNOSTIC (fires only on fault)
// ---------------------------------------------------------------------------
__global__ void k_diag(int hostA, int wsMB, int hostB, int ran,
                       const int* __restrict__ offs, const int* __restrict__ csrp,
                       const float* __restrict__ W1, float* __restrict__ out)
{
    if (threadIdx.x != 0 || blockIdx.x != 0) return;
    int A = hostA, B = hostB;
    if (ran) {
        if (offs[N_NODES] != N_EDGES) A |= 4;
        int impl = 0;
        for (int i = 0; i < 256; i++) {
            float v = W1[i];
            if (!(fabsf(v) < 100.f)) impl++;
        }
        if (impl > 10) A |= 8;
        int oob = 0;
        for (int i = 0; i < 1000; i++) {
            int r = csrp[i];
            int s = r & 0xFFFF;
            if (s >= N_NODES || (r >> 22) != 0 || r < 0) oob++;
        }
        B = oob;
    }
    if (B > 1023) B = 1023;
    if (A == 0 && B == 0) return;
    out[0] = (float)((A << 20) | (wsMB << 10) | B);
}

// ---------------------------------------------------------------------------
extern "C" void kernel_launch(void* const* d_in, const int* in_sizes, int n_in,
                              void* d_out, int out_size, void* d_ws, size_t ws_size,
                              hipStream_t stream) {
    static const int rsize[22] = {50000, 800000, 1600000, 50000, 512, 96,
                                  16384, 4096, 256, 256, 256, 64,
                                  16384, 4096, 256, 256, 256, 64,
                                  4096, 64, 128, 2};
    static const int cand_pos[3][22] = {
        {21,19,18,12,20,17,0,2,8,4,6,10,1,3,9,5,7,11,15,13,16,14},   // ASCII sorted (R7)
        {0,1,2,3,4,5,6,7,8,9,10,11,12,13,14,15,16,17,18,19,20,21},   // dict order
        {17,15,14,8,16,13,18,20,4,0,2,6,19,21,5,1,3,7,11,9,12,10},   // case-insens
    };
    int mc = -1;
    if (n_in == 22) {
        for (int c = 0; c < 3 && mc < 0; c++) {
            bool ok = true;
            for (int r = 0; r < 22; r++)
                if (in_sizes[cand_pos[c][r]] != rsize[r]) { ok = false; break; }
            if (ok) mc = c;
        }
    }
    int hostA = 0, hostB = 0;
    if (mc < 0) { hostA |= 1; hostB = (n_in != 22) ? (n_in < 1023 ? n_in : 1023) : 0; }

    char* ws = (char*)d_ws;
    size_t off = 0;
    auto alloc = [&](size_t b) { size_t r = off; off += (b + 255) & ~(size_t)255; return r; };
    int*   deg    = (int*)(ws + alloc(N_NODES * 4));
    int*   cnt    = (int*)(ws + alloc(N_GRAPH * 4));
    float* s_pool = (float*)(ws + alloc(N_GRAPH * CDIM * 4));
    size_t zero_bytes = off;
    int*   blksum = (int*)(ws + alloc(NBLK_SCAN * 4));
    int*   offs   = (int*)(ws + alloc((N_NODES + 1) * 4));
    int*   cursor = (int*)(ws + alloc(N_NODES * 4));
    int*   csrp   = (int*)(ws + alloc(N_EDGES * 4));
    float* t_h0   = (float*)(ws + alloc(NTT * HC * 4));
    float* t_as0  = (float*)(ws + alloc(NTT * NHEAD * 4));
    float* t_ad0  = (float*)(ws + alloc(NTT * NHEAD * 4));
    float* t_ae0  = (float*)(ws + alloc(NRR * NHEAD * 4));
    float* t_ae1  = (float*)(ws + alloc(NRR * NHEAD * 4));
    u16*   w1b    = (u16*)(ws + alloc(CDIM * HC * 2));
    float* asrc1  = (float*)(ws + alloc((size_t)N_NODES * NHEAD * 4));
    float* adst1  = (float*)(ws + alloc((size_t)N_NODES * NHEAD * 4));
    u16*   h1b    = (u16*)(ws + alloc((size_t)N_NODES * HC * 2));

    if (mc >= 0 && off > ws_size) hostA |= 2;
    int wsMB = (int)(ws_size >> 20); if (wsMB > 1023) wsMB = 1023;
    int ran = (hostA == 0) ? 1 : 0;

    if (ran) {
        const int* P = cand_pos[mc];
        const int*   node_type  = (const int*)d_in[P[0]];
        const int*   edge_type  = (const int*)d_in[P[1]];
        const int*   edge_index = (const int*)d_in[P[2]];
        const int*   batch      = (const int*)d_in[P[3]];
        const float* node_emb   = (const float*)d_in[P[4]];
        const float* edge_emb   = (const float*)d_in[P[5]];
        const float* W0  = (const float*)d_in[P[6]];
        const float* We0 = (const float*)d_in[P[7]];
        const float* as0 = (const float*)d_in[P[8]];
        const float* ad0 = (const float*)d_in[P[9]];
        const float* ae0 = (const float*)d_in[P[10]];
        const float* b0  = (const float*)d_in[P[11]];
        const float* W1  = (const float*)d_in[P[12]];
        const float* We1 = (const float*)d_in[P[13]];
        const float* as1 = (const float*)d_in[P[14]];
        const float* ad1 = (const float*)d_in[P[15]];
        const float* ae1 = (const float*)d_in[P[16]];
        const float* b1  = (const float*)d_in[P[17]];
        const float* cw1 = (const float*)d_in[P[18]];
        const float* cb1 = (const float*)d_in[P[19]];
        const float* cw2 = (const float*)d_in[P[20]];
        const float* cb2 = (const float*)d_in[P[21]];

        int zero_elems = (int)(zero_bytes / 4);
        k_zero<<<(zero_elems + 255) / 256, 256, 0, stream>>>((float*)ws, zero_elems);
        k_tables<<<1, 256, 0, stream>>>(node_emb, edge_emb, W0, We0, as0, ad0, ae0,
                                        We1, ae1, W1,
                                        t_h0, t_as0, t_ad0, t_ae0, t_ae1, w1b);
        k_count<<<(N_EDGES + 255) / 256, 256, 0, stream>>>(edge_index, batch, deg, cnt);
        k_scan1<<<NBLK_SCAN, 256, 0, stream>>>(deg, blksum);
        k_scan2<<<1, 64, 0, stream>>>(blksum, offs);
        k_scan3<<<NBLK_SCAN, 256, 0, stream>>>(deg, blksum, offs, cursor);
        k_scatter<<<(N_EDGES + 255) / 256, 256, 0, stream>>>(edge_index, edge_type,
                                                             node_type, cursor, csrp);
        k_fused<<<FB, 256, 0, stream>>>(
            node_type, offs, csrp,
            t_h0, t_as0, t_ad0, t_ae0, b0, w1b, as1, ad1, h1b, asrc1, adst1);
        k_agg1<<<(N_NODES * 64) / 256, 256, 0, stream>>>(
            offs, csrp, h1b, asrc1, adst1, t_ae1, b1, batch, s_pool);
        k_cls<<<N_GRAPH, 64, 0, stream>>>(s_pool, cnt, cw1, cb1, cw2, cb2, (float*)d_out);
        k_diag<<<1, 64, 0, stream>>>(0, wsMB, 0, 1, offs, csrp, W1, (float*)d_out);
    } else {
        k_diag<<<1, 64, 0, stream>>>(hostA, wsMB, hostB, 0, nullptr, nullptr,
                                     nullptr, (float*)d_out);
    }
}

// Round 10
// 674.815 us; speedup vs baseline: 1.8727x; 1.3023x over previous
//
#include <hip/hip_runtime.h>
#include <hip/hip_bf16.h>

#define N_NODES 50000
#define N_EDGES 800000
#define N_GRAPH 64
#define NHEAD 4
#define CDIM 64
#define HC 256      // NHEAD*CDIM
#define NTT 8
#define NRR 6
#define EDIMM 16
#define SCAN_CHUNK 1024
#define NBLK_SCAN ((N_NODES + SCAN_CHUNK - 1) / SCAN_CHUNK)   // 49
#define FB 3125     // k_fused blocks; FB*4 waves * 4 groups = 50000 nodes

typedef unsigned short u16;

__device__ __forceinline__ float eluf(float v) { return v > 0.f ? v : expm1f(v); }
__device__ __forceinline__ float u2f(u16 u) {
    union { float f; unsigned int i; } c; c.i = ((unsigned int)u) << 16; return c.f;
}
__device__ __forceinline__ u16 f2u(float f) {
    union { float f; unsigned int i; } c; c.f = f;
    unsigned int i = c.i;
    return (u16)((i + 0x7FFFu + ((i >> 16) & 1u)) >> 16);
}
__device__ __forceinline__ float lrelu(float v) { return v > 0.f ? v : 0.2f * v; }

__global__ __launch_bounds__(256) void k_zero(float* __restrict__ p, int n)
{
    int i = blockIdx.x * 256 + threadIdx.x;
    if (i < n) p[i] = 0.f;
}

// ---------------------------------------------------------------------------
// Tiny tables + W1 -> bf16 conversion
// ---------------------------------------------------------------------------
__global__ __launch_bounds__(256) void k_tables(
    const float* __restrict__ node_emb, const float* __restrict__ edge_emb,
    const float* __restrict__ W0, const float* __restrict__ We0,
    const float* __restrict__ as0, const float* __restrict__ ad0,
    const float* __restrict__ ae0, const float* __restrict__ We1,
    const float* __restrict__ ae1, const float* __restrict__ W1,
    float* __restrict__ t_h0, float* __restrict__ t_as0,
    float* __restrict__ t_ad0, float* __restrict__ t_ae0,
    float* __restrict__ t_ae1, u16* __restrict__ w1b)
{
    __shared__ float s_h0[NTT * HC];
    __shared__ float s_he[NRR * HC];
    int tid = threadIdx.x;

    for (int i = tid; i < CDIM * HC; i += 256) w1b[i] = f2u(W1[i]);

    for (int t = 0; t < NTT; t++) {
        float acc = 0.f;
        #pragma unroll 8
        for (int k = 0; k < CDIM; k++)
            acc += node_emb[t * CDIM + k] * W0[k * HC + tid];
        s_h0[t * HC + tid] = acc;
        t_h0[t * HC + tid] = acc;
    }
    for (int r = 0; r < NRR; r++) {
        float acc = 0.f;
        #pragma unroll
        for (int k = 0; k < EDIMM; k++)
            acc += edge_emb[r * EDIMM + k] * We0[k * HC + tid];
        s_he[r * HC + tid] = acc;
    }
    __syncthreads();
    if (tid < NTT * NHEAD) {
        int t = tid >> 2, h = tid & 3;
        float a = 0.f, d = 0.f;
        for (int c = 0; c < CDIM; c++) {
            float hv = s_h0[t * HC + h * CDIM + c];
            a += hv * as0[h * CDIM + c];
            d += hv * ad0[h * CDIM + c];
        }
        t_as0[tid] = a;
        t_ad0[tid] = d;
    }
    if (tid < NRR * NHEAD) {
        int r = tid >> 2, h = tid & 3;
        float a = 0.f;
        for (int c = 0; c < CDIM; c++)
            a += s_he[r * HC + h * CDIM + c] * ae0[h * CDIM + c];
        t_ae0[tid] = a;
    }
    __syncthreads();
    for (int r = 0; r < NRR; r++) {
        float acc = 0.f;
        #pragma unroll
        for (int k = 0; k < EDIMM; k++)
            acc += edge_emb[r * EDIMM + k] * We1[k * HC + tid];
        s_he[r * HC + tid] = acc;
    }
    __syncthreads();
    if (tid < NRR * NHEAD) {
        int r = tid >> 2, h = tid & 3;
        float a = 0.f;
        for (int c = 0; c < CDIM; c++)
            a += s_he[r * HC + h * CDIM + c] * ae1[h * CDIM + c];
        t_ae1[tid] = a;
    }
}

// ---------------------------------------------------------------------------
// CSR build (packed records: src | edge_type<<16 | node_type[src]<<19)
// ---------------------------------------------------------------------------
__global__ __launch_bounds__(256) void k_count(
    const int* __restrict__ edge_index, const int* __restrict__ batch,
    int* __restrict__ deg, int* __restrict__ cnt)
{
    int i = blockIdx.x * 256 + threadIdx.x;
    if (i < N_EDGES) atomicAdd(&deg[edge_index[N_EDGES + i]], 1);
    if (i < N_NODES) atomicAdd(&cnt[batch[i]], 1);
}

__global__ __launch_bounds__(256) void k_scan1(
    const int* __restrict__ deg, int* __restrict__ blksum)
{
    __shared__ int s[256];
    int b = blockIdx.x, tid = threadIdx.x;
    int base = b * SCAN_CHUNK + tid * 4;
    int t = 0;
    #pragma unroll
    for (int k = 0; k < 4; k++) { int i = base + k; if (i < N_NODES) t += deg[i]; }
    s[tid] = t;
    __syncthreads();
    for (int off = 128; off > 0; off >>= 1) {
        if (tid < off) s[tid] += s[tid + off];
        __syncthreads();
    }
    if (tid == 0) blksum[b] = s[0];
}

// also prefix-scans per-graph node counts (batch is sorted -> contiguous)
__global__ void k_scan2(int* __restrict__ blksum, int* __restrict__ offs,
                        const int* __restrict__ cnt, int* __restrict__ goffs)
{
    if (threadIdx.x == 0 && blockIdx.x == 0) {
        int acc = 0;
        for (int b = 0; b < NBLK_SCAN; b++) { int t = blksum[b]; blksum[b] = acc; acc += t; }
        offs[N_NODES] = acc;
        int a2 = 0;
        for (int g = 0; g < N_GRAPH; g++) { goffs[g] = a2; a2 += cnt[g]; }
        goffs[N_GRAPH] = a2;
    }
}

__global__ __launch_bounds__(256) void k_scan3(
    const int* __restrict__ deg, const int* __restrict__ blksum,
    int* __restrict__ offs, int* __restrict__ cursor)
{
    __shared__ int s[256];
    int b = blockIdx.x, tid = threadIdx.x;
    int base = b * SCAN_CHUNK + tid * 4;
    int d[4]; int t = 0;
    #pragma unroll
    for (int k = 0; k < 4; k++) {
        int i = base + k;
        d[k] = (i < N_NODES) ? deg[i] : 0;
        t += d[k];
    }
    s[tid] = t;
    __syncthreads();
    for (int off = 1; off < 256; off <<= 1) {
        int v = (tid >= off) ? s[tid - off] : 0;
        __syncthreads();
        s[tid] += v;
        __syncthreads();
    }
    int excl = blksum[b] + s[tid] - t;
    #pragma unroll
    for (int k = 0; k < 4; k++) {
        int i = base + k;
        if (i < N_NODES) { offs[i] = excl; cursor[i] = excl; }
        excl += d[k];
    }
}

__global__ __launch_bounds__(256) void k_scatter(
    const int* __restrict__ edge_index, const int* __restrict__ edge_type,
    const int* __restrict__ node_type, int* __restrict__ cursor,
    int* __restrict__ csrp)
{
    int e = blockIdx.x * 256 + threadIdx.x;
    if (e < N_EDGES) {
        int d  = edge_index[N_EDGES + e];
        int s  = edge_index[e];
        int et = edge_type[e];
        int ts = node_type[s];
        int pos = atomicAdd(&cursor[d], 1);
        csrp[pos] = s | (et << 16) | (ts << 19);
    }
}

// ---------------------------------------------------------------------------
// FUSED layer0 + (x1@W1) + attention dots.
// ---------------------------------------------------------------------------
__global__ __launch_bounds__(256) void k_fused(
    const int* __restrict__ node_type, const int* __restrict__ offs,
    const int* __restrict__ csrp,
    const float* __restrict__ t_h0, const float* __restrict__ t_as0,
    const float* __restrict__ t_ad0, const float* __restrict__ t_ae0,
    const float* __restrict__ b0, const u16* __restrict__ w1b,
    const float* __restrict__ as1, const float* __restrict__ ad1,
    u16* __restrict__ h1b, float* __restrict__ asrc1, float* __restrict__ adst1)
{
    __shared__ float s_h0[NTT * HC];                 // 8 KB
    __shared__ u16  s_W1[CDIM * HC];                 // 32 KB
    __shared__ float s_as[NTT * NHEAD], s_ad[NTT * NHEAD], s_ae[NRR * NHEAD];
    __shared__ float s_as1[HC], s_ad1[HC], s_b0[CDIM];
    __shared__ float xrow[4][CDIM];                  // 1 KB

    int tid = threadIdx.x;
    for (int i = tid; i < NTT * HC; i += 256) s_h0[i] = t_h0[i];
    {
        const uint4* src = (const uint4*)w1b;
        uint4* dst = (uint4*)s_W1;
        for (int i = tid; i < 2048; i += 256) dst[i] = src[i];
    }
    if (tid < NTT * NHEAD) { s_as[tid] = t_as0[tid]; s_ad[tid] = t_ad0[tid]; }
    if (tid < NRR * NHEAD) s_ae[tid] = t_ae0[tid];
    for (int i = tid; i < HC; i += 256) { s_as1[i] = as1[i]; s_ad1[i] = ad1[i]; }
    if (tid < CDIM) s_b0[tid] = b0[tid];
    __syncthreads();

    int lane = tid & 63;
    int wv = tid >> 6;
    int h = lane >> 4;
    int cq = (lane & 15) << 2;
    int c0 = lane << 2;

    for (int grp = 0; grp < 4; ++grp) {
        int n = (grp * FB + blockIdx.x) * 4 + wv;

        int tn = node_type[n];
        float adst = s_ad[tn * NHEAD + h];
        int e0 = offs[n], e1 = offs[n + 1];
        float ax = 0.f, ay = 0.f, az = 0.f, aw = 0.f, den = 0.f;
        for (int i = e0; i < e1; i += 4) {
            int last = e1 - 1;
            int i1 = i + 1 > last ? last : i + 1;
            int i2 = i + 2 > last ? last : i + 2;
            int i3 = i + 3 > last ? last : i + 3;
            float m1 = (i + 1 < e1) ? 1.f : 0.f;
            float m2 = (i + 2 < e1) ? 1.f : 0.f;
            float m3 = (i + 3 < e1) ? 1.f : 0.f;
            int rA = csrp[i],  rB = csrp[i1], rC = csrp[i2], rD = csrp[i3];
            int tA = rA >> 19, tB = rB >> 19, tC = rC >> 19, tD = rD >> 19;
            int eA = (rA >> 16) & 7, eB = (rB >> 16) & 7;
            int eC = (rC >> 16) & 7, eD = (rD >> 16) & 7;
            float pA = __expf(lrelu(s_as[tA * NHEAD + h] + adst + s_ae[eA * NHEAD + h]));
            float pB = m1 * __expf(lrelu(s_as[tB * NHEAD + h] + adst + s_ae[eB * NHEAD + h]));
            float pC = m2 * __expf(lrelu(s_as[tC * NHEAD + h] + adst + s_ae[eC * NHEAD + h]));
            float pD = m3 * __expf(lrelu(s_as[tD * NHEAD + h] + adst + s_ae[eD * NHEAD + h]));
            den += pA + pB + pC + pD;
            const float4 vA = *(const float4*)(s_h0 + tA * HC + h * CDIM + cq);
            const float4 vB = *(const float4*)(s_h0 + tB * HC + h * CDIM + cq);
            const float4 vC = *(const float4*)(s_h0 + tC * HC + h * CDIM + cq);
            const float4 vD = *(const float4*)(s_h0 + tD * HC + h * CDIM + cq);
            ax += pA * vA.x + pB * vB.x + pC * vC.x + pD * vD.x;
            ay += pA * vA.y + pB * vB.y + pC * vC.y + pD * vD.y;
            az += pA * vA.z + pB * vB.z + pC * vC.z + pD * vD.z;
            aw += pA * vA.w + pB * vB.w + pC * vC.w + pD * vD.w;
        }
        float inv = 0.25f / (den + 1e-16f);
        ax *= inv; ay *= inv; az *= inv; aw *= inv;
        ax += __shfl_xor(ax, 16); ax += __shfl_xor(ax, 32);
        ay += __shfl_xor(ay, 16); ay += __shfl_xor(ay, 32);
        az += __shfl_xor(az, 16); az += __shfl_xor(az, 32);
        aw += __shfl_xor(aw, 16); aw += __shfl_xor(aw, 32);
        if (lane < 16) {
            xrow[wv][cq + 0] = eluf(ax + s_b0[cq + 0]);
            xrow[wv][cq + 1] = eluf(ay + s_b0[cq + 1]);
            xrow[wv][cq + 2] = eluf(az + s_b0[cq + 2]);
            xrow[wv][cq + 3] = eluf(aw + s_b0[cq + 3]);
        }
        __syncthreads();

        float a0 = 0.f, a1 = 0.f, a2 = 0.f, a3 = 0.f;
        #pragma unroll 8
        for (int k = 0; k < CDIM; k++) {
            float xk = xrow[wv][k];
            const ushort4 w = *(const ushort4*)(s_W1 + k * HC + c0);
            a0 += xk * u2f(w.x); a1 += xk * u2f(w.y);
            a2 += xk * u2f(w.z); a3 += xk * u2f(w.w);
        }
        ushort4 hv;
        hv.x = f2u(a0); hv.y = f2u(a1); hv.z = f2u(a2); hv.w = f2u(a3);
        *(ushort4*)(h1b + (size_t)n * HC + c0) = hv;

        float rs = a0 * s_as1[c0] + a1 * s_as1[c0 + 1] + a2 * s_as1[c0 + 2] + a3 * s_as1[c0 + 3];
        float rd = a0 * s_ad1[c0] + a1 * s_ad1[c0 + 1] + a2 * s_ad1[c0 + 2] + a3 * s_ad1[c0 + 3];
        #pragma unroll
        for (int d = 8; d >= 1; d >>= 1) {
            rs += __shfl_xor(rs, d);
            rd += __shfl_xor(rd, d);
        }
        int hh = lane >> 4;
        if ((lane & 15) == 0) {
            asrc1[n * NHEAD + hh] = rs;
            adst1[n * NHEAD + hh] = rd;
        }
        __syncthreads();   // xrow reused next grp
    }
}

// ---------------------------------------------------------------------------
// Layer 1 aggregation + ELU. Writes per-node x2 row (coalesced stream,
// NO atomics — the atomic RMW writeback was R9's hidden 100+ us).
// ---------------------------------------------------------------------------
__global__ __launch_bounds__(256) void k_agg1(
    const int* __restrict__ offs, const int* __restrict__ csrp,
    const u16* __restrict__ h1b, const float* __restrict__ asrc1,
    const float* __restrict__ adst1, const float* __restrict__ t_ae1,
    const float* __restrict__ b1, float* __restrict__ x2)
{
    __shared__ float s_ae[NRR * NHEAD];
    if (threadIdx.x < NRR * NHEAD) s_ae[threadIdx.x] = t_ae1[threadIdx.x];
    __syncthreads();

    int n = (blockIdx.x * 256 + threadIdx.x) >> 6;
    int lane = threadIdx.x & 63;
    int h = lane >> 4;
    int cq = (lane & 15) << 2;
    float adst = adst1[n * NHEAD + h];
    int e0 = offs[n], e1 = offs[n + 1];

    float ax = 0.f, ay = 0.f, az = 0.f, aw = 0.f, den = 0.f;
    for (int i = e0; i < e1; i += 8) {
        int last = e1 - 1;
        int idx[8];
        float m[8];
        #pragma unroll
        for (int k = 0; k < 8; k++) {
            int ik = i + k;
            idx[k] = ik > last ? last : ik;
            m[k] = (k == 0 || ik < e1) ? 1.f : 0.f;
        }
        int rec[8], s[8], et[8];
        #pragma unroll
        for (int k = 0; k < 8; k++) rec[k] = csrp[idx[k]];
        #pragma unroll
        for (int k = 0; k < 8; k++) { s[k] = rec[k] & 0xFFFF; et[k] = (rec[k] >> 16) & 7; }
        float asv[8];
        ushort4 hv[8];
        #pragma unroll
        for (int k = 0; k < 8; k++) asv[k] = asrc1[s[k] * NHEAD + h];
        #pragma unroll
        for (int k = 0; k < 8; k++)
            hv[k] = *(const ushort4*)(h1b + (size_t)s[k] * HC + h * CDIM + cq);
        #pragma unroll
        for (int k = 0; k < 8; k++) {
            float p = m[k] * __expf(lrelu(asv[k] + adst + s_ae[et[k] * NHEAD + h]));
            den += p;
            ax += p * u2f(hv[k].x);
            ay += p * u2f(hv[k].y);
            az += p * u2f(hv[k].z);
            aw += p * u2f(hv[k].w);
        }
    }
    float inv = 0.25f / (den + 1e-16f);
    ax *= inv; ay *= inv; az *= inv; aw *= inv;
    ax += __shfl_xor(ax, 16); ax += __shfl_xor(ax, 32);
    ay += __shfl_xor(ay, 16); ay += __shfl_xor(ay, 32);
    az += __shfl_xor(az, 16); az += __shfl_xor(az, 32);
    aw += __shfl_xor(aw, 16); aw += __shfl_xor(aw, 32);
    if (lane < 16) {
        float4 o;
        o.x = eluf(ax + b1[cq + 0]);
        o.y = eluf(ay + b1[cq + 1]);
        o.z = eluf(az + b1[cq + 2]);
        o.w = eluf(aw + b1[cq + 3]);
        *(float4*)(x2 + (size_t)n * CDIM + cq) = o;
    }
}

// ---------------------------------------------------------------------------
// Mean-pool per graph: batch is sorted so graph g owns rows [goffs[g],goffs[g+1]).
// 64 blocks, zero atomics.
// ---------------------------------------------------------------------------
__global__ __launch_bounds__(256) void k_pool(
    const float* __restrict__ x2, const int* __restrict__ goffs,
    float* __restrict__ gm)
{
    __shared__ float part[4][CDIM];
    int g = blockIdx.x;
    int ch = threadIdx.x & 63, rg = threadIdx.x >> 6;
    int gs = goffs[g], ge = goffs[g + 1];
    float acc = 0.f;
    for (int r = gs + rg; r < ge; r += 4)
        acc += x2[(size_t)r * CDIM + ch];
    part[rg][ch] = acc;
    __syncthreads();
    if (threadIdx.x < CDIM) {
        float s = part[0][ch] + part[1][ch] + part[2][ch] + part[3][ch];
        int c = ge - gs;
        gm[g * CDIM + ch] = s / (float)(c > 1 ? c : 1);
    }
}

// ---------------------------------------------------------------------------
// Classifier: one wave per graph, reads pooled means.
// ---------------------------------------------------------------------------
__global__ __launch_bounds__(64) void k_cls(
    const float* __restrict__ gm, const float* __restrict__ cw1,
    const float* __restrict__ cb1, const float* __restrict__ cw2,
    const float* __restrict__ cb2, float* __restrict__ out)
{
    int g = blockIdx.x, j = threadIdx.x;
    __shared__ float gsh[CDIM];
    gsh[j] = gm[g * CDIM + j];
    __syncthreads();
    float acc = cb1[j];
    #pragma unroll
    for (int k = 0; k < CDIM; k++) acc += gsh[k] * cw1[k * CDIM + j];
    float hid = acc > 0.f ? acc : 0.f;
    float o0 = hid * cw2[j * 2 + 0];
    float o1 = hid * cw2[j * 2 + 1];
    #pragma unroll
    for (int d = 32; d >= 1; d >>= 1) {
        o0 += __shfl_xor(o0, d);
        o1 += __shfl_xor(o1, d);
    }
    if (j == 0) {
        out[g * 2 + 0] = o0 + cb2[0];
        out[g * 2 + 1] = o1 + cb2[1];
    }
}

// ---------------------------------------------------------------------------
// DIAGNOSTIC (parallelized; fires only on fault)
// ---------------------------------------------------------------------------
__global__ __launch_bounds__(256) void k_diag(
    int hostA, int wsMB, int hostB, int ran,
    const int* __restrict__ offs, const int* __restrict__ csrp,
    const float* __restrict__ W1, float* __restrict__ out)
{
    __shared__ int simpl, soob, sA;
    int tid = threadIdx.x;
    if (tid == 0) { simpl = 0; soob = 0; sA = hostA; }
    __syncthreads();
    if (ran) {
        if (tid == 0 && offs[N_NODES] != N_EDGES) atomicOr(&sA, 4);
        float v = W1[tid];
        if (!(fabsf(v) < 100.f)) atomicAdd(&simpl, 1);
        int r = csrp[tid];
        if ((r & 0xFFFF) >= N_NODES || (r >> 22) != 0 || r < 0) atomicAdd(&soob, 1);
    }
    __syncthreads();
    if (tid != 0) return;
    int A = sA, B = hostB;
    if (ran) {
        if (simpl > 10) A |= 8;
        B = soob;
    }
    if (B > 1023) B = 1023;
    if (A == 0 && B == 0) return;
    out[0] = (float)((A << 20) | (wsMB << 10) | B);
}

// ---------------------------------------------------------------------------
extern "C" void kernel_launch(void* const* d_in, const int* in_sizes, int n_in,
                              void* d_out, int out_size, void* d_ws, size_t ws_size,
                              hipStream_t stream) {
    static const int rsize[22] = {50000, 800000, 1600000, 50000, 512, 96,
                                  16384, 4096, 256, 256, 256, 64,
                                  16384, 4096, 256, 256, 256, 64,
                                  4096, 64, 128, 2};
    static const int cand_pos[3][22] = {
        {21,19,18,12,20,17,0,2,8,4,6,10,1,3,9,5,7,11,15,13,16,14},   // ASCII sorted (R7)
        {0,1,2,3,4,5,6,7,8,9,10,11,12,13,14,15,16,17,18,19,20,21},   // dict order
        {17,15,14,8,16,13,18,20,4,0,2,6,19,21,5,1,3,7,11,9,12,10},   // case-insens
    };
    int mc = -1;
    if (n_in == 22) {
        for (int c = 0; c < 3 && mc < 0; c++) {
            bool ok = true;
            for (int r = 0; r < 22; r++)
                if (in_sizes[cand_pos[c][r]] != rsize[r]) { ok = false; break; }
            if (ok) mc = c;
        }
    }
    int hostA = 0, hostB = 0;
    if (mc < 0) { hostA |= 1; hostB = (n_in != 22) ? (n_in < 1023 ? n_in : 1023) : 0; }

    char* ws = (char*)d_ws;
    size_t off = 0;
    auto alloc = [&](size_t b) { size_t r = off; off += (b + 255) & ~(size_t)255; return r; };
    int*   deg    = (int*)(ws + alloc(N_NODES * 4));
    int*   cnt    = (int*)(ws + alloc(N_GRAPH * 4));
    size_t zero_bytes = off;
    int*   blksum = (int*)(ws + alloc(NBLK_SCAN * 4));
    int*   offs   = (int*)(ws + alloc((N_NODES + 1) * 4));
    int*   cursor = (int*)(ws + alloc(N_NODES * 4));
    int*   csrp   = (int*)(ws + alloc(N_EDGES * 4));
    int*   goffs  = (int*)(ws + alloc((N_GRAPH + 1) * 4));
    float* t_h0   = (float*)(ws + alloc(NTT * HC * 4));
    float* t_as0  = (float*)(ws + alloc(NTT * NHEAD * 4));
    float* t_ad0  = (float*)(ws + alloc(NTT * NHEAD * 4));
    float* t_ae0  = (float*)(ws + alloc(NRR * NHEAD * 4));
    float* t_ae1  = (float*)(ws + alloc(NRR * NHEAD * 4));
    u16*   w1b    = (u16*)(ws + alloc(CDIM * HC * 2));
    float* asrc1  = (float*)(ws + alloc((size_t)N_NODES * NHEAD * 4));
    float* adst1  = (float*)(ws + alloc((size_t)N_NODES * NHEAD * 4));
    u16*   h1b    = (u16*)(ws + alloc((size_t)N_NODES * HC * 2));
    float* x2     = (float*)(ws + alloc((size_t)N_NODES * CDIM * 4));
    float* gm     = (float*)(ws + alloc(N_GRAPH * CDIM * 4));

    if (mc >= 0 && off > ws_size) hostA |= 2;
    int wsMB = (int)(ws_size >> 20); if (wsMB > 1023) wsMB = 1023;
    int ran = (hostA == 0) ? 1 : 0;

    if (ran) {
        const int* P = cand_pos[mc];
        const int*   node_type  = (const int*)d_in[P[0]];
        const int*   edge_type  = (const int*)d_in[P[1]];
        const int*   edge_index = (const int*)d_in[P[2]];
        const int*   batch      = (const int*)d_in[P[3]];
        const float* node_emb   = (const float*)d_in[P[4]];
        const float* edge_emb   = (const float*)d_in[P[5]];
        const float* W0  = (const float*)d_in[P[6]];
        const float* We0 = (const float*)d_in[P[7]];
        const float* as0 = (const float*)d_in[P[8]];
        const float* ad0 = (const float*)d_in[P[9]];
        const float* ae0 = (const float*)d_in[P[10]];
        const float* b0  = (const float*)d_in[P[11]];
        const float* W1  = (const float*)d_in[P[12]];
        const float* We1 = (const float*)d_in[P[13]];
        const float* as1 = (const float*)d_in[P[14]];
        const float* ad1 = (const float*)d_in[P[15]];
        const float* ae1 = (const float*)d_in[P[16]];
        const float* b1  = (const float*)d_in[P[17]];
        const float* cw1 = (const float*)d_in[P[18]];
        const float* cb1 = (const float*)d_in[P[19]];
        const float* cw2 = (const float*)d_in[P[20]];
        const float* cb2 = (const float*)d_in[P[21]];

        int zero_elems = (int)(zero_bytes / 4);
        k_zero<<<(zero_elems + 255) / 256, 256, 0, stream>>>((float*)ws, zero_elems);
        k_tables<<<1, 256, 0, stream>>>(node_emb, edge_emb, W0, We0, as0, ad0, ae0,
                                        We1, ae1, W1,
                                        t_h0, t_as0, t_ad0, t_ae0, t_ae1, w1b);
        k_count<<<(N_EDGES + 255) / 256, 256, 0, stream>>>(edge_index, batch, deg, cnt);
        k_scan1<<<NBLK_SCAN, 256, 0, stream>>>(deg, blksum);
        k_scan2<<<1, 64, 0, stream>>>(blksum, offs, cnt, goffs);
        k_scan3<<<NBLK_SCAN, 256, 0, stream>>>(deg, blksum, offs, cursor);
        k_scatter<<<(N_EDGES + 255) / 256, 256, 0, stream>>>(edge_index, edge_type,
                                                             node_type, cursor, csrp);
        k_fused<<<FB, 256, 0, stream>>>(
            node_type, offs, csrp,
            t_h0, t_as0, t_ad0, t_ae0, b0, w1b, as1, ad1, h1b, asrc1, adst1);
        k_agg1<<<(N_NODES * 64) / 256, 256, 0, stream>>>(
            offs, csrp, h1b, asrc1, adst1, t_ae1, b1, x2);
        k_pool<<<N_GRAPH, 256, 0, stream>>>(x2, goffs, gm);
        k_cls<<<N_GRAPH, 64, 0, stream>>>(gm, cw1, cb1, cw2, cb2, (float*)d_out);
        k_diag<<<1, 256, 0, stream>>>(0, wsMB, 0, 1, offs, csrp, W1, (float*)d_out);
    } else {
        k_diag<<<1, 256, 0, stream>>>(hostA, wsMB, hostB, 0, nullptr, nullptr,
                                      nullptr, (float*)d_out);
    }
}

// Round 11
// 444.238 us; speedup vs baseline: 2.8448x; 1.5190x over previous
//
#include <hip/hip_runtime.h>
#include <hip/hip_bf16.h>

#define N_NODES 50000
#define N_EDGES 800000
#define N_GRAPH 64
#define NHEAD 4
#define CDIM 64
#define HC 256      // NHEAD*CDIM
#define NTT 8
#define NRR 6
#define EDIMM 16
#define SCAN_CHUNK 1024
#define NBLK_SCAN ((N_NODES + SCAN_CHUNK - 1) / SCAN_CHUNK)   // 49
#define FB 3125     // k_fused blocks; FB*4 waves * 4 groups = 50000 nodes

typedef unsigned short u16;

__device__ __forceinline__ float eluf(float v) { return v > 0.f ? v : expm1f(v); }
__device__ __forceinline__ float u2f(u16 u) {
    union { float f; unsigned int i; } c; c.i = ((unsigned int)u) << 16; return c.f;
}
__device__ __forceinline__ u16 f2u(float f) {
    union { float f; unsigned int i; } c; c.f = f;
    unsigned int i = c.i;
    return (u16)((i + 0x7FFFu + ((i >> 16) & 1u)) >> 16);
}
__device__ __forceinline__ float lrelu(float v) { return v > 0.f ? v : 0.2f * v; }

__global__ __launch_bounds__(256) void k_zero(float* __restrict__ p, int n)
{
    int i = blockIdx.x * 256 + threadIdx.x;
    if (i < n) p[i] = 0.f;
}

// ---------------------------------------------------------------------------
// Tiny tables + W1 -> bf16 conversion
// ---------------------------------------------------------------------------
__global__ __launch_bounds__(256) void k_tables(
    const float* __restrict__ node_emb, const float* __restrict__ edge_emb,
    const float* __restrict__ W0, const float* __restrict__ We0,
    const float* __restrict__ as0, const float* __restrict__ ad0,
    const float* __restrict__ ae0, const float* __restrict__ We1,
    const float* __restrict__ ae1, const float* __restrict__ W1,
    float* __restrict__ t_h0, float* __restrict__ t_as0,
    float* __restrict__ t_ad0, float* __restrict__ t_ae0,
    float* __restrict__ t_ae1, u16* __restrict__ w1b)
{
    __shared__ float s_h0[NTT * HC];
    __shared__ float s_he[NRR * HC];
    int tid = threadIdx.x;

    for (int i = tid; i < CDIM * HC; i += 256) w1b[i] = f2u(W1[i]);

    for (int t = 0; t < NTT; t++) {
        float acc = 0.f;
        #pragma unroll 8
        for (int k = 0; k < CDIM; k++)
            acc += node_emb[t * CDIM + k] * W0[k * HC + tid];
        s_h0[t * HC + tid] = acc;
        t_h0[t * HC + tid] = acc;
    }
    for (int r = 0; r < NRR; r++) {
        float acc = 0.f;
        #pragma unroll
        for (int k = 0; k < EDIMM; k++)
            acc += edge_emb[r * EDIMM + k] * We0[k * HC + tid];
        s_he[r * HC + tid] = acc;
    }
    __syncthreads();
    if (tid < NTT * NHEAD) {
        int t = tid >> 2, h = tid & 3;
        float a = 0.f, d = 0.f;
        for (int c = 0; c < CDIM; c++) {
            float hv = s_h0[t * HC + h * CDIM + c];
            a += hv * as0[h * CDIM + c];
            d += hv * ad0[h * CDIM + c];
        }
        t_as0[tid] = a;
        t_ad0[tid] = d;
    }
    if (tid < NRR * NHEAD) {
        int r = tid >> 2, h = tid & 3;
        float a = 0.f;
        for (int c = 0; c < CDIM; c++)
            a += s_he[r * HC + h * CDIM + c] * ae0[h * CDIM + c];
        t_ae0[tid] = a;
    }
    __syncthreads();
    for (int r = 0; r < NRR; r++) {
        float acc = 0.f;
        #pragma unroll
        for (int k = 0; k < EDIMM; k++)
            acc += edge_emb[r * EDIMM + k] * We1[k * HC + tid];
        s_he[r * HC + tid] = acc;
    }
    __syncthreads();
    if (tid < NRR * NHEAD) {
        int r = tid >> 2, h = tid & 3;
        float a = 0.f;
        for (int c = 0; c < CDIM; c++)
            a += s_he[r * HC + h * CDIM + c] * ae1[h * CDIM + c];
        t_ae1[tid] = a;
    }
}

// ---------------------------------------------------------------------------
// Degree count: 4-way privatized (cuts per-line RMW serialization).
// NO cnt atomics (graph ranges come from k_goffs boundary detection).
// ---------------------------------------------------------------------------
__global__ __launch_bounds__(256) void k_count(
    const int* __restrict__ edge_index, int* __restrict__ deg4)
{
    int i = blockIdx.x * 256 + threadIdx.x;
    if (i < N_EDGES)
        atomicAdd(&deg4[(blockIdx.x & 3) * N_NODES + edge_index[N_EDGES + i]], 1);
}

// batch is sorted: goffs[g] = first node index with batch[i] >= g.
__global__ __launch_bounds__(256) void k_goffs(
    const int* __restrict__ batch, int* __restrict__ goffs)
{
    int i = blockIdx.x * 256 + threadIdx.x;
    if (i >= N_NODES) return;
    int bi = batch[i];
    int bp = (i == 0) ? -1 : batch[i - 1];
    for (int g = bp + 1; g <= bi; g++) goffs[g] = i;
    if (i == N_NODES - 1)
        for (int g = bi + 1; g <= N_GRAPH; g++) goffs[g] = N_NODES;
}

// merge deg4 -> deg (plain stores) + per-chunk sums
__global__ __launch_bounds__(256) void k_scan1(
    const int* __restrict__ deg4, int* __restrict__ deg, int* __restrict__ blksum)
{
    __shared__ int s[256];
    int b = blockIdx.x, tid = threadIdx.x;
    int base = b * SCAN_CHUNK + tid * 4;
    int t = 0;
    #pragma unroll
    for (int k = 0; k < 4; k++) {
        int i = base + k;
        if (i < N_NODES) {
            int d = deg4[i] + deg4[N_NODES + i] + deg4[2 * N_NODES + i]
                  + deg4[3 * N_NODES + i];
            deg[i] = d;
            t += d;
        }
    }
    s[tid] = t;
    __syncthreads();
    for (int off = 128; off > 0; off >>= 1) {
        if (tid < off) s[tid] += s[tid + off];
        __syncthreads();
    }
    if (tid == 0) blksum[b] = s[0];
}

__global__ void k_scan2(int* __restrict__ blksum, int* __restrict__ offs)
{
    if (threadIdx.x == 0 && blockIdx.x == 0) {
        int acc = 0;
        for (int b = 0; b < NBLK_SCAN; b++) { int t = blksum[b]; blksum[b] = acc; acc += t; }
        offs[N_NODES] = acc;
    }
}

__global__ __launch_bounds__(256) void k_scan3(
    const int* __restrict__ deg, const int* __restrict__ blksum,
    int* __restrict__ offs, int* __restrict__ cursor)
{
    __shared__ int s[256];
    int b = blockIdx.x, tid = threadIdx.x;
    int base = b * SCAN_CHUNK + tid * 4;
    int d[4]; int t = 0;
    #pragma unroll
    for (int k = 0; k < 4; k++) {
        int i = base + k;
        d[k] = (i < N_NODES) ? deg[i] : 0;
        t += d[k];
    }
    s[tid] = t;
    __syncthreads();
    for (int off = 1; off < 256; off <<= 1) {
        int v = (tid >= off) ? s[tid - off] : 0;
        __syncthreads();
        s[tid] += v;
        __syncthreads();
    }
    int excl = blksum[b] + s[tid] - t;
    #pragma unroll
    for (int k = 0; k < 4; k++) {
        int i = base + k;
        if (i < N_NODES) { offs[i] = excl; cursor[i] = excl; }
        excl += d[k];
    }
}

__global__ __launch_bounds__(256) void k_scatter(
    const int* __restrict__ edge_index, const int* __restrict__ edge_type,
    const int* __restrict__ node_type, int* __restrict__ cursor,
    int* __restrict__ csrp)
{
    int e = blockIdx.x * 256 + threadIdx.x;
    if (e < N_EDGES) {
        int d  = edge_index[N_EDGES + e];
        int s  = edge_index[e];
        int et = edge_type[e];
        int ts = node_type[s];
        int pos = atomicAdd(&cursor[d], 1);
        csrp[pos] = s | (et << 16) | (ts << 19);
    }
}

// ---------------------------------------------------------------------------
// FUSED layer0 + (x1@W1) + attention dots.
// ---------------------------------------------------------------------------
__global__ __launch_bounds__(256) void k_fused(
    const int* __restrict__ node_type, const int* __restrict__ offs,
    const int* __restrict__ csrp,
    const float* __restrict__ t_h0, const float* __restrict__ t_as0,
    const float* __restrict__ t_ad0, const float* __restrict__ t_ae0,
    const float* __restrict__ b0, const u16* __restrict__ w1b,
    const float* __restrict__ as1, const float* __restrict__ ad1,
    u16* __restrict__ h1b, float* __restrict__ asrc1, float* __restrict__ adst1)
{
    __shared__ float s_h0[NTT * HC];                 // 8 KB
    __shared__ u16  s_W1[CDIM * HC];                 // 32 KB
    __shared__ float s_as[NTT * NHEAD], s_ad[NTT * NHEAD], s_ae[NRR * NHEAD];
    __shared__ float s_as1[HC], s_ad1[HC], s_b0[CDIM];
    __shared__ float xrow[4][CDIM];                  // 1 KB

    int tid = threadIdx.x;
    for (int i = tid; i < NTT * HC; i += 256) s_h0[i] = t_h0[i];
    {
        const uint4* src = (const uint4*)w1b;
        uint4* dst = (uint4*)s_W1;
        for (int i = tid; i < 2048; i += 256) dst[i] = src[i];
    }
    if (tid < NTT * NHEAD) { s_as[tid] = t_as0[tid]; s_ad[tid] = t_ad0[tid]; }
    if (tid < NRR * NHEAD) s_ae[tid] = t_ae0[tid];
    for (int i = tid; i < HC; i += 256) { s_as1[i] = as1[i]; s_ad1[i] = ad1[i]; }
    if (tid < CDIM) s_b0[tid] = b0[tid];
    __syncthreads();

    int lane = tid & 63;
    int wv = tid >> 6;
    int h = lane >> 4;
    int cq = (lane & 15) << 2;
    int c0 = lane << 2;

    for (int grp = 0; grp < 4; ++grp) {
        int n = (grp * FB + blockIdx.x) * 4 + wv;

        int tn = node_type[n];
        float adst = s_ad[tn * NHEAD + h];
        int e0 = offs[n], e1 = offs[n + 1];
        float ax = 0.f, ay = 0.f, az = 0.f, aw = 0.f, den = 0.f;
        for (int i = e0; i < e1; i += 4) {
            int last = e1 - 1;
            int i1 = i + 1 > last ? last : i + 1;
            int i2 = i + 2 > last ? last : i + 2;
            int i3 = i + 3 > last ? last : i + 3;
            float m1 = (i + 1 < e1) ? 1.f : 0.f;
            float m2 = (i + 2 < e1) ? 1.f : 0.f;
            float m3 = (i + 3 < e1) ? 1.f : 0.f;
            int rA = csrp[i],  rB = csrp[i1], rC = csrp[i2], rD = csrp[i3];
            int tA = rA >> 19, tB = rB >> 19, tC = rC >> 19, tD = rD >> 19;
            int eA = (rA >> 16) & 7, eB = (rB >> 16) & 7;
            int eC = (rC >> 16) & 7, eD = (rD >> 16) & 7;
            float pA = __expf(lrelu(s_as[tA * NHEAD + h] + adst + s_ae[eA * NHEAD + h]));
            float pB = m1 * __expf(lrelu(s_as[tB * NHEAD + h] + adst + s_ae[eB * NHEAD + h]));
            float pC = m2 * __expf(lrelu(s_as[tC * NHEAD + h] + adst + s_ae[eC * NHEAD + h]));
            float pD = m3 * __expf(lrelu(s_as[tD * NHEAD + h] + adst + s_ae[eD * NHEAD + h]));
            den += pA + pB + pC + pD;
            const float4 vA = *(const float4*)(s_h0 + tA * HC + h * CDIM + cq);
            const float4 vB = *(const float4*)(s_h0 + tB * HC + h * CDIM + cq);
            const float4 vC = *(const float4*)(s_h0 + tC * HC + h * CDIM + cq);
            const float4 vD = *(const float4*)(s_h0 + tD * HC + h * CDIM + cq);
            ax += pA * vA.x + pB * vB.x + pC * vC.x + pD * vD.x;
            ay += pA * vA.y + pB * vB.y + pC * vC.y + pD * vD.y;
            az += pA * vA.z + pB * vB.z + pC * vC.z + pD * vD.z;
            aw += pA * vA.w + pB * vB.w + pC * vC.w + pD * vD.w;
        }
        float inv = 0.25f / (den + 1e-16f);
        ax *= inv; ay *= inv; az *= inv; aw *= inv;
        ax += __shfl_xor(ax, 16); ax += __shfl_xor(ax, 32);
        ay += __shfl_xor(ay, 16); ay += __shfl_xor(ay, 32);
        az += __shfl_xor(az, 16); az += __shfl_xor(az, 32);
        aw += __shfl_xor(aw, 16); aw += __shfl_xor(aw, 32);
        if (lane < 16) {
            xrow[wv][cq + 0] = eluf(ax + s_b0[cq + 0]);
            xrow[wv][cq + 1] = eluf(ay + s_b0[cq + 1]);
            xrow[wv][cq + 2] = eluf(az + s_b0[cq + 2]);
            xrow[wv][cq + 3] = eluf(aw + s_b0[cq + 3]);
        }
        __syncthreads();

        float a0 = 0.f, a1 = 0.f, a2 = 0.f, a3 = 0.f;
        #pragma unroll 8
        for (int k = 0; k < CDIM; k++) {
            float xk = xrow[wv][k];
            const ushort4 w = *(const ushort4*)(s_W1 + k * HC + c0);
            a0 += xk * u2f(w.x); a1 += xk * u2f(w.y);
            a2 += xk * u2f(w.z); a3 += xk * u2f(w.w);
        }
        ushort4 hv;
        hv.x = f2u(a0); hv.y = f2u(a1); hv.z = f2u(a2); hv.w = f2u(a3);
        *(ushort4*)(h1b + (size_t)n * HC + c0) = hv;

        float rs = a0 * s_as1[c0] + a1 * s_as1[c0 + 1] + a2 * s_as1[c0 + 2] + a3 * s_as1[c0 + 3];
        float rd = a0 * s_ad1[c0] + a1 * s_ad1[c0 + 1] + a2 * s_ad1[c0 + 2] + a3 * s_ad1[c0 + 3];
        #pragma unroll
        for (int d = 8; d >= 1; d >>= 1) {
            rs += __shfl_xor(rs, d);
            rd += __shfl_xor(rd, d);
        }
        int hh = lane >> 4;
        if ((lane & 15) == 0) {
            asrc1[n * NHEAD + hh] = rs;
            adst1[n * NHEAD + hh] = rd;
        }
        __syncthreads();   // xrow reused next grp
    }
}

// ---------------------------------------------------------------------------
// Layer 1 aggregation + ELU -> coalesced x2 stream (no atomics).
// ---------------------------------------------------------------------------
__global__ __launch_bounds__(256) void k_agg1(
    const int* __restrict__ offs, const int* __restrict__ csrp,
    const u16* __restrict__ h1b, const float* __restrict__ asrc1,
    const float* __restrict__ adst1, const float* __restrict__ t_ae1,
    const float* __restrict__ b1, float* __restrict__ x2)
{
    __shared__ float s_ae[NRR * NHEAD];
    if (threadIdx.x < NRR * NHEAD) s_ae[threadIdx.x] = t_ae1[threadIdx.x];
    __syncthreads();

    int n = (blockIdx.x * 256 + threadIdx.x) >> 6;
    int lane = threadIdx.x & 63;
    int h = lane >> 4;
    int cq = (lane & 15) << 2;
    float adst = adst1[n * NHEAD + h];
    int e0 = offs[n], e1 = offs[n + 1];

    float ax = 0.f, ay = 0.f, az = 0.f, aw = 0.f, den = 0.f;
    for (int i = e0; i < e1; i += 8) {
        int last = e1 - 1;
        int idx[8];
        float m[8];
        #pragma unroll
        for (int k = 0; k < 8; k++) {
            int ik = i + k;
            idx[k] = ik > last ? last : ik;
            m[k] = (k == 0 || ik < e1) ? 1.f : 0.f;
        }
        int rec[8], s[8], et[8];
        #pragma unroll
        for (int k = 0; k < 8; k++) rec[k] = csrp[idx[k]];
        #pragma unroll
        for (int k = 0; k < 8; k++) { s[k] = rec[k] & 0xFFFF; et[k] = (rec[k] >> 16) & 7; }
        float asv[8];
        ushort4 hv[8];
        #pragma unroll
        for (int k = 0; k < 8; k++) asv[k] = asrc1[s[k] * NHEAD + h];
        #pragma unroll
        for (int k = 0; k < 8; k++)
            hv[k] = *(const ushort4*)(h1b + (size_t)s[k] * HC + h * CDIM + cq);
        #pragma unroll
        for (int k = 0; k < 8; k++) {
            float p = m[k] * __expf(lrelu(asv[k] + adst + s_ae[et[k] * NHEAD + h]));
            den += p;
            ax += p * u2f(hv[k].x);
            ay += p * u2f(hv[k].y);
            az += p * u2f(hv[k].z);
            aw += p * u2f(hv[k].w);
        }
    }
    float inv = 0.25f / (den + 1e-16f);
    ax *= inv; ay *= inv; az *= inv; aw *= inv;
    ax += __shfl_xor(ax, 16); ax += __shfl_xor(ax, 32);
    ay += __shfl_xor(ay, 16); ay += __shfl_xor(ay, 32);
    az += __shfl_xor(az, 16); az += __shfl_xor(az, 32);
    aw += __shfl_xor(aw, 16); aw += __shfl_xor(aw, 32);
    if (lane < 16) {
        float4 o;
        o.x = eluf(ax + b1[cq + 0]);
        o.y = eluf(ay + b1[cq + 1]);
        o.z = eluf(az + b1[cq + 2]);
        o.w = eluf(aw + b1[cq + 3]);
        *(float4*)(x2 + (size_t)n * CDIM + cq) = o;
    }
}

// ---------------------------------------------------------------------------
// Mean-pool per graph (contiguous ranges, zero atomics)
// ---------------------------------------------------------------------------
__global__ __launch_bounds__(256) void k_pool(
    const float* __restrict__ x2, const int* __restrict__ goffs,
    float* __restrict__ gm)
{
    __shared__ float part[4][CDIM];
    int g = blockIdx.x;
    int ch = threadIdx.x & 63, rg = threadIdx.x >> 6;
    int gs = goffs[g], ge = goffs[g + 1];
    float acc = 0.f;
    for (int r = gs + rg; r < ge; r += 4)
        acc += x2[(size_t)r * CDIM + ch];
    part[rg][ch] = acc;
    __syncthreads();
    if (threadIdx.x < CDIM) {
        float s = part[0][ch] + part[1][ch] + part[2][ch] + part[3][ch];
        int c = ge - gs;
        gm[g * CDIM + ch] = s / (float)(c > 1 ? c : 1);
    }
}

// ---------------------------------------------------------------------------
// Classifier
// ---------------------------------------------------------------------------
__global__ __launch_bounds__(64) void k_cls(
    const float* __restrict__ gm, const float* __restrict__ cw1,
    const float* __restrict__ cb1, const float* __restrict__ cw2,
    const float* __restrict__ cb2, float* __restrict__ out)
{
    int g = blockIdx.x, j = threadIdx.x;
    __shared__ float gsh[CDIM];
    gsh[j] = gm[g * CDIM + j];
    __syncthreads();
    float acc = cb1[j];
    #pragma unroll
    for (int k = 0; k < CDIM; k++) acc += gsh[k] * cw1[k * CDIM + j];
    float hid = acc > 0.f ? acc : 0.f;
    float o0 = hid * cw2[j * 2 + 0];
    float o1 = hid * cw2[j * 2 + 1];
    #pragma unroll
    for (int d = 32; d >= 1; d >>= 1) {
        o0 += __shfl_xor(o0, d);
        o1 += __shfl_xor(o1, d);
    }
    if (j == 0) {
        out[g * 2 + 0] = o0 + cb2[0];
        out[g * 2 + 1] = o1 + cb2[1];
    }
}

// ---------------------------------------------------------------------------
// DIAGNOSTIC (fires only on fault)
// ---------------------------------------------------------------------------
__global__ __launch_bounds__(256) void k_diag(
    int hostA, int wsMB, int hostB, int ran,
    const int* __restrict__ offs, const int* __restrict__ csrp,
    const float* __restrict__ W1, float* __restrict__ out)
{
    __shared__ int simpl, soob, sA;
    int tid = threadIdx.x;
    if (tid == 0) { simpl = 0; soob = 0; sA = hostA; }
    __syncthreads();
    if (ran) {
        if (tid == 0 && offs[N_NODES] != N_EDGES) atomicOr(&sA, 4);
        float v = W1[tid];
        if (!(fabsf(v) < 100.f)) atomicAdd(&simpl, 1);
        int r = csrp[tid];
        if ((r & 0xFFFF) >= N_NODES || (r >> 22) != 0 || r < 0) atomicAdd(&soob, 1);
    }
    __syncthreads();
    if (tid != 0) return;
    int A = sA, B = hostB;
    if (ran) {
        if (simpl > 10) A |= 8;
        B = soob;
    }
    if (B > 1023) B = 1023;
    if (A == 0 && B == 0) return;
    out[0] = (float)((A << 20) | (wsMB << 10) | B);
}

// ---------------------------------------------------------------------------
extern "C" void kernel_launch(void* const* d_in, const int* in_sizes, int n_in,
                              void* d_out, int out_size, void* d_ws, size_t ws_size,
                              hipStream_t stream) {
    static const int rsize[22] = {50000, 800000, 1600000, 50000, 512, 96,
                                  16384, 4096, 256, 256, 256, 64,
                                  16384, 4096, 256, 256, 256, 64,
                                  4096, 64, 128, 2};
    static const int cand_pos[3][22] = {
        {21,19,18,12,20,17,0,2,8,4,6,10,1,3,9,5,7,11,15,13,16,14},   // ASCII sorted (R7)
        {0,1,2,3,4,5,6,7,8,9,10,11,12,13,14,15,16,17,18,19,20,21},   // dict order
        {17,15,14,8,16,13,18,20,4,0,2,6,19,21,5,1,3,7,11,9,12,10},   // case-insens
    };
    int mc = -1;
    if (n_in == 22) {
        for (int c = 0; c < 3 && mc < 0; c++) {
            bool ok = true;
            for (int r = 0; r < 22; r++)
                if (in_sizes[cand_pos[c][r]] != rsize[r]) { ok = false; break; }
            if (ok) mc = c;
        }
    }
    int hostA = 0, hostB = 0;
    if (mc < 0) { hostA |= 1; hostB = (n_in != 22) ? (n_in < 1023 ? n_in : 1023) : 0; }

    char* ws = (char*)d_ws;
    size_t off = 0;
    auto alloc = [&](size_t b) { size_t r = off; off += (b + 255) & ~(size_t)255; return r; };
    int*   deg4   = (int*)(ws + alloc((size_t)4 * N_NODES * 4));   // zeroed
    size_t zero_bytes = off;
    int*   deg    = (int*)(ws + alloc(N_NODES * 4));
    int*   blksum = (int*)(ws + alloc(NBLK_SCAN * 4));
    int*   offs   = (int*)(ws + alloc((N_NODES + 1) * 4));
    int*   cursor = (int*)(ws + alloc(N_NODES * 4));
    int*   csrp   = (int*)(ws + alloc(N_EDGES * 4));
    int*   goffs  = (int*)(ws + alloc((N_GRAPH + 1) * 4));
    float* t_h0   = (float*)(ws + alloc(NTT * HC * 4));
    float* t_as0  = (float*)(ws + alloc(NTT * NHEAD * 4));
    float* t_ad0  = (float*)(ws + alloc(NTT * NHEAD * 4));
    float* t_ae0  = (float*)(ws + alloc(NRR * NHEAD * 4));
    float* t_ae1  = (float*)(ws + alloc(NRR * NHEAD * 4));
    u16*   w1b    = (u16*)(ws + alloc(CDIM * HC * 2));
    float* asrc1  = (float*)(ws + alloc((size_t)N_NODES * NHEAD * 4));
    float* adst1  = (float*)(ws + alloc((size_t)N_NODES * NHEAD * 4));
    u16*   h1b    = (u16*)(ws + alloc((size_t)N_NODES * HC * 2));
    float* x2     = (float*)(ws + alloc((size_t)N_NODES * CDIM * 4));
    float* gm     = (float*)(ws + alloc(N_GRAPH * CDIM * 4));

    if (mc >= 0 && off > ws_size) hostA |= 2;
    int wsMB = (int)(ws_size >> 20); if (wsMB > 1023) wsMB = 1023;
    int ran = (hostA == 0) ? 1 : 0;

    if (ran) {
        const int* P = cand_pos[mc];
        const int*   node_type  = (const int*)d_in[P[0]];
        const int*   edge_type  = (const int*)d_in[P[1]];
        const int*   edge_index = (const int*)d_in[P[2]];
        const int*   batch      = (const int*)d_in[P[3]];
        const float* node_emb   = (const float*)d_in[P[4]];
        const float* edge_emb   = (const float*)d_in[P[5]];
        const float* W0  = (const float*)d_in[P[6]];
        const float* We0 = (const float*)d_in[P[7]];
        const float* as0 = (const float*)d_in[P[8]];
        const float* ad0 = (const float*)d_in[P[9]];
        const float* ae0 = (const float*)d_in[P[10]];
        const float* b0  = (const float*)d_in[P[11]];
        const float* W1  = (const float*)d_in[P[12]];
        const float* We1 = (const float*)d_in[P[13]];
        const float* as1 = (const float*)d_in[P[14]];
        const float* ad1 = (const float*)d_in[P[15]];
        const float* ae1 = (const float*)d_in[P[16]];
        const float* b1  = (const float*)d_in[P[17]];
        const float* cw1 = (const float*)d_in[P[18]];
        const float* cb1 = (const float*)d_in[P[19]];
        const float* cw2 = (const float*)d_in[P[20]];
        const float* cb2 = (const float*)d_in[P[21]];

        int zero_elems = (int)(zero_bytes / 4);
        k_zero<<<(zero_elems + 255) / 256, 256, 0, stream>>>((float*)ws, zero_elems);
        k_tables<<<1, 256, 0, stream>>>(node_emb, edge_emb, W0, We0, as0, ad0, ae0,
                                        We1, ae1, W1,
                                        t_h0, t_as0, t_ad0, t_ae0, t_ae1, w1b);
        k_count<<<(N_EDGES + 255) / 256, 256, 0, stream>>>(edge_index, deg4);
        k_goffs<<<(N_NODES + 255) / 256, 256, 0, stream>>>(batch, goffs);
        k_scan1<<<NBLK_SCAN, 256, 0, stream>>>(deg4, deg, blksum);
        k_scan2<<<1, 64, 0, stream>>>(blksum, offs);
        k_scan3<<<NBLK_SCAN, 256, 0, stream>>>(deg, blksum, offs, cursor);
        k_scatter<<<(N_EDGES + 255) / 256, 256, 0, stream>>>(edge_index, edge_type,
                                                             node_type, cursor, csrp);
        k_fused<<<FB, 256, 0, stream>>>(
            node_type, offs, csrp,
            t_h0, t_as0, t_ad0, t_ae0, b0, w1b, as1, ad1, h1b, asrc1, adst1);
        k_agg1<<<(N_NODES * 64) / 256, 256, 0, stream>>>(
            offs, csrp, h1b, asrc1, adst1, t_ae1, b1, x2);
        k_pool<<<N_GRAPH, 256, 0, stream>>>(x2, goffs, gm);
        k_cls<<<N_GRAPH, 64, 0, stream>>>(gm, cw1, cb1, cw2, cb2, (float*)d_out);
        k_diag<<<1, 256, 0, stream>>>(0, wsMB, 0, 1, offs, csrp, W1, (float*)d_out);
    } else {
        k_diag<<<1, 256, 0, stream>>>(hostA, wsMB, hostB, 0, nullptr, nullptr,
                                      nullptr, (float*)d_out);
    }
}

// Round 12
// 428.502 us; speedup vs baseline: 2.9492x; 1.0367x over previous
//
#include <hip/hip_runtime.h>
#include <hip/hip_bf16.h>

#define N_NODES 50000
#define N_EDGES 800000
#define N_GRAPH 64
#define NHEAD 4
#define CDIM 64
#define HC 256      // NHEAD*CDIM
#define NTT 8
#define NRR 6
#define EDIMM 16
#define SCAN_CHUNK 1024
#define NBLK_SCAN ((N_NODES + SCAN_CHUNK - 1) / SCAN_CHUNK)   // 49

typedef unsigned short u16;

__device__ __forceinline__ float eluf(float v) { return v > 0.f ? v : expm1f(v); }
__device__ __forceinline__ float u2f(u16 u) {
    union { float f; unsigned int i; } c; c.i = ((unsigned int)u) << 16; return c.f;
}
__device__ __forceinline__ u16 f2u(float f) {
    union { float f; unsigned int i; } c; c.f = f;
    unsigned int i = c.i;
    return (u16)((i + 0x7FFFu + ((i >> 16) & 1u)) >> 16);
}
__device__ __forceinline__ float lrelu(float v) { return v > 0.f ? v : 0.2f * v; }

__global__ __launch_bounds__(256) void k_zero(float* __restrict__ p, int n)
{
    int i = blockIdx.x * 256 + threadIdx.x;
    if (i < n) p[i] = 0.f;
}

// ---------------------------------------------------------------------------
// Tiny tables (W1 stays fp32 now — k_gemm1 preloads it into registers)
// ---------------------------------------------------------------------------
__global__ __launch_bounds__(256) void k_tables(
    const float* __restrict__ node_emb, const float* __restrict__ edge_emb,
    const float* __restrict__ W0, const float* __restrict__ We0,
    const float* __restrict__ as0, const float* __restrict__ ad0,
    const float* __restrict__ ae0, const float* __restrict__ We1,
    const float* __restrict__ ae1,
    float* __restrict__ t_h0, float* __restrict__ t_as0,
    float* __restrict__ t_ad0, float* __restrict__ t_ae0,
    float* __restrict__ t_ae1)
{
    __shared__ float s_h0[NTT * HC];
    __shared__ float s_he[NRR * HC];
    int tid = threadIdx.x;

    for (int t = 0; t < NTT; t++) {
        float acc = 0.f;
        #pragma unroll 8
        for (int k = 0; k < CDIM; k++)
            acc += node_emb[t * CDIM + k] * W0[k * HC + tid];
        s_h0[t * HC + tid] = acc;
        t_h0[t * HC + tid] = acc;
    }
    for (int r = 0; r < NRR; r++) {
        float acc = 0.f;
        #pragma unroll
        for (int k = 0; k < EDIMM; k++)
            acc += edge_emb[r * EDIMM + k] * We0[k * HC + tid];
        s_he[r * HC + tid] = acc;
    }
    __syncthreads();
    if (tid < NTT * NHEAD) {
        int t = tid >> 2, h = tid & 3;
        float a = 0.f, d = 0.f;
        for (int c = 0; c < CDIM; c++) {
            float hv = s_h0[t * HC + h * CDIM + c];
            a += hv * as0[h * CDIM + c];
            d += hv * ad0[h * CDIM + c];
        }
        t_as0[tid] = a;
        t_ad0[tid] = d;
    }
    if (tid < NRR * NHEAD) {
        int r = tid >> 2, h = tid & 3;
        float a = 0.f;
        for (int c = 0; c < CDIM; c++)
            a += s_he[r * HC + h * CDIM + c] * ae0[h * CDIM + c];
        t_ae0[tid] = a;
    }
    __syncthreads();
    for (int r = 0; r < NRR; r++) {
        float acc = 0.f;
        #pragma unroll
        for (int k = 0; k < EDIMM; k++)
            acc += edge_emb[r * EDIMM + k] * We1[k * HC + tid];
        s_he[r * HC + tid] = acc;
    }
    __syncthreads();
    if (tid < NRR * NHEAD) {
        int r = tid >> 2, h = tid & 3;
        float a = 0.f;
        for (int c = 0; c < CDIM; c++)
            a += s_he[r * HC + h * CDIM + c] * ae1[h * CDIM + c];
        t_ae1[tid] = a;
    }
}

// ---------------------------------------------------------------------------
// Degree count (4-way privatized) + graph ranges via boundary detection
// ---------------------------------------------------------------------------
__global__ __launch_bounds__(256) void k_count(
    const int* __restrict__ edge_index, int* __restrict__ deg4)
{
    int i = blockIdx.x * 256 + threadIdx.x;
    if (i < N_EDGES)
        atomicAdd(&deg4[(blockIdx.x & 3) * N_NODES + edge_index[N_EDGES + i]], 1);
}

__global__ __launch_bounds__(256) void k_goffs(
    const int* __restrict__ batch, int* __restrict__ goffs)
{
    int i = blockIdx.x * 256 + threadIdx.x;
    if (i >= N_NODES) return;
    int bi = batch[i];
    int bp = (i == 0) ? -1 : batch[i - 1];
    for (int g = bp + 1; g <= bi; g++) goffs[g] = i;
    if (i == N_NODES - 1)
        for (int g = bi + 1; g <= N_GRAPH; g++) goffs[g] = N_NODES;
}

__global__ __launch_bounds__(256) void k_scan1(
    const int* __restrict__ deg4, int* __restrict__ deg, int* __restrict__ blksum)
{
    __shared__ int s[256];
    int b = blockIdx.x, tid = threadIdx.x;
    int base = b * SCAN_CHUNK + tid * 4;
    int t = 0;
    #pragma unroll
    for (int k = 0; k < 4; k++) {
        int i = base + k;
        if (i < N_NODES) {
            int d = deg4[i] + deg4[N_NODES + i] + deg4[2 * N_NODES + i]
                  + deg4[3 * N_NODES + i];
            deg[i] = d;
            t += d;
        }
    }
    s[tid] = t;
    __syncthreads();
    for (int off = 128; off > 0; off >>= 1) {
        if (tid < off) s[tid] += s[tid + off];
        __syncthreads();
    }
    if (tid == 0) blksum[b] = s[0];
}

__global__ void k_scan2(int* __restrict__ blksum, int* __restrict__ offs)
{
    if (threadIdx.x == 0 && blockIdx.x == 0) {
        int acc = 0;
        for (int b = 0; b < NBLK_SCAN; b++) { int t = blksum[b]; blksum[b] = acc; acc += t; }
        offs[N_NODES] = acc;
    }
}

__global__ __launch_bounds__(256) void k_scan3(
    const int* __restrict__ deg, const int* __restrict__ blksum,
    int* __restrict__ offs, int* __restrict__ cursor)
{
    __shared__ int s[256];
    int b = blockIdx.x, tid = threadIdx.x;
    int base = b * SCAN_CHUNK + tid * 4;
    int d[4]; int t = 0;
    #pragma unroll
    for (int k = 0; k < 4; k++) {
        int i = base + k;
        d[k] = (i < N_NODES) ? deg[i] : 0;
        t += d[k];
    }
    s[tid] = t;
    __syncthreads();
    for (int off = 1; off < 256; off <<= 1) {
        int v = (tid >= off) ? s[tid - off] : 0;
        __syncthreads();
        s[tid] += v;
        __syncthreads();
    }
    int excl = blksum[b] + s[tid] - t;
    #pragma unroll
    for (int k = 0; k < 4; k++) {
        int i = base + k;
        if (i < N_NODES) { offs[i] = excl; cursor[i] = excl; }
        excl += d[k];
    }
}

__global__ __launch_bounds__(256) void k_scatter(
    const int* __restrict__ edge_index, const int* __restrict__ edge_type,
    const int* __restrict__ node_type, int* __restrict__ cursor,
    int* __restrict__ csrp)
{
    int e = blockIdx.x * 256 + threadIdx.x;
    if (e < N_EDGES) {
        int d  = edge_index[N_EDGES + e];
        int s  = edge_index[e];
        int et = edge_type[e];
        int ts = node_type[s];
        int pos = atomicAdd(&cursor[d], 1);
        csrp[pos] = s | (et << 16) | (ts << 19);
    }
}

// ---------------------------------------------------------------------------
// Layer-0 edge phase only: one wave per node, ~9 KB LDS (high occupancy).
// Writes x1 f32 (12.8 MB round-trip is cheap; the GEMM reads it back).
// ---------------------------------------------------------------------------
__global__ __launch_bounds__(256) void k_layer0(
    const int* __restrict__ node_type, const int* __restrict__ offs,
    const int* __restrict__ csrp,
    const float* __restrict__ t_h0, const float* __restrict__ t_as0,
    const float* __restrict__ t_ad0, const float* __restrict__ t_ae0,
    const float* __restrict__ b0, float* __restrict__ x1)
{
    __shared__ float s_h0[NTT * HC];                 // 8 KB
    __shared__ float s_as[NTT * NHEAD], s_ad[NTT * NHEAD], s_ae[NRR * NHEAD];
    __shared__ float s_b0[CDIM];

    int tid = threadIdx.x;
    for (int i = tid; i < NTT * HC; i += 256) s_h0[i] = t_h0[i];
    if (tid < NTT * NHEAD) { s_as[tid] = t_as0[tid]; s_ad[tid] = t_ad0[tid]; }
    if (tid < NRR * NHEAD) s_ae[tid] = t_ae0[tid];
    if (tid < CDIM) s_b0[tid] = b0[tid];
    __syncthreads();

    int n = (blockIdx.x * 256 + tid) >> 6;           // 12500 blocks, exact cover
    int lane = tid & 63;
    int h = lane >> 4;
    int cq = (lane & 15) << 2;

    int tn = node_type[n];
    float adst = s_ad[tn * NHEAD + h];
    int e0 = offs[n], e1 = offs[n + 1];
    float ax = 0.f, ay = 0.f, az = 0.f, aw = 0.f, den = 0.f;
    for (int i = e0; i < e1; i += 4) {
        int last = e1 - 1;
        int i1 = i + 1 > last ? last : i + 1;
        int i2 = i + 2 > last ? last : i + 2;
        int i3 = i + 3 > last ? last : i + 3;
        float m1 = (i + 1 < e1) ? 1.f : 0.f;
        float m2 = (i + 2 < e1) ? 1.f : 0.f;
        float m3 = (i + 3 < e1) ? 1.f : 0.f;
        int rA = csrp[i],  rB = csrp[i1], rC = csrp[i2], rD = csrp[i3];
        int tA = rA >> 19, tB = rB >> 19, tC = rC >> 19, tD = rD >> 19;
        int eA = (rA >> 16) & 7, eB = (rB >> 16) & 7;
        int eC = (rC >> 16) & 7, eD = (rD >> 16) & 7;
        float pA = __expf(lrelu(s_as[tA * NHEAD + h] + adst + s_ae[eA * NHEAD + h]));
        float pB = m1 * __expf(lrelu(s_as[tB * NHEAD + h] + adst + s_ae[eB * NHEAD + h]));
        float pC = m2 * __expf(lrelu(s_as[tC * NHEAD + h] + adst + s_ae[eC * NHEAD + h]));
        float pD = m3 * __expf(lrelu(s_as[tD * NHEAD + h] + adst + s_ae[eD * NHEAD + h]));
        den += pA + pB + pC + pD;
        const float4 vA = *(const float4*)(s_h0 + tA * HC + h * CDIM + cq);
        const float4 vB = *(const float4*)(s_h0 + tB * HC + h * CDIM + cq);
        const float4 vC = *(const float4*)(s_h0 + tC * HC + h * CDIM + cq);
        const float4 vD = *(const float4*)(s_h0 + tD * HC + h * CDIM + cq);
        ax += pA * vA.x + pB * vB.x + pC * vC.x + pD * vD.x;
        ay += pA * vA.y + pB * vB.y + pC * vC.y + pD * vD.y;
        az += pA * vA.z + pB * vB.z + pC * vC.z + pD * vD.z;
        aw += pA * vA.w + pB * vB.w + pC * vC.w + pD * vD.w;
    }
    float inv = 0.25f / (den + 1e-16f);
    ax *= inv; ay *= inv; az *= inv; aw *= inv;
    ax += __shfl_xor(ax, 16); ax += __shfl_xor(ax, 32);
    ay += __shfl_xor(ay, 16); ay += __shfl_xor(ay, 32);
    az += __shfl_xor(az, 16); az += __shfl_xor(az, 32);
    aw += __shfl_xor(aw, 16); aw += __shfl_xor(aw, 32);
    if (lane < 16) {
        float4 o;
        o.x = eluf(ax + s_b0[cq + 0]);
        o.y = eluf(ay + s_b0[cq + 1]);
        o.z = eluf(az + s_b0[cq + 2]);
        o.w = eluf(aw + s_b0[cq + 3]);
        *(float4*)(x1 + (size_t)n * CDIM + cq) = o;
    }
}

// ---------------------------------------------------------------------------
// h1 = x1 @ W1 + per-head dots. Thread owns column tid, W1 column in f32
// registers (zero converts in inner loop). Wave w == head w. (R7-verified.)
// ---------------------------------------------------------------------------
__global__ __launch_bounds__(256) void k_gemm1(
    const float* __restrict__ x1, const float* __restrict__ W1,
    const float* __restrict__ as1, const float* __restrict__ ad1,
    u16* __restrict__ h1b, float* __restrict__ asrc1, float* __restrict__ adst1)
{
    int tid = threadIdx.x;
    float Wcol[CDIM];
    #pragma unroll
    for (int k = 0; k < CDIM; k++) Wcol[k] = W1[k * HC + tid];
    float a_s = as1[tid];
    float a_d = ad1[tid];

    __shared__ float xs[32][CDIM];
    int n0 = blockIdx.x * 32;
    for (int i = tid; i < 32 * CDIM; i += 256) {
        int nn = n0 + (i >> 6);
        xs[i >> 6][i & 63] = (nn < N_NODES) ? x1[(size_t)nn * CDIM + (i & 63)] : 0.f;
    }
    __syncthreads();

    int wv = tid >> 6;
    int lane = tid & 63;
    for (int j = 0; j < 32; j++) {
        int n = n0 + j;
        if (n >= N_NODES) break;   // block-uniform
        float acc = 0.f;
        #pragma unroll
        for (int k = 0; k < CDIM; k++) acc += xs[j][k] * Wcol[k];
        h1b[(size_t)n * HC + tid] = f2u(acc);
        float rs = acc * a_s, rd = acc * a_d;
        #pragma unroll
        for (int d = 32; d >= 1; d >>= 1) {
            rs += __shfl_xor(rs, d);
            rd += __shfl_xor(rd, d);
        }
        if (lane == 0) {
            asrc1[n * NHEAD + wv] = rs;
            adst1[n * NHEAD + wv] = rd;
        }
    }
}

// ---------------------------------------------------------------------------
// Layer 1 aggregation + ELU -> coalesced x2 stream (no atomics).
// ---------------------------------------------------------------------------
__global__ __launch_bounds__(256) void k_agg1(
    const int* __restrict__ offs, const int* __restrict__ csrp,
    const u16* __restrict__ h1b, const float* __restrict__ asrc1,
    const float* __restrict__ adst1, const float* __restrict__ t_ae1,
    const float* __restrict__ b1, float* __restrict__ x2)
{
    __shared__ float s_ae[NRR * NHEAD];
    if (threadIdx.x < NRR * NHEAD) s_ae[threadIdx.x] = t_ae1[threadIdx.x];
    __syncthreads();

    int n = (blockIdx.x * 256 + threadIdx.x) >> 6;
    int lane = threadIdx.x & 63;
    int h = lane >> 4;
    int cq = (lane & 15) << 2;
    float adst = adst1[n * NHEAD + h];
    int e0 = offs[n], e1 = offs[n + 1];

    float ax = 0.f, ay = 0.f, az = 0.f, aw = 0.f, den = 0.f;
    for (int i = e0; i < e1; i += 8) {
        int last = e1 - 1;
        int idx[8];
        float m[8];
        #pragma unroll
        for (int k = 0; k < 8; k++) {
            int ik = i + k;
            idx[k] = ik > last ? last : ik;
            m[k] = (k == 0 || ik < e1) ? 1.f : 0.f;
        }
        int rec[8], s[8], et[8];
        #pragma unroll
        for (int k = 0; k < 8; k++) rec[k] = csrp[idx[k]];
        #pragma unroll
        for (int k = 0; k < 8; k++) { s[k] = rec[k] & 0xFFFF; et[k] = (rec[k] >> 16) & 7; }
        float asv[8];
        ushort4 hv[8];
        #pragma unroll
        for (int k = 0; k < 8; k++) asv[k] = asrc1[s[k] * NHEAD + h];
        #pragma unroll
        for (int k = 0; k < 8; k++)
            hv[k] = *(const ushort4*)(h1b + (size_t)s[k] * HC + h * CDIM + cq);
        #pragma unroll
        for (int k = 0; k < 8; k++) {
            float p = m[k] * __expf(lrelu(asv[k] + adst + s_ae[et[k] * NHEAD + h]));
            den += p;
            ax += p * u2f(hv[k].x);
            ay += p * u2f(hv[k].y);
            az += p * u2f(hv[k].z);
            aw += p * u2f(hv[k].w);
        }
    }
    float inv = 0.25f / (den + 1e-16f);
    ax *= inv; ay *= inv; az *= inv; aw *= inv;
    ax += __shfl_xor(ax, 16); ax += __shfl_xor(ax, 32);
    ay += __shfl_xor(ay, 16); ay += __shfl_xor(ay, 32);
    az += __shfl_xor(az, 16); az += __shfl_xor(az, 32);
    aw += __shfl_xor(aw, 16); aw += __shfl_xor(aw, 32);
    if (lane < 16) {
        float4 o;
        o.x = eluf(ax + b1[cq + 0]);
        o.y = eluf(ay + b1[cq + 1]);
        o.z = eluf(az + b1[cq + 2]);
        o.w = eluf(aw + b1[cq + 3]);
        *(float4*)(x2 + (size_t)n * CDIM + cq) = o;
    }
}

// ---------------------------------------------------------------------------
// Mean-pool per graph (contiguous ranges, zero atomics)
// ---------------------------------------------------------------------------
__global__ __launch_bounds__(256) void k_pool(
    const float* __restrict__ x2, const int* __restrict__ goffs,
    float* __restrict__ gm)
{
    __shared__ float part[4][CDIM];
    int g = blockIdx.x;
    int ch = threadIdx.x & 63, rg = threadIdx.x >> 6;
    int gs = goffs[g], ge = goffs[g + 1];
    float acc = 0.f;
    for (int r = gs + rg; r < ge; r += 4)
        acc += x2[(size_t)r * CDIM + ch];
    part[rg][ch] = acc;
    __syncthreads();
    if (threadIdx.x < CDIM) {
        float s = part[0][ch] + part[1][ch] + part[2][ch] + part[3][ch];
        int c = ge - gs;
        gm[g * CDIM + ch] = s / (float)(c > 1 ? c : 1);
    }
}

// ---------------------------------------------------------------------------
// Classifier
// ---------------------------------------------------------------------------
__global__ __launch_bounds__(64) void k_cls(
    const float* __restrict__ gm, const float* __restrict__ cw1,
    const float* __restrict__ cb1, const float* __restrict__ cw2,
    const float* __restrict__ cb2, float* __restrict__ out)
{
    int g = blockIdx.x, j = threadIdx.x;
    __shared__ float gsh[CDIM];
    gsh[j] = gm[g * CDIM + j];
    __syncthreads();
    float acc = cb1[j];
    #pragma unroll
    for (int k = 0; k < CDIM; k++) acc += gsh[k] * cw1[k * CDIM + j];
    float hid = acc > 0.f ? acc : 0.f;
    float o0 = hid * cw2[j * 2 + 0];
    float o1 = hid * cw2[j * 2 + 1];
    #pragma unroll
    for (int d = 32; d >= 1; d >>= 1) {
        o0 += __shfl_xor(o0, d);
        o1 += __shfl_xor(o1, d);
    }
    if (j == 0) {
        out[g * 2 + 0] = o0 + cb2[0];
        out[g * 2 + 1] = o1 + cb2[1];
    }
}

// ---------------------------------------------------------------------------
// DIAGNOSTIC (fires only on fault)
// ---------------------------------------------------------------------------
__global__ __launch_bounds__(256) void k_diag(
    int hostA, int wsMB, int hostB, int ran,
    const int* __restrict__ offs, const int* __restrict__ csrp,
    const float* __restrict__ W1, float* __restrict__ out)
{
    __shared__ int simpl, soob, sA;
    int tid = threadIdx.x;
    if (tid == 0) { simpl = 0; soob = 0; sA = hostA; }
    __syncthreads();
    if (ran) {
        if (tid == 0 && offs[N_NODES] != N_EDGES) atomicOr(&sA, 4);
        float v = W1[tid];
        if (!(fabsf(v) < 100.f)) atomicAdd(&simpl, 1);
        int r = csrp[tid];
        if ((r & 0xFFFF) >= N_NODES || (r >> 22) != 0 || r < 0) atomicAdd(&soob, 1);
    }
    __syncthreads();
    if (tid != 0) return;
    int A = sA, B = hostB;
    if (ran) {
        if (simpl > 10) A |= 8;
        B = soob;
    }
    if (B > 1023) B = 1023;
    if (A == 0 && B == 0) return;
    out[0] = (float)((A << 20) | (wsMB << 10) | B);
}

// ---------------------------------------------------------------------------
extern "C" void kernel_launch(void* const* d_in, const int* in_sizes, int n_in,
                              void* d_out, int out_size, void* d_ws, size_t ws_size,
                              hipStream_t stream) {
    static const int rsize[22] = {50000, 800000, 1600000, 50000, 512, 96,
                                  16384, 4096, 256, 256, 256, 64,
                                  16384, 4096, 256, 256, 256, 64,
                                  4096, 64, 128, 2};
    static const int cand_pos[3][22] = {
        {21,19,18,12,20,17,0,2,8,4,6,10,1,3,9,5,7,11,15,13,16,14},   // ASCII sorted (R7)
        {0,1,2,3,4,5,6,7,8,9,10,11,12,13,14,15,16,17,18,19,20,21},   // dict order
        {17,15,14,8,16,13,18,20,4,0,2,6,19,21,5,1,3,7,11,9,12,10},   // case-insens
    };
    int mc = -1;
    if (n_in == 22) {
        for (int c = 0; c < 3 && mc < 0; c++) {
            bool ok = true;
            for (int r = 0; r < 22; r++)
                if (in_sizes[cand_pos[c][r]] != rsize[r]) { ok = false; break; }
            if (ok) mc = c;
        }
    }
    int hostA = 0, hostB = 0;
    if (mc < 0) { hostA |= 1; hostB = (n_in != 22) ? (n_in < 1023 ? n_in : 1023) : 0; }

    char* ws = (char*)d_ws;
    size_t off = 0;
    auto alloc = [&](size_t b) { size_t r = off; off += (b + 255) & ~(size_t)255; return r; };
    int*   deg4   = (int*)(ws + alloc((size_t)4 * N_NODES * 4));   // zeroed
    size_t zero_bytes = off;
    int*   deg    = (int*)(ws + alloc(N_NODES * 4));
    int*   blksum = (int*)(ws + alloc(NBLK_SCAN * 4));
    int*   offs   = (int*)(ws + alloc((N_NODES + 1) * 4));
    int*   cursor = (int*)(ws + alloc(N_NODES * 4));
    int*   csrp   = (int*)(ws + alloc(N_EDGES * 4));
    int*   goffs  = (int*)(ws + alloc((N_GRAPH + 1) * 4));
    float* t_h0   = (float*)(ws + alloc(NTT * HC * 4));
    float* t_as0  = (float*)(ws + alloc(NTT * NHEAD * 4));
    float* t_ad0  = (float*)(ws + alloc(NTT * NHEAD * 4));
    float* t_ae0  = (float*)(ws + alloc(NRR * NHEAD * 4));
    float* t_ae1  = (float*)(ws + alloc(NRR * NHEAD * 4));
    float* x1     = (float*)(ws + alloc((size_t)N_NODES * CDIM * 4));
    float* asrc1  = (float*)(ws + alloc((size_t)N_NODES * NHEAD * 4));
    float* adst1  = (float*)(ws + alloc((size_t)N_NODES * NHEAD * 4));
    u16*   h1b    = (u16*)(ws + alloc((size_t)N_NODES * HC * 2));
    float* x2     = (float*)(ws + alloc((size_t)N_NODES * CDIM * 4));
    float* gm     = (float*)(ws + alloc(N_GRAPH * CDIM * 4));

    if (mc >= 0 && off > ws_size) hostA |= 2;
    int wsMB = (int)(ws_size >> 20); if (wsMB > 1023) wsMB = 1023;
    int ran = (hostA == 0) ? 1 : 0;

    if (ran) {
        const int* P = cand_pos[mc];
        const int*   node_type  = (const int*)d_in[P[0]];
        const int*   edge_type  = (const int*)d_in[P[1]];
        const int*   edge_index = (const int*)d_in[P[2]];
        const int*   batch      = (const int*)d_in[P[3]];
        const float* node_emb   = (const float*)d_in[P[4]];
        const float* edge_emb   = (const float*)d_in[P[5]];
        const float* W0  = (const float*)d_in[P[6]];
        const float* We0 = (const float*)d_in[P[7]];
        const float* as0 = (const float*)d_in[P[8]];
        const float* ad0 = (const float*)d_in[P[9]];
        const float* ae0 = (const float*)d_in[P[10]];
        const float* b0  = (const float*)d_in[P[11]];
        const float* W1  = (const float*)d_in[P[12]];
        const float* We1 = (const float*)d_in[P[13]];
        const float* as1 = (const float*)d_in[P[14]];
        const float* ad1 = (const float*)d_in[P[15]];
        const float* ae1 = (const float*)d_in[P[16]];
        const float* b1  = (const float*)d_in[P[17]];
        const float* cw1 = (const float*)d_in[P[18]];
        const float* cb1 = (const float*)d_in[P[19]];
        const float* cw2 = (const float*)d_in[P[20]];
        const float* cb2 = (const float*)d_in[P[21]];

        int zero_elems = (int)(zero_bytes / 4);
        k_zero<<<(zero_elems + 255) / 256, 256, 0, stream>>>((float*)ws, zero_elems);
        k_tables<<<1, 256, 0, stream>>>(node_emb, edge_emb, W0, We0, as0, ad0, ae0,
                                        We1, ae1,
                                        t_h0, t_as0, t_ad0, t_ae0, t_ae1);
        k_count<<<(N_EDGES + 255) / 256, 256, 0, stream>>>(edge_index, deg4);
        k_goffs<<<(N_NODES + 255) / 256, 256, 0, stream>>>(batch, goffs);
        k_scan1<<<NBLK_SCAN, 256, 0, stream>>>(deg4, deg, blksum);
        k_scan2<<<1, 64, 0, stream>>>(blksum, offs);
        k_scan3<<<NBLK_SCAN, 256, 0, stream>>>(deg, blksum, offs, cursor);
        k_scatter<<<(N_EDGES + 255) / 256, 256, 0, stream>>>(edge_index, edge_type,
                                                             node_type, cursor, csrp);
        k_layer0<<<(N_NODES * 64) / 256, 256, 0, stream>>>(
            node_type, offs, csrp, t_h0, t_as0, t_ad0, t_ae0, b0, x1);
        k_gemm1<<<(N_NODES + 31) / 32, 256, 0, stream>>>(
            x1, W1, as1, ad1, h1b, asrc1, adst1);
        k_agg1<<<(N_NODES * 64) / 256, 256, 0, stream>>>(
            offs, csrp, h1b, asrc1, adst1, t_ae1, b1, x2);
        k_pool<<<N_GRAPH, 256, 0, stream>>>(x2, goffs, gm);
        k_cls<<<N_GRAPH, 64, 0, stream>>>(gm, cw1, cb1, cw2, cb2, (float*)d_out);
        k_diag<<<1, 256, 0, stream>>>(0, wsMB, 0, 1, offs, csrp, W1, (float*)d_out);
    } else {
        k_diag<<<1, 256, 0, stream>>>(hostA, wsMB, hostB, 0, nullptr, nullptr,
                                      nullptr, (float*)d_out);
    }
}

// Round 13
// 396.506 us; speedup vs baseline: 3.1872x; 1.0807x over previous
//
#include <hip/hip_runtime.h>
#include <hip/hip_bf16.h>

#define N_NODES 50000
#define N_EDGES 800000
#define N_GRAPH 64
#define NHEAD 4
#define CDIM 64
#define HC 256      // NHEAD*CDIM
#define NTT 8
#define NRR 6
#define EDIMM 16
#define SCAN_CHUNK 1024
#define NBLK_SCAN ((N_NODES + SCAN_CHUNK - 1) / SCAN_CHUNK)   // 49

typedef unsigned short u16;
typedef __attribute__((ext_vector_type(8))) short bf8;   // 8 bf16 (4 VGPRs)
typedef __attribute__((ext_vector_type(4))) float f4;    // MFMA acc

__device__ __forceinline__ float eluf(float v) { return v > 0.f ? v : expm1f(v); }
__device__ __forceinline__ float u2f(u16 u) {
    union { float f; unsigned int i; } c; c.i = ((unsigned int)u) << 16; return c.f;
}
__device__ __forceinline__ u16 f2u(float f) {
    union { float f; unsigned int i; } c; c.f = f;
    unsigned int i = c.i;
    return (u16)((i + 0x7FFFu + ((i >> 16) & 1u)) >> 16);
}
__device__ __forceinline__ float lrelu(float v) { return v > 0.f ? v : 0.2f * v; }

__global__ __launch_bounds__(256) void k_zero(float* __restrict__ p, int n)
{
    int i = blockIdx.x * 256 + threadIdx.x;
    if (i < n) p[i] = 0.f;
}

// ---------------------------------------------------------------------------
// Tiny tables + W1 -> bf16 (MFMA B operand)
// ---------------------------------------------------------------------------
__global__ __launch_bounds__(256) void k_tables(
    const float* __restrict__ node_emb, const float* __restrict__ edge_emb,
    const float* __restrict__ W0, const float* __restrict__ We0,
    const float* __restrict__ as0, const float* __restrict__ ad0,
    const float* __restrict__ ae0, const float* __restrict__ We1,
    const float* __restrict__ ae1, const float* __restrict__ W1,
    float* __restrict__ t_h0, float* __restrict__ t_as0,
    float* __restrict__ t_ad0, float* __restrict__ t_ae0,
    float* __restrict__ t_ae1, u16* __restrict__ w1b)
{
    __shared__ float s_h0[NTT * HC];
    __shared__ float s_he[NRR * HC];
    int tid = threadIdx.x;

    for (int i = tid; i < CDIM * HC; i += 256) w1b[i] = f2u(W1[i]);

    for (int t = 0; t < NTT; t++) {
        float acc = 0.f;
        #pragma unroll 8
        for (int k = 0; k < CDIM; k++)
            acc += node_emb[t * CDIM + k] * W0[k * HC + tid];
        s_h0[t * HC + tid] = acc;
        t_h0[t * HC + tid] = acc;
    }
    for (int r = 0; r < NRR; r++) {
        float acc = 0.f;
        #pragma unroll
        for (int k = 0; k < EDIMM; k++)
            acc += edge_emb[r * EDIMM + k] * We0[k * HC + tid];
        s_he[r * HC + tid] = acc;
    }
    __syncthreads();
    if (tid < NTT * NHEAD) {
        int t = tid >> 2, h = tid & 3;
        float a = 0.f, d = 0.f;
        for (int c = 0; c < CDIM; c++) {
            float hv = s_h0[t * HC + h * CDIM + c];
            a += hv * as0[h * CDIM + c];
            d += hv * ad0[h * CDIM + c];
        }
        t_as0[tid] = a;
        t_ad0[tid] = d;
    }
    if (tid < NRR * NHEAD) {
        int r = tid >> 2, h = tid & 3;
        float a = 0.f;
        for (int c = 0; c < CDIM; c++)
            a += s_he[r * HC + h * CDIM + c] * ae0[h * CDIM + c];
        t_ae0[tid] = a;
    }
    __syncthreads();
    for (int r = 0; r < NRR; r++) {
        float acc = 0.f;
        #pragma unroll
        for (int k = 0; k < EDIMM; k++)
            acc += edge_emb[r * EDIMM + k] * We1[k * HC + tid];
        s_he[r * HC + tid] = acc;
    }
    __syncthreads();
    if (tid < NRR * NHEAD) {
        int r = tid >> 2, h = tid & 3;
        float a = 0.f;
        for (int c = 0; c < CDIM; c++)
            a += s_he[r * HC + h * CDIM + c] * ae1[h * CDIM + c];
        t_ae1[tid] = a;
    }
}

// ---------------------------------------------------------------------------
// CSR build (unchanged from R11/R12, HW-verified)
// ---------------------------------------------------------------------------
__global__ __launch_bounds__(256) void k_count(
    const int* __restrict__ edge_index, int* __restrict__ deg4)
{
    int i = blockIdx.x * 256 + threadIdx.x;
    if (i < N_EDGES)
        atomicAdd(&deg4[(blockIdx.x & 3) * N_NODES + edge_index[N_EDGES + i]], 1);
}

__global__ __launch_bounds__(256) void k_goffs(
    const int* __restrict__ batch, int* __restrict__ goffs)
{
    int i = blockIdx.x * 256 + threadIdx.x;
    if (i >= N_NODES) return;
    int bi = batch[i];
    int bp = (i == 0) ? -1 : batch[i - 1];
    for (int g = bp + 1; g <= bi; g++) goffs[g] = i;
    if (i == N_NODES - 1)
        for (int g = bi + 1; g <= N_GRAPH; g++) goffs[g] = N_NODES;
}

__global__ __launch_bounds__(256) void k_scan1(
    const int* __restrict__ deg4, int* __restrict__ deg, int* __restrict__ blksum)
{
    __shared__ int s[256];
    int b = blockIdx.x, tid = threadIdx.x;
    int base = b * SCAN_CHUNK + tid * 4;
    int t = 0;
    #pragma unroll
    for (int k = 0; k < 4; k++) {
        int i = base + k;
        if (i < N_NODES) {
            int d = deg4[i] + deg4[N_NODES + i] + deg4[2 * N_NODES + i]
                  + deg4[3 * N_NODES + i];
            deg[i] = d;
            t += d;
        }
    }
    s[tid] = t;
    __syncthreads();
    for (int off = 128; off > 0; off >>= 1) {
        if (tid < off) s[tid] += s[tid + off];
        __syncthreads();
    }
    if (tid == 0) blksum[b] = s[0];
}

__global__ void k_scan2(int* __restrict__ blksum, int* __restrict__ offs)
{
    if (threadIdx.x == 0 && blockIdx.x == 0) {
        int acc = 0;
        for (int b = 0; b < NBLK_SCAN; b++) { int t = blksum[b]; blksum[b] = acc; acc += t; }
        offs[N_NODES] = acc;
    }
}

__global__ __launch_bounds__(256) void k_scan3(
    const int* __restrict__ deg, const int* __restrict__ blksum,
    int* __restrict__ offs, int* __restrict__ cursor)
{
    __shared__ int s[256];
    int b = blockIdx.x, tid = threadIdx.x;
    int base = b * SCAN_CHUNK + tid * 4;
    int d[4]; int t = 0;
    #pragma unroll
    for (int k = 0; k < 4; k++) {
        int i = base + k;
        d[k] = (i < N_NODES) ? deg[i] : 0;
        t += d[k];
    }
    s[tid] = t;
    __syncthreads();
    for (int off = 1; off < 256; off <<= 1) {
        int v = (tid >= off) ? s[tid - off] : 0;
        __syncthreads();
        s[tid] += v;
        __syncthreads();
    }
    int excl = blksum[b] + s[tid] - t;
    #pragma unroll
    for (int k = 0; k < 4; k++) {
        int i = base + k;
        if (i < N_NODES) { offs[i] = excl; cursor[i] = excl; }
        excl += d[k];
    }
}

__global__ __launch_bounds__(256) void k_scatter(
    const int* __restrict__ edge_index, const int* __restrict__ edge_type,
    const int* __restrict__ node_type, int* __restrict__ cursor,
    int* __restrict__ csrp)
{
    int e = blockIdx.x * 256 + threadIdx.x;
    if (e < N_EDGES) {
        int d  = edge_index[N_EDGES + e];
        int s  = edge_index[e];
        int et = edge_type[e];
        int ts = node_type[s];
        int pos = atomicAdd(&cursor[d], 1);
        csrp[pos] = s | (et << 16) | (ts << 19);
    }
}

// ---------------------------------------------------------------------------
// Layer-0 edge phase: one wave per node; writes x1 as bf16 (MFMA A operand).
// ---------------------------------------------------------------------------
__global__ __launch_bounds__(256) void k_layer0(
    const int* __restrict__ node_type, const int* __restrict__ offs,
    const int* __restrict__ csrp,
    const float* __restrict__ t_h0, const float* __restrict__ t_as0,
    const float* __restrict__ t_ad0, const float* __restrict__ t_ae0,
    const float* __restrict__ b0, u16* __restrict__ x1b)
{
    __shared__ float s_h0[NTT * HC];                 // 8 KB
    __shared__ float s_as[NTT * NHEAD], s_ad[NTT * NHEAD], s_ae[NRR * NHEAD];
    __shared__ float s_b0[CDIM];

    int tid = threadIdx.x;
    for (int i = tid; i < NTT * HC; i += 256) s_h0[i] = t_h0[i];
    if (tid < NTT * NHEAD) { s_as[tid] = t_as0[tid]; s_ad[tid] = t_ad0[tid]; }
    if (tid < NRR * NHEAD) s_ae[tid] = t_ae0[tid];
    if (tid < CDIM) s_b0[tid] = b0[tid];
    __syncthreads();

    int n = (blockIdx.x * 256 + tid) >> 6;
    int lane = tid & 63;
    int h = lane >> 4;
    int cq = (lane & 15) << 2;

    int tn = node_type[n];
    float adst = s_ad[tn * NHEAD + h];
    int e0 = offs[n], e1 = offs[n + 1];
    float ax = 0.f, ay = 0.f, az = 0.f, aw = 0.f, den = 0.f;
    for (int i = e0; i < e1; i += 4) {
        int last = e1 - 1;
        int i1 = i + 1 > last ? last : i + 1;
        int i2 = i + 2 > last ? last : i + 2;
        int i3 = i + 3 > last ? last : i + 3;
        float m1 = (i + 1 < e1) ? 1.f : 0.f;
        float m2 = (i + 2 < e1) ? 1.f : 0.f;
        float m3 = (i + 3 < e1) ? 1.f : 0.f;
        int rA = csrp[i],  rB = csrp[i1], rC = csrp[i2], rD = csrp[i3];
        int tA = rA >> 19, tB = rB >> 19, tC = rC >> 19, tD = rD >> 19;
        int eA = (rA >> 16) & 7, eB = (rB >> 16) & 7;
        int eC = (rC >> 16) & 7, eD = (rD >> 16) & 7;
        float pA = __expf(lrelu(s_as[tA * NHEAD + h] + adst + s_ae[eA * NHEAD + h]));
        float pB = m1 * __expf(lrelu(s_as[tB * NHEAD + h] + adst + s_ae[eB * NHEAD + h]));
        float pC = m2 * __expf(lrelu(s_as[tC * NHEAD + h] + adst + s_ae[eC * NHEAD + h]));
        float pD = m3 * __expf(lrelu(s_as[tD * NHEAD + h] + adst + s_ae[eD * NHEAD + h]));
        den += pA + pB + pC + pD;
        const float4 vA = *(const float4*)(s_h0 + tA * HC + h * CDIM + cq);
        const float4 vB = *(const float4*)(s_h0 + tB * HC + h * CDIM + cq);
        const float4 vC = *(const float4*)(s_h0 + tC * HC + h * CDIM + cq);
        const float4 vD = *(const float4*)(s_h0 + tD * HC + h * CDIM + cq);
        ax += pA * vA.x + pB * vB.x + pC * vC.x + pD * vD.x;
        ay += pA * vA.y + pB * vB.y + pC * vC.y + pD * vD.y;
        az += pA * vA.z + pB * vB.z + pC * vC.z + pD * vD.z;
        aw += pA * vA.w + pB * vB.w + pC * vC.w + pD * vD.w;
    }
    float inv = 0.25f / (den + 1e-16f);
    ax *= inv; ay *= inv; az *= inv; aw *= inv;
    ax += __shfl_xor(ax, 16); ax += __shfl_xor(ax, 32);
    ay += __shfl_xor(ay, 16); ay += __shfl_xor(ay, 32);
    az += __shfl_xor(az, 16); az += __shfl_xor(az, 32);
    aw += __shfl_xor(aw, 16); aw += __shfl_xor(aw, 32);
    if (lane < 16) {
        ushort4 o;
        o.x = f2u(eluf(ax + s_b0[cq + 0]));
        o.y = f2u(eluf(ay + s_b0[cq + 1]));
        o.z = f2u(eluf(az + s_b0[cq + 2]));
        o.w = f2u(eluf(aw + s_b0[cq + 3]));
        *(ushort4*)(x1b + (size_t)n * CDIM + cq) = o;
    }
}

// ---------------------------------------------------------------------------
// h1 = x1 @ W1 via MFMA 16x16x32 bf16. Wave wv owns cols [wv*64, wv*64+64)
// (== head wv). Per node-tile: 2 A-frag loads, 8 MFMAs, dots in epilogue
// (per-quad shfl reduce; each (quad,reg) owns a distinct node -> no atomics),
// h1 staged via LDS for coalesced stores. 625 blocks x 5 tiles = 3125 tiles.
// ---------------------------------------------------------------------------
__global__ __launch_bounds__(256) void k_gemm1(
    const u16* __restrict__ x1b, const u16* __restrict__ w1b,
    const float* __restrict__ as1, const float* __restrict__ ad1,
    u16* __restrict__ h1b, float* __restrict__ asrc1, float* __restrict__ adst1)
{
    __shared__ u16 ht[16 * HC];   // 8 KB
    int tid = threadIdx.x;
    int lane = tid & 63, wv = tid >> 6;
    int quad = lane >> 4, c16 = lane & 15;

    // B fragments: B[k = kf*32 + quad*8 + j][col], col = wv*64 + t*16 + c16
    bf8 bf[4][2];
    float sv[4], dv[4];
    #pragma unroll
    for (int t = 0; t < 4; t++) {
        int col = wv * 64 + t * 16 + c16;
        sv[t] = as1[col];
        dv[t] = ad1[col];
        #pragma unroll
        for (int kf = 0; kf < 2; kf++)
            #pragma unroll
            for (int j = 0; j < 8; j++)
                bf[t][kf][j] = (short)w1b[(kf * 32 + quad * 8 + j) * HC + col];
    }

    for (int it = 0; it < 5; it++) {
        int nt = it * 625 + blockIdx.x;                 // rows nt*16 .. +15
        // A frags: A[m = c16][k = quad*8 + j] (+32 for second kfrag)
        const bf8 a0 = *(const bf8*)(x1b + (size_t)(nt * 16 + c16) * CDIM + quad * 8);
        const bf8 a1 = *(const bf8*)(x1b + (size_t)(nt * 16 + c16) * CDIM + 32 + quad * 8);
        f4 acc[4];
        #pragma unroll
        for (int t = 0; t < 4; t++) {
            acc[t] = (f4){0.f, 0.f, 0.f, 0.f};
            acc[t] = __builtin_amdgcn_mfma_f32_16x16x32_bf16(a0, bf[t][0], acc[t], 0, 0, 0);
            acc[t] = __builtin_amdgcn_mfma_f32_16x16x32_bf16(a1, bf[t][1], acc[t], 0, 0, 0);
        }
        // D: row = quad*4 + reg (node), col = wv*64 + t*16 + c16
        float rs[4] = {0.f, 0.f, 0.f, 0.f}, rd[4] = {0.f, 0.f, 0.f, 0.f};
        #pragma unroll
        for (int t = 0; t < 4; t++)
            #pragma unroll
            for (int reg = 0; reg < 4; reg++) {
                float v = acc[t][reg];
                rs[reg] += v * sv[t];
                rd[reg] += v * dv[t];
                ht[(quad * 4 + reg) * HC + wv * 64 + t * 16 + c16] = f2u(v);
            }
        #pragma unroll
        for (int reg = 0; reg < 4; reg++)
            #pragma unroll
            for (int d = 1; d < 16; d <<= 1) {
                rs[reg] += __shfl_xor(rs[reg], d);
                rd[reg] += __shfl_xor(rd[reg], d);
            }
        if (c16 == 0) {
            #pragma unroll
            for (int reg = 0; reg < 4; reg++) {
                int n = nt * 16 + quad * 4 + reg;
                asrc1[n * NHEAD + wv] = rs[reg];
                adst1[n * NHEAD + wv] = rd[reg];
            }
        }
        __syncthreads();
        const uint4* src = (const uint4*)ht;            // 512 uint4
        uint4* dst = (uint4*)(h1b + (size_t)nt * 16 * HC);
        dst[tid] = src[tid];
        dst[tid + 256] = src[tid + 256];
        __syncthreads();
    }
}

// ---------------------------------------------------------------------------
// Layer 1 aggregation + ELU -> coalesced x2 stream (no atomics).
// ---------------------------------------------------------------------------
__global__ __launch_bounds__(256) void k_agg1(
    const int* __restrict__ offs, const int* __restrict__ csrp,
    const u16* __restrict__ h1b, const float* __restrict__ asrc1,
    const float* __restrict__ adst1, const float* __restrict__ t_ae1,
    const float* __restrict__ b1, float* __restrict__ x2)
{
    __shared__ float s_ae[NRR * NHEAD];
    if (threadIdx.x < NRR * NHEAD) s_ae[threadIdx.x] = t_ae1[threadIdx.x];
    __syncthreads();

    int n = (blockIdx.x * 256 + threadIdx.x) >> 6;
    int lane = threadIdx.x & 63;
    int h = lane >> 4;
    int cq = (lane & 15) << 2;
    float adst = adst1[n * NHEAD + h];
    int e0 = offs[n], e1 = offs[n + 1];

    float ax = 0.f, ay = 0.f, az = 0.f, aw = 0.f, den = 0.f;
    for (int i = e0; i < e1; i += 8) {
        int last = e1 - 1;
        int idx[8];
        float m[8];
        #pragma unroll
        for (int k = 0; k < 8; k++) {
            int ik = i + k;
            idx[k] = ik > last ? last : ik;
            m[k] = (k == 0 || ik < e1) ? 1.f : 0.f;
        }
        int rec[8], s[8], et[8];
        #pragma unroll
        for (int k = 0; k < 8; k++) rec[k] = csrp[idx[k]];
        #pragma unroll
        for (int k = 0; k < 8; k++) { s[k] = rec[k] & 0xFFFF; et[k] = (rec[k] >> 16) & 7; }
        float asv[8];
        ushort4 hv[8];
        #pragma unroll
        for (int k = 0; k < 8; k++) asv[k] = asrc1[s[k] * NHEAD + h];
        #pragma unroll
        for (int k = 0; k < 8; k++)
            hv[k] = *(const ushort4*)(h1b + (size_t)s[k] * HC + h * CDIM + cq);
        #pragma unroll
        for (int k = 0; k < 8; k++) {
            float p = m[k] * __expf(lrelu(asv[k] + adst + s_ae[et[k] * NHEAD + h]));
            den += p;
            ax += p * u2f(hv[k].x);
            ay += p * u2f(hv[k].y);
            az += p * u2f(hv[k].z);
            aw += p * u2f(hv[k].w);
        }
    }
    float inv = 0.25f / (den + 1e-16f);
    ax *= inv; ay *= inv; az *= inv; aw *= inv;
    ax += __shfl_xor(ax, 16); ax += __shfl_xor(ax, 32);
    ay += __shfl_xor(ay, 16); ay += __shfl_xor(ay, 32);
    az += __shfl_xor(az, 16); az += __shfl_xor(az, 32);
    aw += __shfl_xor(aw, 16); aw += __shfl_xor(aw, 32);
    if (lane < 16) {
        float4 o;
        o.x = eluf(ax + b1[cq + 0]);
        o.y = eluf(ay + b1[cq + 1]);
        o.z = eluf(az + b1[cq + 2]);
        o.w = eluf(aw + b1[cq + 3]);
        *(float4*)(x2 + (size_t)n * CDIM + cq) = o;
    }
}

// ---------------------------------------------------------------------------
// Mean-pool per graph (contiguous ranges, zero atomics)
// ---------------------------------------------------------------------------
__global__ __launch_bounds__(256) void k_pool(
    const float* __restrict__ x2, const int* __restrict__ goffs,
    float* __restrict__ gm)
{
    __shared__ float part[4][CDIM];
    int g = blockIdx.x;
    int ch = threadIdx.x & 63, rg = threadIdx.x >> 6;
    int gs = goffs[g], ge = goffs[g + 1];
    float acc = 0.f;
    for (int r = gs + rg; r < ge; r += 4)
        acc += x2[(size_t)r * CDIM + ch];
    part[rg][ch] = acc;
    __syncthreads();
    if (threadIdx.x < CDIM) {
        float s = part[0][ch] + part[1][ch] + part[2][ch] + part[3][ch];
        int c = ge - gs;
        gm[g * CDIM + ch] = s / (float)(c > 1 ? c : 1);
    }
}

// ---------------------------------------------------------------------------
// Classifier
// ---------------------------------------------------------------------------
__global__ __launch_bounds__(64) void k_cls(
    const float* __restrict__ gm, const float* __restrict__ cw1,
    const float* __restrict__ cb1, const float* __restrict__ cw2,
    const float* __restrict__ cb2, float* __restrict__ out)
{
    int g = blockIdx.x, j = threadIdx.x;
    __shared__ float gsh[CDIM];
    gsh[j] = gm[g * CDIM + j];
    __syncthreads();
    float acc = cb1[j];
    #pragma unroll
    for (int k = 0; k < CDIM; k++) acc += gsh[k] * cw1[k * CDIM + j];
    float hid = acc > 0.f ? acc : 0.f;
    float o0 = hid * cw2[j * 2 + 0];
    float o1 = hid * cw2[j * 2 + 1];
    #pragma unroll
    for (int d = 32; d >= 1; d >>= 1) {
        o0 += __shfl_xor(o0, d);
        o1 += __shfl_xor(o1, d);
    }
    if (j == 0) {
        out[g * 2 + 0] = o0 + cb2[0];
        out[g * 2 + 1] = o1 + cb2[1];
    }
}

// ---------------------------------------------------------------------------
// DIAGNOSTIC (fires only on fault)
// ---------------------------------------------------------------------------
__global__ __launch_bounds__(256) void k_diag(
    int hostA, int wsMB, int hostB, int ran,
    const int* __restrict__ offs, const int* __restrict__ csrp,
    const float* __restrict__ W1, float* __restrict__ out)
{
    __shared__ int simpl, soob, sA;
    int tid = threadIdx.x;
    if (tid == 0) { simpl = 0; soob = 0; sA = hostA; }
    __syncthreads();
    if (ran) {
        if (tid == 0 && offs[N_NODES] != N_EDGES) atomicOr(&sA, 4);
        float v = W1[tid];
        if (!(fabsf(v) < 100.f)) atomicAdd(&simpl, 1);
        int r = csrp[tid];
        if ((r & 0xFFFF) >= N_NODES || (r >> 22) != 0 || r < 0) atomicAdd(&soob, 1);
    }
    __syncthreads();
    if (tid != 0) return;
    int A = sA, B = hostB;
    if (ran) {
        if (simpl > 10) A |= 8;
        B = soob;
    }
    if (B > 1023) B = 1023;
    if (A == 0 && B == 0) return;
    out[0] = (float)((A << 20) | (wsMB << 10) | B);
}

// ---------------------------------------------------------------------------
extern "C" void kernel_launch(void* const* d_in, const int* in_sizes, int n_in,
                              void* d_out, int out_size, void* d_ws, size_t ws_size,
                              hipStream_t stream) {
    static const int rsize[22] = {50000, 800000, 1600000, 50000, 512, 96,
                                  16384, 4096, 256, 256, 256, 64,
                                  16384, 4096, 256, 256, 256, 64,
                                  4096, 64, 128, 2};
    static const int cand_pos[3][22] = {
        {21,19,18,12,20,17,0,2,8,4,6,10,1,3,9,5,7,11,15,13,16,14},   // ASCII sorted (R7)
        {0,1,2,3,4,5,6,7,8,9,10,11,12,13,14,15,16,17,18,19,20,21},   // dict order
        {17,15,14,8,16,13,18,20,4,0,2,6,19,21,5,1,3,7,11,9,12,10},   // case-insens
    };
    int mc = -1;
    if (n_in == 22) {
        for (int c = 0; c < 3 && mc < 0; c++) {
            bool ok = true;
            for (int r = 0; r < 22; r++)
                if (in_sizes[cand_pos[c][r]] != rsize[r]) { ok = false; break; }
            if (ok) mc = c;
        }
    }
    int hostA = 0, hostB = 0;
    if (mc < 0) { hostA |= 1; hostB = (n_in != 22) ? (n_in < 1023 ? n_in : 1023) : 0; }

    char* ws = (char*)d_ws;
    size_t off = 0;
    auto alloc = [&](size_t b) { size_t r = off; off += (b + 255) & ~(size_t)255; return r; };
    int*   deg4   = (int*)(ws + alloc((size_t)4 * N_NODES * 4));   // zeroed
    size_t zero_bytes = off;
    int*   deg    = (int*)(ws + alloc(N_NODES * 4));
    int*   blksum = (int*)(ws + alloc(NBLK_SCAN * 4));
    int*   offs   = (int*)(ws + alloc((N_NODES + 1) * 4));
    int*   cursor = (int*)(ws + alloc(N_NODES * 4));
    int*   csrp   = (int*)(ws + alloc(N_EDGES * 4));
    int*   goffs  = (int*)(ws + alloc((N_GRAPH + 1) * 4));
    float* t_h0   = (float*)(ws + alloc(NTT * HC * 4));
    float* t_as0  = (float*)(ws + alloc(NTT * NHEAD * 4));
    float* t_ad0  = (float*)(ws + alloc(NTT * NHEAD * 4));
    float* t_ae0  = (float*)(ws + alloc(NRR * NHEAD * 4));
    float* t_ae1  = (float*)(ws + alloc(NRR * NHEAD * 4));
    u16*   w1b    = (u16*)(ws + alloc(CDIM * HC * 2));
    u16*   x1b    = (u16*)(ws + alloc((size_t)N_NODES * CDIM * 2));
    float* asrc1  = (float*)(ws + alloc((size_t)N_NODES * NHEAD * 4));
    float* adst1  = (float*)(ws + alloc((size_t)N_NODES * NHEAD * 4));
    u16*   h1b    = (u16*)(ws + alloc((size_t)N_NODES * HC * 2));
    float* x2     = (float*)(ws + alloc((size_t)N_NODES * CDIM * 4));
    float* gm     = (float*)(ws + alloc(N_GRAPH * CDIM * 4));

    if (mc >= 0 && off > ws_size) hostA |= 2;
    int wsMB = (int)(ws_size >> 20); if (wsMB > 1023) wsMB = 1023;
    int ran = (hostA == 0) ? 1 : 0;

    if (ran) {
        const int* P = cand_pos[mc];
        const int*   node_type  = (const int*)d_in[P[0]];
        const int*   edge_type  = (const int*)d_in[P[1]];
        const int*   edge_index = (const int*)d_in[P[2]];
        const int*   batch      = (const int*)d_in[P[3]];
        const float* node_emb   = (const float*)d_in[P[4]];
        const float* edge_emb   = (const float*)d_in[P[5]];
        const float* W0  = (const float*)d_in[P[6]];
        const float* We0 = (const float*)d_in[P[7]];
        const float* as0 = (const float*)d_in[P[8]];
        const float* ad0 = (const float*)d_in[P[9]];
        const float* ae0 = (const float*)d_in[P[10]];
        const float* b0  = (const float*)d_in[P[11]];
        const float* W1  = (const float*)d_in[P[12]];
        const float* We1 = (const float*)d_in[P[13]];
        const float* as1 = (const float*)d_in[P[14]];
        const float* ad1 = (const float*)d_in[P[15]];
        const float* ae1 = (const float*)d_in[P[16]];
        const float* b1  = (const float*)d_in[P[17]];
        const float* cw1 = (const float*)d_in[P[18]];
        const float* cb1 = (const float*)d_in[P[19]];
        const float* cw2 = (const float*)d_in[P[20]];
        const float* cb2 = (const float*)d_in[P[21]];

        int zero_elems = (int)(zero_bytes / 4);
        k_zero<<<(zero_elems + 255) / 256, 256, 0, stream>>>((float*)ws, zero_elems);
        k_tables<<<1, 256, 0, stream>>>(node_emb, edge_emb, W0, We0, as0, ad0, ae0,
                                        We1, ae1, W1,
                                        t_h0, t_as0, t_ad0, t_ae0, t_ae1, w1b);
        k_count<<<(N_EDGES + 255) / 256, 256, 0, stream>>>(edge_index, deg4);
        k_goffs<<<(N_NODES + 255) / 256, 256, 0, stream>>>(batch, goffs);
        k_scan1<<<NBLK_SCAN, 256, 0, stream>>>(deg4, deg, blksum);
        k_scan2<<<1, 64, 0, stream>>>(blksum, offs);
        k_scan3<<<NBLK_SCAN, 256, 0, stream>>>(deg, blksum, offs, cursor);
        k_scatter<<<(N_EDGES + 255) / 256, 256, 0, stream>>>(edge_index, edge_type,
                                                             node_type, cursor, csrp);
        k_layer0<<<(N_NODES * 64) / 256, 256, 0, stream>>>(
            node_type, offs, csrp, t_h0, t_as0, t_ad0, t_ae0, b0, x1b);
        k_gemm1<<<625, 256, 0, stream>>>(
            x1b, w1b, as1, ad1, h1b, asrc1, adst1);
        k_agg1<<<(N_NODES * 64) / 256, 256, 0, stream>>>(
            offs, csrp, h1b, asrc1, adst1, t_ae1, b1, x2);
        k_pool<<<N_GRAPH, 256, 0, stream>>>(x2, goffs, gm);
        k_cls<<<N_GRAPH, 64, 0, stream>>>(gm, cw1, cb1, cw2, cb2, (float*)d_out);
        k_diag<<<1, 256, 0, stream>>>(0, wsMB, 0, 1, offs, csrp, W1, (float*)d_out);
    } else {
        k_diag<<<1, 256, 0, stream>>>(hostA, wsMB, hostB, 0, nullptr, nullptr,
                                      nullptr, (float*)d_out);
    }
}

// Round 14
// 371.801 us; speedup vs baseline: 3.3990x; 1.0664x over previous
//
#include <hip/hip_runtime.h>
#include <hip/hip_bf16.h>

#define N_NODES 50000
#define N_EDGES 800000
#define N_GRAPH 64
#define NHEAD 4
#define CDIM 64
#define HC 256      // NHEAD*CDIM
#define NTT 8
#define NRR 6
#define EDIMM 16
#define SCAN_CHUNK 1024
#define NBLK_SCAN ((N_NODES + SCAN_CHUNK - 1) / SCAN_CHUNK)   // 49

typedef unsigned short u16;
typedef __attribute__((ext_vector_type(8))) short bf8;   // 8 bf16 (4 VGPRs)
typedef __attribute__((ext_vector_type(4))) float f4;    // MFMA acc

__device__ __forceinline__ float eluf(float v) { return v > 0.f ? v : expm1f(v); }
__device__ __forceinline__ float u2f(u16 u) {
    union { float f; unsigned int i; } c; c.i = ((unsigned int)u) << 16; return c.f;
}
__device__ __forceinline__ u16 f2u(float f) {
    union { float f; unsigned int i; } c; c.f = f;
    unsigned int i = c.i;
    return (u16)((i + 0x7FFFu + ((i >> 16) & 1u)) >> 16);
}
__device__ __forceinline__ float lrelu(float v) { return v > 0.f ? v : 0.2f * v; }

__global__ __launch_bounds__(256) void k_zero(float* __restrict__ p, int n)
{
    int i = blockIdx.x * 256 + threadIdx.x;
    if (i < n) p[i] = 0.f;
}

// ---------------------------------------------------------------------------
// Tiny tables (single block; W1 conversion removed — gemm1 converts inline)
// ---------------------------------------------------------------------------
__global__ __launch_bounds__(256) void k_tables(
    const float* __restrict__ node_emb, const float* __restrict__ edge_emb,
    const float* __restrict__ W0, const float* __restrict__ We0,
    const float* __restrict__ as0, const float* __restrict__ ad0,
    const float* __restrict__ ae0, const float* __restrict__ We1,
    const float* __restrict__ ae1,
    float* __restrict__ t_h0, float* __restrict__ t_as0,
    float* __restrict__ t_ad0, float* __restrict__ t_ae0,
    float* __restrict__ t_ae1)
{
    __shared__ float s_h0[NTT * HC];
    __shared__ float s_he[NRR * HC];
    int tid = threadIdx.x;

    for (int t = 0; t < NTT; t++) {
        float acc = 0.f;
        #pragma unroll 8
        for (int k = 0; k < CDIM; k++)
            acc += node_emb[t * CDIM + k] * W0[k * HC + tid];
        s_h0[t * HC + tid] = acc;
        t_h0[t * HC + tid] = acc;
    }
    for (int r = 0; r < NRR; r++) {
        float acc = 0.f;
        #pragma unroll
        for (int k = 0; k < EDIMM; k++)
            acc += edge_emb[r * EDIMM + k] * We0[k * HC + tid];
        s_he[r * HC + tid] = acc;
    }
    __syncthreads();
    if (tid < NTT * NHEAD) {
        int t = tid >> 2, h = tid & 3;
        float a = 0.f, d = 0.f;
        for (int c = 0; c < CDIM; c++) {
            float hv = s_h0[t * HC + h * CDIM + c];
            a += hv * as0[h * CDIM + c];
            d += hv * ad0[h * CDIM + c];
        }
        t_as0[tid] = a;
        t_ad0[tid] = d;
    }
    if (tid < NRR * NHEAD) {
        int r = tid >> 2, h = tid & 3;
        float a = 0.f;
        for (int c = 0; c < CDIM; c++)
            a += s_he[r * HC + h * CDIM + c] * ae0[h * CDIM + c];
        t_ae0[tid] = a;
    }
    __syncthreads();
    for (int r = 0; r < NRR; r++) {
        float acc = 0.f;
        #pragma unroll
        for (int k = 0; k < EDIMM; k++)
            acc += edge_emb[r * EDIMM + k] * We1[k * HC + tid];
        s_he[r * HC + tid] = acc;
    }
    __syncthreads();
    if (tid < NRR * NHEAD) {
        int r = tid >> 2, h = tid & 3;
        float a = 0.f;
        for (int c = 0; c < CDIM; c++)
            a += s_he[r * HC + h * CDIM + c] * ae1[h * CDIM + c];
        t_ae1[tid] = a;
    }
}

// ---------------------------------------------------------------------------
// Degree count (4-way privatized) + fused goffs boundary detection
// ---------------------------------------------------------------------------
__global__ __launch_bounds__(256) void k_count(
    const int* __restrict__ edge_index, int* __restrict__ deg4,
    const int* __restrict__ batch, int* __restrict__ goffs)
{
    int i = blockIdx.x * 256 + threadIdx.x;
    if (i < N_EDGES)
        atomicAdd(&deg4[(blockIdx.x & 3) * N_NODES + edge_index[N_EDGES + i]], 1);
    if (i < N_NODES) {
        int bi = batch[i];
        int bp = (i == 0) ? -1 : batch[i - 1];
        for (int g = bp + 1; g <= bi; g++) goffs[g] = i;
        if (i == N_NODES - 1)
            for (int g = bi + 1; g <= N_GRAPH; g++) goffs[g] = N_NODES;
    }
}

// merge deg4 -> deg (plain stores) + raw per-chunk sums
__global__ __launch_bounds__(256) void k_scan1(
    const int* __restrict__ deg4, int* __restrict__ deg, int* __restrict__ blksum)
{
    __shared__ int s[256];
    int b = blockIdx.x, tid = threadIdx.x;
    int base = b * SCAN_CHUNK + tid * 4;
    int t = 0;
    #pragma unroll
    for (int k = 0; k < 4; k++) {
        int i = base + k;
        if (i < N_NODES) {
            int d = deg4[i] + deg4[N_NODES + i] + deg4[2 * N_NODES + i]
                  + deg4[3 * N_NODES + i];
            deg[i] = d;
            t += d;
        }
    }
    s[tid] = t;
    __syncthreads();
    for (int off = 128; off > 0; off >>= 1) {
        if (tid < off) s[tid] += s[tid + off];
        __syncthreads();
    }
    if (tid == 0) blksum[b] = s[0];
}

// intra-chunk scan; each block wave-reduces the raw blksums for its base
// (kills the k_scan2 launch). Last block writes offs[N_NODES].
__global__ __launch_bounds__(256) void k_scan3(
    const int* __restrict__ deg, const int* __restrict__ blksum,
    int* __restrict__ offs, int* __restrict__ cursor)
{
    __shared__ int s[256];
    __shared__ int sbase;
    int b = blockIdx.x, tid = threadIdx.x;
    if (tid < 64) {
        int v = (tid < b) ? blksum[tid] : 0;
        #pragma unroll
        for (int d = 32; d >= 1; d >>= 1) v += __shfl_xor(v, d);
        if (tid == 0) sbase = v;
    }
    int base = b * SCAN_CHUNK + tid * 4;
    int d4[4]; int t = 0;
    #pragma unroll
    for (int k = 0; k < 4; k++) {
        int i = base + k;
        d4[k] = (i < N_NODES) ? deg[i] : 0;
        t += d4[k];
    }
    s[tid] = t;
    __syncthreads();
    for (int off = 1; off < 256; off <<= 1) {
        int v = (tid >= off) ? s[tid - off] : 0;
        __syncthreads();
        s[tid] += v;
        __syncthreads();
    }
    int excl = sbase + s[tid] - t;
    #pragma unroll
    for (int k = 0; k < 4; k++) {
        int i = base + k;
        if (i < N_NODES) { offs[i] = excl; cursor[i] = excl; }
        excl += d4[k];
    }
    if (b == NBLK_SCAN - 1 && tid == 255) offs[N_NODES] = excl;
}

__global__ __launch_bounds__(256) void k_scatter(
    const int* __restrict__ edge_index, const int* __restrict__ edge_type,
    const int* __restrict__ node_type, int* __restrict__ cursor,
    int* __restrict__ csrp)
{
    int e = blockIdx.x * 256 + threadIdx.x;
    if (e < N_EDGES) {
        int d  = edge_index[N_EDGES + e];
        int s  = edge_index[e];
        int et = edge_type[e];
        int ts = node_type[s];
        int pos = atomicAdd(&cursor[d], 1);
        csrp[pos] = s | (et << 16) | (ts << 19);
    }
}

// ---------------------------------------------------------------------------
// Layer-0 edge phase: one wave per node; unmasked batch-4 main loop + tail.
// Writes x1 bf16 (MFMA A operand).
// ---------------------------------------------------------------------------
__global__ __launch_bounds__(256) void k_layer0(
    const int* __restrict__ node_type, const int* __restrict__ offs,
    const int* __restrict__ csrp,
    const float* __restrict__ t_h0, const float* __restrict__ t_as0,
    const float* __restrict__ t_ad0, const float* __restrict__ t_ae0,
    const float* __restrict__ b0, u16* __restrict__ x1b)
{
    __shared__ float s_h0[NTT * HC];                 // 8 KB
    __shared__ float s_as[NTT * NHEAD], s_ad[NTT * NHEAD], s_ae[NRR * NHEAD];
    __shared__ float s_b0[CDIM];

    int tid = threadIdx.x;
    for (int i = tid; i < NTT * HC; i += 256) s_h0[i] = t_h0[i];
    if (tid < NTT * NHEAD) { s_as[tid] = t_as0[tid]; s_ad[tid] = t_ad0[tid]; }
    if (tid < NRR * NHEAD) s_ae[tid] = t_ae0[tid];
    if (tid < CDIM) s_b0[tid] = b0[tid];
    __syncthreads();

    int n = (blockIdx.x * 256 + tid) >> 6;
    int lane = tid & 63;
    int h = lane >> 4;
    int cq = (lane & 15) << 2;

    int tn = node_type[n];
    float adst = s_ad[tn * NHEAD + h];
    int e0 = offs[n], e1 = offs[n + 1];
    int efull = e0 + ((e1 - e0) & ~3);
    float ax = 0.f, ay = 0.f, az = 0.f, aw = 0.f, den = 0.f;
    for (int i = e0; i < efull; i += 4) {
        int rA = csrp[i],     rB = csrp[i + 1];
        int rC = csrp[i + 2], rD = csrp[i + 3];
        int tA = rA >> 19, tB = rB >> 19, tC = rC >> 19, tD = rD >> 19;
        int eA = (rA >> 16) & 7, eB = (rB >> 16) & 7;
        int eC = (rC >> 16) & 7, eD = (rD >> 16) & 7;
        float pA = __expf(lrelu(s_as[tA * NHEAD + h] + adst + s_ae[eA * NHEAD + h]));
        float pB = __expf(lrelu(s_as[tB * NHEAD + h] + adst + s_ae[eB * NHEAD + h]));
        float pC = __expf(lrelu(s_as[tC * NHEAD + h] + adst + s_ae[eC * NHEAD + h]));
        float pD = __expf(lrelu(s_as[tD * NHEAD + h] + adst + s_ae[eD * NHEAD + h]));
        den += pA + pB + pC + pD;
        const float4 vA = *(const float4*)(s_h0 + tA * HC + h * CDIM + cq);
        const float4 vB = *(const float4*)(s_h0 + tB * HC + h * CDIM + cq);
        const float4 vC = *(const float4*)(s_h0 + tC * HC + h * CDIM + cq);
        const float4 vD = *(const float4*)(s_h0 + tD * HC + h * CDIM + cq);
        ax += pA * vA.x + pB * vB.x + pC * vC.x + pD * vD.x;
        ay += pA * vA.y + pB * vB.y + pC * vC.y + pD * vD.y;
        az += pA * vA.z + pB * vB.z + pC * vC.z + pD * vD.z;
        aw += pA * vA.w + pB * vB.w + pC * vC.w + pD * vD.w;
    }
    for (int i = efull; i < e1; i++) {
        int r = csrp[i];
        int ts = r >> 19, et = (r >> 16) & 7;
        float p = __expf(lrelu(s_as[ts * NHEAD + h] + adst + s_ae[et * NHEAD + h]));
        den += p;
        const float4 v = *(const float4*)(s_h0 + ts * HC + h * CDIM + cq);
        ax += p * v.x; ay += p * v.y; az += p * v.z; aw += p * v.w;
    }
    float inv = 0.25f / (den + 1e-16f);
    ax *= inv; ay *= inv; az *= inv; aw *= inv;
    ax += __shfl_xor(ax, 16); ax += __shfl_xor(ax, 32);
    ay += __shfl_xor(ay, 16); ay += __shfl_xor(ay, 32);
    az += __shfl_xor(az, 16); az += __shfl_xor(az, 32);
    aw += __shfl_xor(aw, 16); aw += __shfl_xor(aw, 32);
    if (lane < 16) {
        ushort4 o;
        o.x = f2u(eluf(ax + s_b0[cq + 0]));
        o.y = f2u(eluf(ay + s_b0[cq + 1]));
        o.z = f2u(eluf(az + s_b0[cq + 2]));
        o.w = f2u(eluf(aw + s_b0[cq + 3]));
        *(ushort4*)(x1b + (size_t)n * CDIM + cq) = o;
    }
}

// ---------------------------------------------------------------------------
// h1 = x1 @ W1 via MFMA 16x16x32 bf16 (layouts HW-verified). B-frags loaded
// from f32 W1 and converted once per block.
// ---------------------------------------------------------------------------
__global__ __launch_bounds__(256) void k_gemm1(
    const u16* __restrict__ x1b, const float* __restrict__ W1,
    const float* __restrict__ as1, const float* __restrict__ ad1,
    u16* __restrict__ h1b, float* __restrict__ asrc1, float* __restrict__ adst1)
{
    __shared__ u16 ht[16 * HC];   // 8 KB
    int tid = threadIdx.x;
    int lane = tid & 63, wv = tid >> 6;
    int quad = lane >> 4, c16 = lane & 15;

    bf8 bf[4][2];
    float sv[4], dv[4];
    #pragma unroll
    for (int t = 0; t < 4; t++) {
        int col = wv * 64 + t * 16 + c16;
        sv[t] = as1[col];
        dv[t] = ad1[col];
        #pragma unroll
        for (int kf = 0; kf < 2; kf++)
            #pragma unroll
            for (int j = 0; j < 8; j++)
                bf[t][kf][j] = (short)f2u(W1[(kf * 32 + quad * 8 + j) * HC + col]);
    }

    for (int it = 0; it < 5; it++) {
        int nt = it * 625 + blockIdx.x;
        const bf8 a0 = *(const bf8*)(x1b + (size_t)(nt * 16 + c16) * CDIM + quad * 8);
        const bf8 a1 = *(const bf8*)(x1b + (size_t)(nt * 16 + c16) * CDIM + 32 + quad * 8);
        f4 acc[4];
        #pragma unroll
        for (int t = 0; t < 4; t++) {
            acc[t] = (f4){0.f, 0.f, 0.f, 0.f};
            acc[t] = __builtin_amdgcn_mfma_f32_16x16x32_bf16(a0, bf[t][0], acc[t], 0, 0, 0);
            acc[t] = __builtin_amdgcn_mfma_f32_16x16x32_bf16(a1, bf[t][1], acc[t], 0, 0, 0);
        }
        float rs[4] = {0.f, 0.f, 0.f, 0.f}, rd[4] = {0.f, 0.f, 0.f, 0.f};
        #pragma unroll
        for (int t = 0; t < 4; t++)
            #pragma unroll
            for (int reg = 0; reg < 4; reg++) {
                float v = acc[t][reg];
                rs[reg] += v * sv[t];
                rd[reg] += v * dv[t];
                ht[(quad * 4 + reg) * HC + wv * 64 + t * 16 + c16] = f2u(v);
            }
        #pragma unroll
        for (int reg = 0; reg < 4; reg++)
            #pragma unroll
            for (int d = 1; d < 16; d <<= 1) {
                rs[reg] += __shfl_xor(rs[reg], d);
                rd[reg] += __shfl_xor(rd[reg], d);
            }
        if (c16 == 0) {
            #pragma unroll
            for (int reg = 0; reg < 4; reg++) {
                int n = nt * 16 + quad * 4 + reg;
                asrc1[n * NHEAD + wv] = rs[reg];
                adst1[n * NHEAD + wv] = rd[reg];
            }
        }
        __syncthreads();
        const uint4* src = (const uint4*)ht;
        uint4* dst = (uint4*)(h1b + (size_t)nt * 16 * HC);
        dst[tid] = src[tid];
        dst[tid + 256] = src[tid + 256];
        __syncthreads();
    }
}

// ---------------------------------------------------------------------------
// Layer 1 aggregation + ELU -> coalesced x2 (unmasked batch-8 + tail).
// ---------------------------------------------------------------------------
__global__ __launch_bounds__(256) void k_agg1(
    const int* __restrict__ offs, const int* __restrict__ csrp,
    const u16* __restrict__ h1b, const float* __restrict__ asrc1,
    const float* __restrict__ adst1, const float* __restrict__ t_ae1,
    const float* __restrict__ b1, float* __restrict__ x2)
{
    __shared__ float s_ae[NRR * NHEAD];
    if (threadIdx.x < NRR * NHEAD) s_ae[threadIdx.x] = t_ae1[threadIdx.x];
    __syncthreads();

    int n = (blockIdx.x * 256 + threadIdx.x) >> 6;
    int lane = threadIdx.x & 63;
    int h = lane >> 4;
    int cq = (lane & 15) << 2;
    float adst = adst1[n * NHEAD + h];
    int e0 = offs[n], e1 = offs[n + 1];
    int efull = e0 + ((e1 - e0) & ~7);

    float ax = 0.f, ay = 0.f, az = 0.f, aw = 0.f, den = 0.f;
    for (int i = e0; i < efull; i += 8) {
        int rec[8], s[8], et[8];
        #pragma unroll
        for (int k = 0; k < 8; k++) rec[k] = csrp[i + k];
        #pragma unroll
        for (int k = 0; k < 8; k++) { s[k] = rec[k] & 0xFFFF; et[k] = (rec[k] >> 16) & 7; }
        float asv[8];
        ushort4 hv[8];
        #pragma unroll
        for (int k = 0; k < 8; k++) asv[k] = asrc1[s[k] * NHEAD + h];
        #pragma unroll
        for (int k = 0; k < 8; k++)
            hv[k] = *(const ushort4*)(h1b + (size_t)s[k] * HC + h * CDIM + cq);
        #pragma unroll
        for (int k = 0; k < 8; k++) {
            float p = __expf(lrelu(asv[k] + adst + s_ae[et[k] * NHEAD + h]));
            den += p;
            ax += p * u2f(hv[k].x);
            ay += p * u2f(hv[k].y);
            az += p * u2f(hv[k].z);
            aw += p * u2f(hv[k].w);
        }
    }
    for (int i = efull; i < e1; i++) {
        int rec = csrp[i];
        int s = rec & 0xFFFF, et = (rec >> 16) & 7;
        float p = __expf(lrelu(asrc1[s * NHEAD + h] + adst + s_ae[et * NHEAD + h]));
        den += p;
        ushort4 hv = *(const ushort4*)(h1b + (size_t)s * HC + h * CDIM + cq);
        ax += p * u2f(hv.x); ay += p * u2f(hv.y);
        az += p * u2f(hv.z); aw += p * u2f(hv.w);
    }
    float inv = 0.25f / (den + 1e-16f);
    ax *= inv; ay *= inv; az *= inv; aw *= inv;
    ax += __shfl_xor(ax, 16); ax += __shfl_xor(ax, 32);
    ay += __shfl_xor(ay, 16); ay += __shfl_xor(ay, 32);
    az += __shfl_xor(az, 16); az += __shfl_xor(az, 32);
    aw += __shfl_xor(aw, 16); aw += __shfl_xor(aw, 32);
    if (lane < 16) {
        float4 o;
        o.x = eluf(ax + b1[cq + 0]);
        o.y = eluf(ay + b1[cq + 1]);
        o.z = eluf(az + b1[cq + 2]);
        o.w = eluf(aw + b1[cq + 3]);
        *(float4*)(x2 + (size_t)n * CDIM + cq) = o;
    }
}

// ---------------------------------------------------------------------------
// FUSED mean-pool + classifier (+ diag in block 0, fires only on fault)
// ---------------------------------------------------------------------------
__global__ __launch_bounds__(256) void k_poolcls(
    const float* __restrict__ x2, const int* __restrict__ goffs,
    const float* __restrict__ cw1, const float* __restrict__ cb1,
    const float* __restrict__ cw2, const float* __restrict__ cb2,
    float* __restrict__ out, int wsMB,
    const int* __restrict__ offs, const int* __restrict__ csrp,
    const float* __restrict__ W1)
{
    __shared__ float part[4][CDIM];
    __shared__ float gsh[CDIM];
    int g = blockIdx.x;
    int ch = threadIdx.x & 63, rg = threadIdx.x >> 6;
    int gs = goffs[g], ge = goffs[g + 1];
    float acc = 0.f;
    for (int r = gs + rg; r < ge; r += 4)
        acc += x2[(size_t)r * CDIM + ch];
    part[rg][ch] = acc;
    __syncthreads();
    if (threadIdx.x < CDIM) {
        float s = part[0][ch] + part[1][ch] + part[2][ch] + part[3][ch];
        int c = ge - gs;
        gsh[ch] = s / (float)(c > 1 ? c : 1);
    }
    __syncthreads();
    if (threadIdx.x < 64) {
        int j = threadIdx.x;
        float a = cb1[j];
        #pragma unroll
        for (int k = 0; k < CDIM; k++) a += gsh[k] * cw1[k * CDIM + j];
        float hid = a > 0.f ? a : 0.f;
        float o0 = hid * cw2[j * 2 + 0];
        float o1 = hid * cw2[j * 2 + 1];
        #pragma unroll
        for (int d = 32; d >= 1; d >>= 1) {
            o0 += __shfl_xor(o0, d);
            o1 += __shfl_xor(o1, d);
        }
        if (j == 0) {
            out[g * 2 + 0] = o0 + cb2[0];
            out[g * 2 + 1] = o1 + cb2[1];
        }
    }
    if (g == 0) {
        __shared__ int simpl, soob, sA;
        if (threadIdx.x == 0) { simpl = 0; soob = 0; sA = 0; }
        __syncthreads();
        if (threadIdx.x == 0 && offs[N_NODES] != N_EDGES) atomicOr(&sA, 4);
        float v = W1[threadIdx.x];
        if (!(fabsf(v) < 100.f)) atomicAdd(&simpl, 1);
        int r = csrp[threadIdx.x];
        if ((r & 0xFFFF) >= N_NODES || (r >> 22) != 0 || r < 0) atomicAdd(&soob, 1);
        __syncthreads();
        if (threadIdx.x == 0) {
            int A = sA;
            if (simpl > 10) A |= 8;
            int B = soob > 1023 ? 1023 : soob;
            if (A | B) out[0] = (float)((A << 20) | (wsMB << 10) | B);
        }
    }
}

// host-detected fault reporter (cold path only)
__global__ void k_fault(int code, float* __restrict__ out)
{
    if (threadIdx.x == 0 && blockIdx.x == 0) out[0] = (float)code;
}

// ---------------------------------------------------------------------------
extern "C" void kernel_launch(void* const* d_in, const int* in_sizes, int n_in,
                              void* d_out, int out_size, void* d_ws, size_t ws_size,
                              hipStream_t stream) {
    static const int rsize[22] = {50000, 800000, 1600000, 50000, 512, 96,
                                  16384, 4096, 256, 256, 256, 64,
                                  16384, 4096, 256, 256, 256, 64,
                                  4096, 64, 128, 2};
    static const int cand_pos[3][22] = {
        {21,19,18,12,20,17,0,2,8,4,6,10,1,3,9,5,7,11,15,13,16,14},   // ASCII sorted (R7)
        {0,1,2,3,4,5,6,7,8,9,10,11,12,13,14,15,16,17,18,19,20,21},   // dict order
        {17,15,14,8,16,13,18,20,4,0,2,6,19,21,5,1,3,7,11,9,12,10},   // case-insens
    };
    int mc = -1;
    if (n_in == 22) {
        for (int c = 0; c < 3 && mc < 0; c++) {
            bool ok = true;
            for (int r = 0; r < 22; r++)
                if (in_sizes[cand_pos[c][r]] != rsize[r]) { ok = false; break; }
            if (ok) mc = c;
        }
    }

    char* ws = (char*)d_ws;
    size_t off = 0;
    auto alloc = [&](size_t b) { size_t r = off; off += (b + 255) & ~(size_t)255; return r; };
    int*   deg4   = (int*)(ws + alloc((size_t)4 * N_NODES * 4));   // zeroed
    size_t zero_bytes = off;
    int*   deg    = (int*)(ws + alloc(N_NODES * 4));
    int*   blksum = (int*)(ws + alloc(NBLK_SCAN * 4));
    int*   offs   = (int*)(ws + alloc((N_NODES + 1) * 4));
    int*   cursor = (int*)(ws + alloc(N_NODES * 4));
    int*   csrp   = (int*)(ws + alloc(N_EDGES * 4));
    int*   goffs  = (int*)(ws + alloc((N_GRAPH + 1) * 4));
    float* t_h0   = (float*)(ws + alloc(NTT * HC * 4));
    float* t_as0  = (float*)(ws + alloc(NTT * NHEAD * 4));
    float* t_ad0  = (float*)(ws + alloc(NTT * NHEAD * 4));
    float* t_ae0  = (float*)(ws + alloc(NRR * NHEAD * 4));
    float* t_ae1  = (float*)(ws + alloc(NRR * NHEAD * 4));
    u16*   x1b    = (u16*)(ws + alloc((size_t)N_NODES * CDIM * 2));
    float* asrc1  = (float*)(ws + alloc((size_t)N_NODES * NHEAD * 4));
    float* adst1  = (float*)(ws + alloc((size_t)N_NODES * NHEAD * 4));
    u16*   h1b    = (u16*)(ws + alloc((size_t)N_NODES * HC * 2));
    float* x2     = (float*)(ws + alloc((size_t)N_NODES * CDIM * 4));

    int wsMB = (int)(ws_size >> 20); if (wsMB > 1023) wsMB = 1023;
    int hostA = 0, hostB = 0;
    if (mc < 0) { hostA |= 1; hostB = (n_in != 22) ? (n_in < 1023 ? n_in : 1023) : 0; }
    if (mc >= 0 && off > ws_size) hostA |= 2;

    if (hostA == 0) {
        const int* P = cand_pos[mc];
        const int*   node_type  = (const int*)d_in[P[0]];
        const int*   edge_type  = (const int*)d_in[P[1]];
        const int*   edge_index = (const int*)d_in[P[2]];
        const int*   batch      = (const int*)d_in[P[3]];
        const float* node_emb   = (const float*)d_in[P[4]];
        const float* edge_emb   = (const float*)d_in[P[5]];
        const float* W0  = (const float*)d_in[P[6]];
        const float* We0 = (const float*)d_in[P[7]];
        const float* as0 = (const float*)d_in[P[8]];
        const float* ad0 = (const float*)d_in[P[9]];
        const float* ae0 = (const float*)d_in[P[10]];
        const float* b0  = (const float*)d_in[P[11]];
        const float* W1  = (const float*)d_in[P[12]];
        const float* We1 = (const float*)d_in[P[13]];
        const float* as1 = (const float*)d_in[P[14]];
        const float* ad1 = (const float*)d_in[P[15]];
        const float* ae1 = (const float*)d_in[P[16]];
        const float* b1  = (const float*)d_in[P[17]];
        const float* cw1 = (const float*)d_in[P[18]];
        const float* cb1 = (const float*)d_in[P[19]];
        const float* cw2 = (const float*)d_in[P[20]];
        const float* cb2 = (const float*)d_in[P[21]];

        int zero_elems = (int)(zero_bytes / 4);
        k_zero<<<(zero_elems + 255) / 256, 256, 0, stream>>>((float*)ws, zero_elems);
        k_tables<<<1, 256, 0, stream>>>(node_emb, edge_emb, W0, We0, as0, ad0, ae0,
                                        We1, ae1,
                                        t_h0, t_as0, t_ad0, t_ae0, t_ae1);
        k_count<<<(N_EDGES + 255) / 256, 256, 0, stream>>>(edge_index, deg4,
                                                           batch, goffs);
        k_scan1<<<NBLK_SCAN, 256, 0, stream>>>(deg4, deg, blksum);
        k_scan3<<<NBLK_SCAN, 256, 0, stream>>>(deg, blksum, offs, cursor);
        k_scatter<<<(N_EDGES + 255) / 256, 256, 0, stream>>>(edge_index, edge_type,
                                                             node_type, cursor, csrp);
        k_layer0<<<(N_NODES * 64) / 256, 256, 0, stream>>>(
            node_type, offs, csrp, t_h0, t_as0, t_ad0, t_ae0, b0, x1b);
        k_gemm1<<<625, 256, 0, stream>>>(
            x1b, W1, as1, ad1, h1b, asrc1, adst1);
        k_agg1<<<(N_NODES * 64) / 256, 256, 0, stream>>>(
            offs, csrp, h1b, asrc1, adst1, t_ae1, b1, x2);
        k_poolcls<<<N_GRAPH, 256, 0, stream>>>(
            x2, goffs, cw1, cb1, cw2, cb2, (float*)d_out, wsMB, offs, csrp, W1);
    } else {
        int code = (hostA << 20) | (wsMB << 10) | (hostB > 1023 ? 1023 : hostB);
        k_fault<<<1, 64, 0, stream>>>(code, (float*)d_out);
    }
}